// Round 5
// baseline (1072.829 us; speedup 1.0000x reference)
//
#include <hip/hip_runtime.h>
#include <stdint.h>
#include <math.h>
#include <algorithm>

#define NS 8
#define NA 1024
#define NK 5
#define MAXIT 30
#define TOLER 1e-5
#define SSTRIDE ((size_t)NA * NA + 64 * NA)  // padded per-sample Bcomp stride (floats)

// ---------------- host-side threefry-2x32 (JAX-compatible) ----------------
static inline void tf2x32(uint32_t k0, uint32_t k1, uint32_t c0, uint32_t c1,
                          uint32_t& o0, uint32_t& o1) {
  uint32_t ks2 = k0 ^ k1 ^ 0x1BD11BDAu;
  uint32_t x0 = c0 + k0, x1 = c1 + k1;
  auto rot = [](uint32_t x, int r) { return (x << r) | (x >> (32 - r)); };
  auto R4 = [&](int r0, int r1, int r2, int r3) {
    x0 += x1; x1 = rot(x1, r0); x1 ^= x0;
    x0 += x1; x1 = rot(x1, r1); x1 ^= x0;
    x0 += x1; x1 = rot(x1, r2); x1 ^= x0;
    x0 += x1; x1 = rot(x1, r3); x1 ^= x0;
  };
  R4(13, 15, 26, 6);  x0 += k1;  x1 += ks2 + 1u;
  R4(17, 29, 16, 24); x0 += ks2; x1 += k0 + 2u;
  R4(13, 15, 26, 6);  x0 += k0;  x1 += k1 + 3u;
  R4(17, 29, 16, 24); x0 += k1;  x1 += ks2 + 4u;
  R4(13, 15, 26, 6);  x0 += ks2; x1 += k0 + 5u;
  o0 = x0; o1 = x1;
}

struct InitIdx { int v[NS * NK]; };

// jax_threefry_partitionable=True semantics (verified R3/R5-R8: PASS)
static void compute_init_indices(InitIdx& out) {
  const uint32_t rk0 = 0, rk1 = 42;
  for (int s = 0; s < NS; s++) {
    uint32_t k0, k1;
    tf2x32(rk0, rk1, 0u, (uint32_t)s, k0, k1);
    uint32_t sk0, sk1;
    tf2x32(k0, k1, 0u, 1u, sk0, sk1);
    uint32_t bits[NA];
    for (int i = 0; i < NA; i++) {
      uint32_t b0, b1;
      tf2x32(sk0, sk1, 0u, (uint32_t)i, b0, b1);
      bits[i] = b0 ^ b1;
    }
    int idx[NA];
    for (int i = 0; i < NA; i++) idx[i] = i;
    std::stable_sort(idx, idx + NA, [&](int x, int y) { return bits[x] < bits[y]; });
    for (int c = 0; c < NK; c++) out.v[s * NK + c] = idx[c];
  }
}

// ---------------- device helpers ----------------
__device__ __forceinline__ double wave_reduce64(double v) {
#pragma unroll
  for (int m = 32; m > 0; m >>= 1) v += __shfl_xor(v, m, 64);
  return v;
}

__device__ __forceinline__ double blk_sum_1024(double v, double* red16) {
  double w = wave_reduce64(v);
  if ((threadIdx.x & 63) == 0) red16[threadIdx.x >> 6] = w;
  __syncthreads();
  double tot = 0.0;
#pragma unroll
  for (int i = 0; i < 16; i++) tot += red16[i];
  __syncthreads();
  return tot;
}

__device__ __forceinline__ double blk_sum_256(double v, double* red4) {
  double w = wave_reduce64(v);
  if ((threadIdx.x & 63) == 0) red4[threadIdx.x >> 6] = w;
  __syncthreads();
  double tot = red4[0] + red4[1] + red4[2] + red4[3];
  __syncthreads();
  return tot;
}

// Fused dual block-sum (1024 thr): one LDS pass, one barrier pair, deterministic.
__device__ __forceinline__ void blk_sum2_1024(double a, double b, double* redA, double* redB,
                                              double& ra, double& rb) {
#pragma unroll
  for (int m = 32; m > 0; m >>= 1) {
    a += __shfl_xor(a, m, 64);
    b += __shfl_xor(b, m, 64);
  }
  if ((threadIdx.x & 63) == 0) {
    redA[threadIdx.x >> 6] = a;
    redB[threadIdx.x >> 6] = b;
  }
  __syncthreads();
  ra = 0.0; rb = 0.0;
#pragma unroll
  for (int i = 0; i < 16; i++) { ra += redA[i]; rb += redB[i]; }
  __syncthreads();
}

// ---------------- fused pre-kernel: xn + centers_init + rstd array + state ----------------
// blocks 0..511: xn (inline rstd); 512..551: centers_init; 552: rstd[]+pot+conv.
__global__ __launch_bounds__(256) void k_pre(const float* __restrict__ cov, double* __restrict__ rstd,
                                             double* __restrict__ xn, double* __restrict__ C,
                                             InitIdx ii, double* __restrict__ pot, int* __restrict__ conv) {
  int w = blockIdx.x;
  if (w < 512) {
    int s = w >> 6;
    __shared__ double rsh[NA];
    const float* covS = cov + (size_t)s * NA * NA;
    for (int j = threadIdx.x; j < NA; j += 256)
      rsh[j] = 1.0 / sqrt((double)covS[(size_t)j * NA + j]);
    __syncthreads();
    int lane = threadIdx.x & 63, wave = threadIdx.x >> 6;
    for (int q = 0; q < 4; q++) {
      int i = (w & 63) * 16 + wave * 4 + q;
      const float* row = covS + (size_t)i * NA;
      double acc = 0.0;
      for (int j = lane; j < NA; j += 64) {
        double v = (double)row[j] * rsh[j];
        acc += v * v;
      }
      acc = wave_reduce64(acc);
      if (lane == 0) {
        double ri = rsh[i];
        xn[s * NA + i] = acc * ri * ri;
      }
    }
  } else if (w < 552) {
    int w2 = w - 512;
    int s = w2 / NK, k = w2 % NK;
    int idx = ii.v[s * NK + k];
    const float* covS = cov + (size_t)s * NA * NA;
    double ri = 1.0 / sqrt((double)covS[(size_t)idx * NA + idx]);
    const float* row = covS + (size_t)idx * NA;
    for (int j = threadIdx.x; j < NA; j += 256) {
      double rj = 1.0 / sqrt((double)covS[(size_t)j * NA + j]);
      C[((size_t)s * NK + k) * NA + j] = (double)row[j] * ri * rj;
    }
  } else {
    int t = threadIdx.x;
    for (int gid = t; gid < NS * NA; gid += 256) {
      int s = gid >> 10, a = gid & 1023;
      rstd[gid] = 1.0 / sqrt((double)cov[(size_t)s * NA * NA + (size_t)a * NA + a]);
    }
    if (t < NS) { pot[t] = INFINITY; conv[t] = 0; }
  }
}

// ---------------- KMeans iteration: 2 launches, fused single cov pass ----------------
__global__ __launch_bounds__(1024) void k_assignA(const float* __restrict__ cov, const double* __restrict__ rstd,
                                                  const double* __restrict__ xn, const double* __restrict__ C,
                                                  const int* __restrict__ conv, int* __restrict__ ixs,
                                                  double* __restrict__ mind, double* __restrict__ pU) {
  int blk = blockIdx.x, s = blk >> 5, rblk = blk & 31;
  if (conv[s]) return;  // frozen: coherent via kernel-boundary ordering
  __shared__ double Cs[NK][NA];  // rstd_j-scaled centers, 40 KB
  __shared__ double red16[16];
  __shared__ int bks[32];
  __shared__ double rloc[32];
  int t = threadIdx.x, lane = t & 63, wid = t >> 6;
  double rj = rstd[s * NA + t];
  double sq[NK];
#pragma unroll
  for (int k = 0; k < NK; k++) {
    double c = C[((size_t)s * NK + k) * NA + t];
    Cs[k][t] = c * rj;
    sq[k] = c * c;
  }
  double cn[NK];
#pragma unroll
  for (int k = 0; k < NK; k++) cn[k] = blk_sum_1024(sq[k], red16);
  const float* covS = cov + (size_t)s * NA * NA;
#pragma unroll
  for (int r2 = 0; r2 < 2; r2++) {
    int il = wid * 2 + r2;          // 0..31
    int i = rblk * 32 + il;
    const float* row = covS + (size_t)i * NA;
    double xi = xn[s * NA + i];
    double ri = rstd[s * NA + i];
    double a0 = 0, a1 = 0, a2 = 0, a3 = 0, a4 = 0;
#pragma unroll
    for (int c = 0; c < 16; c++) {
      int j = lane + (c << 6);
      double cv = (double)row[j];
      a0 += cv * Cs[0][j]; a1 += cv * Cs[1][j]; a2 += cv * Cs[2][j];
      a3 += cv * Cs[3][j]; a4 += cv * Cs[4][j];
    }
    a0 = wave_reduce64(a0); a1 = wave_reduce64(a1); a2 = wave_reduce64(a2);
    a3 = wave_reduce64(a3); a4 = wave_reduce64(a4);
    if (lane == 0) {
      double dots[5] = {a0, a1, a2, a3, a4};
      double best = INFINITY;
      int bk = 0;
#pragma unroll
      for (int k = 0; k < NK; k++) {
        double d = xi + cn[k] - 2.0 * ri * dots[k];
        if (d < 0.0) d = 0.0;
        if (d < best) { best = d; bk = k; }  // first-min like jnp.argmin
      }
      ixs[s * NA + i] = bk;
      mind[s * NA + i] = best;
      bks[il] = bk;
      rloc[il] = ri;
    }
  }
  __syncthreads();
  // partial center sums: thread t owns column t; ascending il -> deterministic
  double c0 = 0, c1 = 0, c2 = 0, c3 = 0, c4 = 0;
#pragma unroll
  for (int il = 0; il < 32; il++) {
    int i = rblk * 32 + il;
    double v = (double)covS[(size_t)i * NA + t] * rloc[il];  // L2-hot coalesced re-read
    int k = bks[il];
    c0 += (k == 0) ? v : 0.0;
    c1 += (k == 1) ? v : 0.0;
    c2 += (k == 2) ? v : 0.0;
    c3 += (k == 3) ? v : 0.0;
    c4 += (k == 4) ? v : 0.0;
  }
  double* p = pU + ((size_t)blk * NK) * NA;
  p[0 * NA + t] = c0; p[1 * NA + t] = c1; p[2 * NA + t] = c2;
  p[3 * NA + t] = c3; p[4 * NA + t] = c4;
}

__global__ __launch_bounds__(256) void k_updateB(const double* __restrict__ pU, const double* __restrict__ rstd,
                                                 const int* __restrict__ ixs, const double* __restrict__ mind,
                                                 double* __restrict__ C, double* __restrict__ pot,
                                                 int* __restrict__ conv) {
  int w = blockIdx.x, s = w >> 2, seg = w & 3, t = threadIdx.x;
  if (conv[s]) return;
  __shared__ double red4[4];
  double lc[NK] = {0, 0, 0, 0, 0};
#pragma unroll
  for (int q = 0; q < 4; q++) {
    int c = ixs[s * NA + q * 256 + t];
    lc[0] += (c == 0) ? 1.0 : 0.0;
    lc[1] += (c == 1) ? 1.0 : 0.0;
    lc[2] += (c == 2) ? 1.0 : 0.0;
    lc[3] += (c == 3) ? 1.0 : 0.0;
    lc[4] += (c == 4) ? 1.0 : 0.0;
  }
  double cntk[NK];
#pragma unroll
  for (int k = 0; k < NK; k++) cntk[k] = blk_sum_256(lc[k], red4);
  int j = seg * 256 + t;
  double rjj = rstd[s * NA + j];
  double* CS = C + (size_t)s * NK * NA;
#pragma unroll
  for (int k = 0; k < NK; k++) {
    double a = 0.0;
#pragma unroll
    for (int b = 0; b < 32; b++) {  // ascending b == ascending i: deterministic
      int blk = (s << 5) | b;
      a += pU[((size_t)blk * NK + k) * NA + j];
    }
    if (cntk[k] > 0.0) CS[(size_t)k * NA + j] = a * rjj / cntk[k];
    // empty cluster: keep previous center
  }
  if (seg == 0) {
    double v = mind[s * NA + t] + mind[s * NA + 256 + t] +
               mind[s * NA + 512 + t] + mind[s * NA + 768 + t];
    double p = blk_sum_256(v, red4);
    if (t == 0) {
      double prev = pot[s];
      pot[s] = p;
      if (!(fabs(p - prev) >= TOLER)) conv[s] = 1;  // freeze (while-cond fails)
    }
  }
}

// ---------------- post-processing ----------------
__global__ __launch_bounds__(256) void k_members(const int* __restrict__ ixs, int* __restrict__ g,
                                                 int* __restrict__ cnt, int* __restrict__ off5,
                                                 int* __restrict__ boff) {
  int s = blockIdx.x, t = threadIdx.x;
  __shared__ int sc[NK][256];
  __shared__ int base[NK];
  const int* ix = ixs + s * NA;
  int my[4];
  int lc[NK] = {0, 0, 0, 0, 0};
#pragma unroll
  for (int q = 0; q < 4; q++) { my[q] = ix[t * 4 + q]; lc[my[q]]++; }
#pragma unroll
  for (int k = 0; k < NK; k++) sc[k][t] = lc[k];
  __syncthreads();
  for (int off = 1; off < 256; off <<= 1) {
    int v[NK];
#pragma unroll
    for (int k = 0; k < NK; k++) v[k] = (t >= off) ? sc[k][t - off] : 0;
    __syncthreads();
#pragma unroll
    for (int k = 0; k < NK; k++) sc[k][t] += v[k];
    __syncthreads();
  }
  if (t == 0) {
    int b = 0, bo = 0;
    for (int k = 0; k < NK; k++) {
      int tot = sc[k][255];
      base[k] = b;
      cnt[s * NK + k] = tot;
      off5[s * NK + k] = b;
      boff[s * NK + k] = bo;
      b += tot;
      bo += tot * ((tot + 63) & ~63);  // padded: lda = align64(n)
    }
  }
  __syncthreads();
  int pos[NK];
#pragma unroll
  for (int k = 0; k < NK; k++) pos[k] = base[k] + sc[k][t] - lc[k];
#pragma unroll
  for (int q = 0; q < 4; q++) {
    int k = my[q];
    int p = pos[k]++;
    g[s * NA + p] = t * 4 + q;  // stable ascending asset order within cluster
  }
}

// Compact gather, PADDED: lda = align64(n), zero-filled pad (exact dot contributions).
__global__ __launch_bounds__(1024) void k_gatherB(const float* __restrict__ cov, const int* __restrict__ g,
                                                  const int* __restrict__ cnt, const int* __restrict__ off5,
                                                  const int* __restrict__ boff, float* __restrict__ B) {
  int w = blockIdx.x;  // 40
  int s = w / NK, k = w % NK;
  int n = cnt[s * NK + k];
  if (n == 0) return;
  int lda = (n + 63) & ~63;
  int off = off5[s * NK + k];
  __shared__ int gs[NA];
  int t = threadIdx.x, lane = t & 63, wid = t >> 6;
  if (t < n) gs[t] = g[s * NA + off + t];
  __syncthreads();
  const float* covS = cov + (size_t)s * NA * NA;
  float* Bk = B + (size_t)s * SSTRIDE + (size_t)boff[s * NK + k];
  for (int i = wid; i < n; i += 16) {
    const float* row = covS + (size_t)gs[i] * NA;
    float* out = Bk + (size_t)i * lda;
    for (int j = lane; j < lda; j += 64) out[j] = (j < n) ? row[gs[j]] : 0.0f;
  }
}

// Chronopoulos-Gear CG on padded compact block. Sigma_cc x = 1.
// R4 post-mortem: the toolchain hard-caps this kernel at 64 VGPRs (3 source
// variants, launch_bounds(1024,4) -> all identical codegen, scratch spill).
// Register-resident A (64 floats/thread) is unreachable. New approach: keep A
// in L2 (it is L2-resident across all 50 iters per FETCH_SIZE evidence) and
// fix the LATENCY SHAPE instead: process rows in groups of 4, issuing all 16
// independent L2 loads of a group back-to-back before any FMA, then 4 dot
// chains + 4-way-ILP butterfly. One latency exposure per 4 rows instead of
// per row. Per-lane accumulation order (ascending chunk) and the butterfly
// tree are bitwise-identical to the verified path; guarded chunks add exact
// 0.0; rows >= n are clamped to row 0 (valid memory) and their results
// discarded. ~50 VGPR demand: fits the 64 cap, no spill.
#define MVROW4(MG)                                                              \
  do {                                                                          \
    int i0_ = wid + ((MG) << 4);                                                \
    const float* r0_ = A + (size_t)((i0_ < n) ? i0_ : 0) * lda;                 \
    const float* r1_ = A + (size_t)((i0_ + 16 < n) ? i0_ + 16 : 0) * lda;       \
    const float* r2_ = A + (size_t)((i0_ + 32 < n) ? i0_ + 32 : 0) * lda;       \
    const float* r3_ = A + (size_t)((i0_ + 48 < n) ? i0_ + 48 : 0) * lda;       \
    int j1_ = lane + 64, j2_ = lane + 128, j3_ = lane + 192;                    \
    float f00_ = r0_[lane], f10_ = r1_[lane], f20_ = r2_[lane], f30_ = r3_[lane]; \
    float f01_ = 0.0f, f11_ = 0.0f, f21_ = 0.0f, f31_ = 0.0f;                   \
    float f02_ = 0.0f, f12_ = 0.0f, f22_ = 0.0f, f32_ = 0.0f;                   \
    float f03_ = 0.0f, f13_ = 0.0f, f23_ = 0.0f, f33_ = 0.0f;                   \
    if (lda > 64)  { f01_ = r0_[j1_]; f11_ = r1_[j1_]; f21_ = r2_[j1_]; f31_ = r3_[j1_]; } \
    if (lda > 128) { f02_ = r0_[j2_]; f12_ = r1_[j2_]; f22_ = r2_[j2_]; f32_ = r3_[j2_]; } \
    if (lda > 192) { f03_ = r0_[j3_]; f13_ = r1_[j3_]; f23_ = r2_[j3_]; f33_ = r3_[j3_]; } \
    double a0_ = (double)f00_ * rv0_; double a1_ = (double)f10_ * rv0_;         \
    double a2_ = (double)f20_ * rv0_; double a3_ = (double)f30_ * rv0_;         \
    a0_ += (double)f01_ * rv1_; a1_ += (double)f11_ * rv1_;                     \
    a2_ += (double)f21_ * rv1_; a3_ += (double)f31_ * rv1_;                     \
    a0_ += (double)f02_ * rv2_; a1_ += (double)f12_ * rv2_;                     \
    a2_ += (double)f22_ * rv2_; a3_ += (double)f32_ * rv2_;                     \
    a0_ += (double)f03_ * rv3_; a1_ += (double)f13_ * rv3_;                     \
    a2_ += (double)f23_ * rv3_; a3_ += (double)f33_ * rv3_;                     \
    _Pragma("unroll")                                                           \
    for (int mm_ = 32; mm_ > 0; mm_ >>= 1) {                                    \
      a0_ += __shfl_xor(a0_, mm_, 64);                                          \
      a1_ += __shfl_xor(a1_, mm_, 64);                                          \
      a2_ += __shfl_xor(a2_, mm_, 64);                                          \
      a3_ += __shfl_xor(a3_, mm_, 64);                                          \
    }                                                                           \
    if (lane == 0) {                                                            \
      if (i0_ < n) wv[i0_] = a0_;                                               \
      if (i0_ + 16 < n) wv[i0_ + 16] = a1_;                                     \
      if (i0_ + 32 < n) wv[i0_ + 32] = a2_;                                     \
      if (i0_ + 48 < n) wv[i0_ + 48] = a3_;                                     \
    }                                                                           \
  } while (0)

#define MATVEC_ILP()                                                            \
  do {                                                                          \
    double rv0_ = rv[lane];                                                     \
    double rv1_ = rv[lane + 64];                                                \
    double rv2_ = rv[lane + 128];                                               \
    double rv3_ = rv[lane + 192];                                               \
    MVROW4(0);                                                                  \
    MVROW4(4);                                                                  \
    MVROW4(8);                                                                  \
    MVROW4(12);                                                                 \
  } while (0)

__global__ __launch_bounds__(1024) void k_cg_comp(const float* __restrict__ B, const int* __restrict__ g,
                                                  const int* __restrict__ cnt, const int* __restrict__ off5,
                                                  const int* __restrict__ boff, double* __restrict__ walloc) {
  int w = blockIdx.x;  // 40
  int s = w / NK, k = w % NK;
  int n = cnt[s * NK + k];
  if (n == 0) return;
  int lda = (n + 63) & ~63;
  int nch = lda >> 6;
  int off = off5[s * NK + k];
  const float* A = B + (size_t)s * SSTRIDE + (size_t)boff[s * NK + k];
  __shared__ double xv[NA], rv[NA], pv[NA], sv[NA], wv[NA];
  __shared__ int gs[NA];
  __shared__ double redA[16], redB[16];
  int t = threadIdx.x, lane = t & 63, wid = t >> 6;
  if (t < n) gs[t] = g[s * NA + off + t];
  rv[t] = (t < n) ? 1.0 : 0.0;  // pad region zeroed: matvec reads rv up to lda
  if (t < n) xv[t] = 0.0;
  __syncthreads();
  const double tol = 1e-10 * (double)n;  // rel resid 1e-5: err ~ kappa*1e-5*|w| << floor

  if (n <= 256) {
    // -------- grouped-ILP L2 matvec path --------
    MATVEC_ILP();
    __syncthreads();
    double gam = (double)n;  // (r,r) with r=1
    double d1, d2;
    blk_sum2_1024((t < n) ? wv[t] : 0.0, 0.0, redA, redB, d1, d2);  // (w,r) with r=1
    double alpha = gam / d1;
    if (t < n) { pv[t] = rv[t]; sv[t] = wv[t]; }
    for (int iter = 0; iter < 50; iter++) {
      if (t < n) {
        xv[t] += alpha * pv[t];
        rv[t] -= alpha * sv[t];
      }
      __syncthreads();
      MATVEC_ILP();
      __syncthreads();
      double g1 = 0.0, g2 = 0.0;
      if (t < n) {
        double rt = rv[t];
        g1 = rt * rt;
        g2 = rt * wv[t];
      }
      double gamn, delt;
      blk_sum2_1024(g1, g2, redA, redB, gamn, delt);
      if (gamn < tol) break;  // uniform across block
      double beta = gamn / gam;
      alpha = gamn / (delt - beta * gamn / alpha);
      gam = gamn;
      if (t < n) {
        pv[t] = rv[t] + beta * pv[t];
        sv[t] = wv[t] + beta * sv[t];
      }
      // no extra sync needed: next x/r update is thread-local; matvec sync covers rv
    }
  } else {
    // -------- fallback: global-load matvec (verified path) --------
    // w = A r
    for (int i = wid; i < n; i += 16) {
      const float* row = A + (size_t)i * lda;
      double acc = 0.0;
      for (int c = 0; c < nch; c++) {
        int j = lane + (c << 6);
        acc += (double)row[j] * rv[j];
      }
      acc = wave_reduce64(acc);
      if (lane == 0) wv[i] = acc;
    }
    __syncthreads();
    double gam = (double)n;  // (r,r) with r=1
    double d1, d2;
    blk_sum2_1024((t < n) ? wv[t] : 0.0, 0.0, redA, redB, d1, d2);  // (w,r) with r=1
    double alpha = gam / d1;
    if (t < n) { pv[t] = rv[t]; sv[t] = wv[t]; }
    for (int iter = 0; iter < 50; iter++) {
      if (t < n) {
        xv[t] += alpha * pv[t];
        rv[t] -= alpha * sv[t];
      }
      __syncthreads();
      // w = A r
      for (int i = wid; i < n; i += 16) {
        const float* row = A + (size_t)i * lda;
        double acc = 0.0;
        for (int c = 0; c < nch; c++) {
          int j = lane + (c << 6);
          acc += (double)row[j] * rv[j];
        }
        acc = wave_reduce64(acc);
        if (lane == 0) wv[i] = acc;
      }
      __syncthreads();
      double g1 = 0.0, g2 = 0.0;
      if (t < n) {
        double rt = rv[t];
        g1 = rt * rt;
        g2 = rt * wv[t];
      }
      double gamn, delt;
      blk_sum2_1024(g1, g2, redA, redB, gamn, delt);
      if (gamn < tol) break;  // uniform across block
      double beta = gamn / gam;
      alpha = gamn / (delt - beta * gamn / alpha);
      gam = gamn;
      if (t < n) {
        pv[t] = rv[t] + beta * pv[t];
        sv[t] = wv[t] + beta * sv[t];
      }
    }
  }

  double dp = (t < n) ? xv[t] : 0.0;
  double d3, d4;
  blk_sum2_1024(dp, 0.0, redA, redB, d3, d4);
  if (t < n) walloc[s * NA + gs[t]] = xv[t] / d3;
}

// Fallback (ws too small for compact B): R5's full-row CG — verified PASS.
__global__ __launch_bounds__(1024) void k_cg_full(const float* __restrict__ cov,
                                                  const int* __restrict__ g, const int* __restrict__ cnt,
                                                  const int* __restrict__ off5, double* __restrict__ walloc) {
  int w = blockIdx.x;
  int s = w / NK, k = w % NK;
  int n = cnt[s * NK + k];
  if (n == 0) return;
  int off = off5[s * NK + k];
  const float* covS = cov + (size_t)s * NA * NA;
  __shared__ double pfull[NA];
  __shared__ double xv[NA], rv[NA], pv[NA], ap[NA];
  __shared__ int gs[NA];
  __shared__ double red16[16];
  int t = threadIdx.x, lane = t & 63, wid = t >> 6;
  if (t < n) {
    gs[t] = g[s * NA + off + t];
    xv[t] = 0.0; rv[t] = 1.0; pv[t] = 1.0;
  }
  double rr = (double)n;
  __syncthreads();
  for (int iter = 0; iter < 100; iter++) {
    pfull[t] = 0.0;
    __syncthreads();
    if (t < n) pfull[gs[t]] = pv[t];
    __syncthreads();
    for (int i = wid; i < n; i += 16) {
      const float* row = covS + (size_t)gs[i] * NA;
      double acc = 0.0;
#pragma unroll
      for (int c = 0; c < 16; c++) {
        int j = lane + (c << 6);
        acc += (double)row[j] * pfull[j];
      }
      acc = wave_reduce64(acc);
      if (lane == 0) ap[i] = acc;
    }
    __syncthreads();
    double pp = (t < n) ? pv[t] * ap[t] : 0.0;
    double pap = blk_sum_1024(pp, red16);
    double alpha = rr / pap;
    double rp = 0.0;
    if (t < n) {
      xv[t] += alpha * pv[t];
      double rn = rv[t] - alpha * ap[t];
      rv[t] = rn;
      rp = rn * rn;
    }
    double rrn = blk_sum_1024(rp, red16);
    if (rrn < 1e-20 * (double)n) break;
    double beta = rrn / rr;
    rr = rrn;
    if (t < n) pv[t] = rv[t] + beta * pv[t];
    __syncthreads();
  }
  double dp = (t < n) ? xv[t] : 0.0;
  double denom = blk_sum_1024(dp, red16);
  if (t < n) walloc[s * NA + gs[t]] = xv[t] / denom;
}

__global__ __launch_bounds__(256) void k_intery(const float* __restrict__ cov, const double* __restrict__ walloc,
                                                const int* __restrict__ g, const int* __restrict__ cnt,
                                                const int* __restrict__ off5, double* __restrict__ y2) {
  int w = blockIdx.x;  // 160
  int s = w / 20, rem = w % 20, k = rem / 4, seg = rem % 4;
  int n = cnt[s * NK + k], off = off5[s * NK + k];
  int t = threadIdx.x;
  __shared__ int gsl[NA];
  __shared__ double wl[NA];
  for (int i = t; i < n; i += 256) {
    int a = g[s * NA + off + i];
    gsl[i] = a;
    wl[i] = walloc[s * NA + a];
  }
  __syncthreads();
  int j = seg * 256 + t;
  const float* covS = cov + (size_t)s * NA * NA;
  double acc = 0.0;
  for (int i = 0; i < n; i++) acc += wl[i] * (double)covS[(size_t)gsl[i] * NA + j];
  y2[((size_t)s * NK + k) * NA + j] = acc;
}

__global__ __launch_bounds__(256) void k_icov(const double* __restrict__ y2, const double* __restrict__ walloc,
                                              const int* __restrict__ ixs, double* __restrict__ w_inter) {
  int s = blockIdx.x, t = threadIdx.x;
  __shared__ double red4[4];
  __shared__ double ic[NK * NK];
  for (int k = 0; k < NK; k++) {
    double p0 = 0, p1 = 0, p2 = 0, p3 = 0, p4 = 0;
    for (int j = t; j < NA; j += 256) {
      double v = y2[((size_t)s * NK + k) * NA + j] * walloc[s * NA + j];
      int c = ixs[s * NA + j];
      p0 += (c == 0) ? v : 0.0;
      p1 += (c == 1) ? v : 0.0;
      p2 += (c == 2) ? v : 0.0;
      p3 += (c == 3) ? v : 0.0;
      p4 += (c == 4) ? v : 0.0;
    }
    double q0 = blk_sum_256(p0, red4);
    double q1 = blk_sum_256(p1, red4);
    double q2 = blk_sum_256(p2, red4);
    double q3 = blk_sum_256(p3, red4);
    double q4 = blk_sum_256(p4, red4);
    if (t == 0) {
      ic[k * NK + 0] = q0; ic[k * NK + 1] = q1; ic[k * NK + 2] = q2;
      ic[k * NK + 3] = q3; ic[k * NK + 4] = q4;
    }
  }
  __syncthreads();
  if (t == 0) {
    double M[NK * NK], b[NK], z[NK];
    for (int i = 0; i < NK * NK; i++) M[i] = ic[i];
    for (int i = 0; i < NK; i++) b[i] = 1.0;
    for (int c = 0; c < NK; c++) {
      int pr = c;
      double mb = fabs(M[c * NK + c]);
      for (int r = c + 1; r < NK; r++) {
        double a = fabs(M[r * NK + c]);
        if (a > mb) { mb = a; pr = r; }
      }
      if (pr != c) {
        for (int cc = 0; cc < NK; cc++) {
          double tmp = M[c * NK + cc]; M[c * NK + cc] = M[pr * NK + cc]; M[pr * NK + cc] = tmp;
        }
        double tb = b[c]; b[c] = b[pr]; b[pr] = tb;
      }
      double piv = M[c * NK + c];
      for (int r = c + 1; r < NK; r++) {
        double f = M[r * NK + c] / piv;
        for (int cc = c; cc < NK; cc++) M[r * NK + cc] -= f * M[c * NK + cc];
        b[r] -= f * b[c];
      }
    }
    for (int r = NK - 1; r >= 0; r--) {
      double acc = b[r];
      for (int cc = r + 1; cc < NK; cc++) acc -= M[r * NK + cc] * z[cc];
      z[r] = acc / M[r * NK + r];
    }
    double ssum = z[0] + z[1] + z[2] + z[3] + z[4];
    for (int k = 0; k < NK; k++) w_inter[s * NK + k] = z[k] / ssum;
  }
}

__global__ __launch_bounds__(256) void k_final(const double* __restrict__ walloc, const double* __restrict__ w_inter,
                                               const int* __restrict__ ixs, float* __restrict__ out) {
  int gid = blockIdx.x * 256 + threadIdx.x;
  if (gid >= NS * NA) return;
  int s = gid >> 10;
  out[gid] = (float)(walloc[gid] * w_inter[s * NK + ixs[gid]]);
}

// ---------------- launch ----------------
extern "C" void kernel_launch(void* const* d_in, const int* in_sizes, int n_in,
                              void* d_out, int out_size, void* d_ws, size_t ws_size,
                              hipStream_t stream) {
  const float* cov = (const float*)d_in[0];
  float* out = (float*)d_out;
  char* ws = (char*)d_ws;
  size_t o = 0;
  auto alloc = [&](size_t bytes) {
    size_t cur = o;
    o += (bytes + 255) & ~(size_t)255;
    return cur;
  };
  double* C = (double*)(ws + alloc((size_t)NS * NK * NA * 8));
  double* y2 = (double*)(ws + alloc((size_t)NS * NK * NA * 8));
  double* pU = (double*)(ws + alloc((size_t)256 * NK * NA * 8));  // 10.5 MB partials
  double* rstd = (double*)(ws + alloc((size_t)NS * NA * 8));
  double* xn = (double*)(ws + alloc((size_t)NS * NA * 8));
  double* mind = (double*)(ws + alloc((size_t)NS * NA * 8));
  double* walloc = (double*)(ws + alloc((size_t)NS * NA * 8));
  int* ixs = (int*)(ws + alloc((size_t)NS * NA * 4));
  int* g = (int*)(ws + alloc((size_t)NS * NA * 4));
  int* cnt = (int*)(ws + alloc((size_t)NS * NK * 4));
  int* off5 = (int*)(ws + alloc((size_t)NS * NK * 4));
  int* boff = (int*)(ws + alloc((size_t)NS * NK * 4));
  int* conv = (int*)(ws + alloc((size_t)NS * 4));
  double* pot = (double*)(ws + alloc((size_t)NS * 8));
  double* w_inter = (double*)(ws + alloc((size_t)NS * NK * 8));
  size_t bcomp_off = alloc(NS * SSTRIDE * 4);  // 35.7 MB padded blocks, guarded
  float* Bcomp = (float*)(ws + bcomp_off);
  bool use_compact = (ws_size >= o);  // launch-time constant: same graph every call
  (void)in_sizes; (void)n_in; (void)out_size;

  InitIdx ii;
  compute_init_indices(ii);  // data-independent, identical every call

  k_pre<<<553, 256, 0, stream>>>(cov, rstd, xn, C, ii, pot, conv);
  for (int it = 0; it < MAXIT; it++) {
    k_assignA<<<256, 1024, 0, stream>>>(cov, rstd, xn, C, conv, ixs, mind, pU);
    k_updateB<<<32, 256, 0, stream>>>(pU, rstd, ixs, mind, C, pot, conv);
  }
  k_members<<<8, 256, 0, stream>>>(ixs, g, cnt, off5, boff);
  if (use_compact) {
    k_gatherB<<<40, 1024, 0, stream>>>(cov, g, cnt, off5, boff, Bcomp);
    k_cg_comp<<<40, 1024, 0, stream>>>(Bcomp, g, cnt, off5, boff, walloc);
  } else {
    k_cg_full<<<40, 1024, 0, stream>>>(cov, g, cnt, off5, walloc);
  }
  k_intery<<<160, 256, 0, stream>>>(cov, walloc, g, cnt, off5, y2);
  k_icov<<<8, 256, 0, stream>>>(y2, walloc, ixs, w_inter);
  k_final<<<32, 256, 0, stream>>>(walloc, w_inter, ixs, out);
}

// Round 7
// 1064.821 us; speedup vs baseline: 1.0075x; 1.0075x over previous
//
#include <hip/hip_runtime.h>
#include <stdint.h>
#include <math.h>
#include <algorithm>

#define NS 8
#define NA 1024
#define NK 5
#define MAXIT 30
#define TOLER 1e-5
#define SSTRIDE ((size_t)NA * NA + 64 * NA)  // padded per-sample Bcomp stride (floats)

// ---------------- host-side threefry-2x32 (JAX-compatible) ----------------
static inline void tf2x32(uint32_t k0, uint32_t k1, uint32_t c0, uint32_t c1,
                          uint32_t& o0, uint32_t& o1) {
  uint32_t ks2 = k0 ^ k1 ^ 0x1BD11BDAu;
  uint32_t x0 = c0 + k0, x1 = c1 + k1;
  auto rot = [](uint32_t x, int r) { return (x << r) | (x >> (32 - r)); };
  auto R4 = [&](int r0, int r1, int r2, int r3) {
    x0 += x1; x1 = rot(x1, r0); x1 ^= x0;
    x0 += x1; x1 = rot(x1, r1); x1 ^= x0;
    x0 += x1; x1 = rot(x1, r2); x1 ^= x0;
    x0 += x1; x1 = rot(x1, r3); x1 ^= x0;
  };
  R4(13, 15, 26, 6);  x0 += k1;  x1 += ks2 + 1u;
  R4(17, 29, 16, 24); x0 += ks2; x1 += k0 + 2u;
  R4(13, 15, 26, 6);  x0 += k0;  x1 += k1 + 3u;
  R4(17, 29, 16, 24); x0 += k1;  x1 += ks2 + 4u;
  R4(13, 15, 26, 6);  x0 += ks2; x1 += k0 + 5u;
  o0 = x0; o1 = x1;
}

struct InitIdx { int v[NS * NK]; };

// jax_threefry_partitionable=True semantics (verified R3/R5-R8: PASS)
static void compute_init_indices(InitIdx& out) {
  const uint32_t rk0 = 0, rk1 = 42;
  for (int s = 0; s < NS; s++) {
    uint32_t k0, k1;
    tf2x32(rk0, rk1, 0u, (uint32_t)s, k0, k1);
    uint32_t sk0, sk1;
    tf2x32(k0, k1, 0u, 1u, sk0, sk1);
    uint32_t bits[NA];
    for (int i = 0; i < NA; i++) {
      uint32_t b0, b1;
      tf2x32(sk0, sk1, 0u, (uint32_t)i, b0, b1);
      bits[i] = b0 ^ b1;
    }
    int idx[NA];
    for (int i = 0; i < NA; i++) idx[i] = i;
    std::stable_sort(idx, idx + NA, [&](int x, int y) { return bits[x] < bits[y]; });
    for (int c = 0; c < NK; c++) out.v[s * NK + c] = idx[c];
  }
}

// ---------------- device helpers ----------------
__device__ __forceinline__ double wave_reduce64(double v) {
#pragma unroll
  for (int m = 32; m > 0; m >>= 1) v += __shfl_xor(v, m, 64);
  return v;
}

__device__ __forceinline__ double blk_sum_1024(double v, double* red16) {
  double w = wave_reduce64(v);
  if ((threadIdx.x & 63) == 0) red16[threadIdx.x >> 6] = w;
  __syncthreads();
  double tot = 0.0;
#pragma unroll
  for (int i = 0; i < 16; i++) tot += red16[i];
  __syncthreads();
  return tot;
}

__device__ __forceinline__ double blk_sum_256(double v, double* red4) {
  double w = wave_reduce64(v);
  if ((threadIdx.x & 63) == 0) red4[threadIdx.x >> 6] = w;
  __syncthreads();
  double tot = red4[0] + red4[1] + red4[2] + red4[3];
  __syncthreads();
  return tot;
}

// Fused dual block-sum (1024 thr): one LDS pass, one barrier pair, deterministic.
__device__ __forceinline__ void blk_sum2_1024(double a, double b, double* redA, double* redB,
                                              double& ra, double& rb) {
#pragma unroll
  for (int m = 32; m > 0; m >>= 1) {
    a += __shfl_xor(a, m, 64);
    b += __shfl_xor(b, m, 64);
  }
  if ((threadIdx.x & 63) == 0) {
    redA[threadIdx.x >> 6] = a;
    redB[threadIdx.x >> 6] = b;
  }
  __syncthreads();
  ra = 0.0; rb = 0.0;
#pragma unroll
  for (int i = 0; i < 16; i++) { ra += redA[i]; rb += redB[i]; }
  __syncthreads();
}

// ---------------- fused pre-kernel: xn + centers_init + rstd array + state ----------------
// blocks 0..511: xn (inline rstd); 512..551: centers_init; 552: rstd[]+pot+conv.
__global__ __launch_bounds__(256) void k_pre(const float* __restrict__ cov, double* __restrict__ rstd,
                                             double* __restrict__ xn, double* __restrict__ C,
                                             InitIdx ii, double* __restrict__ pot, int* __restrict__ conv) {
  int w = blockIdx.x;
  if (w < 512) {
    int s = w >> 6;
    __shared__ double rsh[NA];
    const float* covS = cov + (size_t)s * NA * NA;
    for (int j = threadIdx.x; j < NA; j += 256)
      rsh[j] = 1.0 / sqrt((double)covS[(size_t)j * NA + j]);
    __syncthreads();
    int lane = threadIdx.x & 63, wave = threadIdx.x >> 6;
    for (int q = 0; q < 4; q++) {
      int i = (w & 63) * 16 + wave * 4 + q;
      const float* row = covS + (size_t)i * NA;
      double acc = 0.0;
      for (int j = lane; j < NA; j += 64) {
        double v = (double)row[j] * rsh[j];
        acc += v * v;
      }
      acc = wave_reduce64(acc);
      if (lane == 0) {
        double ri = rsh[i];
        xn[s * NA + i] = acc * ri * ri;
      }
    }
  } else if (w < 552) {
    int w2 = w - 512;
    int s = w2 / NK, k = w2 % NK;
    int idx = ii.v[s * NK + k];
    const float* covS = cov + (size_t)s * NA * NA;
    double ri = 1.0 / sqrt((double)covS[(size_t)idx * NA + idx]);
    const float* row = covS + (size_t)idx * NA;
    for (int j = threadIdx.x; j < NA; j += 256) {
      double rj = 1.0 / sqrt((double)covS[(size_t)j * NA + j]);
      C[((size_t)s * NK + k) * NA + j] = (double)row[j] * ri * rj;
    }
  } else {
    int t = threadIdx.x;
    for (int gid = t; gid < NS * NA; gid += 256) {
      int s = gid >> 10, a = gid & 1023;
      rstd[gid] = 1.0 / sqrt((double)cov[(size_t)s * NA * NA + (size_t)a * NA + a]);
    }
    if (t < NS) { pot[t] = INFINITY; conv[t] = 0; }
  }
}

// ---------------- KMeans iteration: 2 launches, fused single cov pass ----------------
__global__ __launch_bounds__(1024) void k_assignA(const float* __restrict__ cov, const double* __restrict__ rstd,
                                                  const double* __restrict__ xn, const double* __restrict__ C,
                                                  const int* __restrict__ conv, int* __restrict__ ixs,
                                                  double* __restrict__ mind, double* __restrict__ pU) {
  int blk = blockIdx.x, s = blk >> 5, rblk = blk & 31;
  if (conv[s]) return;  // frozen: coherent via kernel-boundary ordering
  __shared__ double Cs[NK][NA];  // rstd_j-scaled centers, 40 KB
  __shared__ double red16[16];
  __shared__ int bks[32];
  __shared__ double rloc[32];
  int t = threadIdx.x, lane = t & 63, wid = t >> 6;
  double rj = rstd[s * NA + t];
  double sq[NK];
#pragma unroll
  for (int k = 0; k < NK; k++) {
    double c = C[((size_t)s * NK + k) * NA + t];
    Cs[k][t] = c * rj;
    sq[k] = c * c;
  }
  double cn[NK];
#pragma unroll
  for (int k = 0; k < NK; k++) cn[k] = blk_sum_1024(sq[k], red16);
  const float* covS = cov + (size_t)s * NA * NA;
#pragma unroll
  for (int r2 = 0; r2 < 2; r2++) {
    int il = wid * 2 + r2;          // 0..31
    int i = rblk * 32 + il;
    const float* row = covS + (size_t)i * NA;
    double xi = xn[s * NA + i];
    double ri = rstd[s * NA + i];
    double a0 = 0, a1 = 0, a2 = 0, a3 = 0, a4 = 0;
#pragma unroll
    for (int c = 0; c < 16; c++) {
      int j = lane + (c << 6);
      double cv = (double)row[j];
      a0 += cv * Cs[0][j]; a1 += cv * Cs[1][j]; a2 += cv * Cs[2][j];
      a3 += cv * Cs[3][j]; a4 += cv * Cs[4][j];
    }
    a0 = wave_reduce64(a0); a1 = wave_reduce64(a1); a2 = wave_reduce64(a2);
    a3 = wave_reduce64(a3); a4 = wave_reduce64(a4);
    if (lane == 0) {
      double dots[5] = {a0, a1, a2, a3, a4};
      double best = INFINITY;
      int bk = 0;
#pragma unroll
      for (int k = 0; k < NK; k++) {
        double d = xi + cn[k] - 2.0 * ri * dots[k];
        if (d < 0.0) d = 0.0;
        if (d < best) { best = d; bk = k; }  // first-min like jnp.argmin
      }
      ixs[s * NA + i] = bk;
      mind[s * NA + i] = best;
      bks[il] = bk;
      rloc[il] = ri;
    }
  }
  __syncthreads();
  // partial center sums: thread t owns column t; ascending il -> deterministic
  double c0 = 0, c1 = 0, c2 = 0, c3 = 0, c4 = 0;
#pragma unroll
  for (int il = 0; il < 32; il++) {
    int i = rblk * 32 + il;
    double v = (double)covS[(size_t)i * NA + t] * rloc[il];  // L2-hot coalesced re-read
    int k = bks[il];
    c0 += (k == 0) ? v : 0.0;
    c1 += (k == 1) ? v : 0.0;
    c2 += (k == 2) ? v : 0.0;
    c3 += (k == 3) ? v : 0.0;
    c4 += (k == 4) ? v : 0.0;
  }
  double* p = pU + ((size_t)blk * NK) * NA;
  p[0 * NA + t] = c0; p[1 * NA + t] = c1; p[2 * NA + t] = c2;
  p[3 * NA + t] = c3; p[4 * NA + t] = c4;
}

__global__ __launch_bounds__(256) void k_updateB(const double* __restrict__ pU, const double* __restrict__ rstd,
                                                 const int* __restrict__ ixs, const double* __restrict__ mind,
                                                 double* __restrict__ C, double* __restrict__ pot,
                                                 int* __restrict__ conv) {
  int w = blockIdx.x, s = w >> 2, seg = w & 3, t = threadIdx.x;
  if (conv[s]) return;
  __shared__ double red4[4];
  double lc[NK] = {0, 0, 0, 0, 0};
#pragma unroll
  for (int q = 0; q < 4; q++) {
    int c = ixs[s * NA + q * 256 + t];
    lc[0] += (c == 0) ? 1.0 : 0.0;
    lc[1] += (c == 1) ? 1.0 : 0.0;
    lc[2] += (c == 2) ? 1.0 : 0.0;
    lc[3] += (c == 3) ? 1.0 : 0.0;
    lc[4] += (c == 4) ? 1.0 : 0.0;
  }
  double cntk[NK];
#pragma unroll
  for (int k = 0; k < NK; k++) cntk[k] = blk_sum_256(lc[k], red4);
  int j = seg * 256 + t;
  double rjj = rstd[s * NA + j];
  double* CS = C + (size_t)s * NK * NA;
#pragma unroll
  for (int k = 0; k < NK; k++) {
    double a = 0.0;
#pragma unroll
    for (int b = 0; b < 32; b++) {  // ascending b == ascending i: deterministic
      int blk = (s << 5) | b;
      a += pU[((size_t)blk * NK + k) * NA + j];
    }
    if (cntk[k] > 0.0) CS[(size_t)k * NA + j] = a * rjj / cntk[k];
    // empty cluster: keep previous center
  }
  if (seg == 0) {
    double v = mind[s * NA + t] + mind[s * NA + 256 + t] +
               mind[s * NA + 512 + t] + mind[s * NA + 768 + t];
    double p = blk_sum_256(v, red4);
    if (t == 0) {
      double prev = pot[s];
      pot[s] = p;
      if (!(fabs(p - prev) >= TOLER)) conv[s] = 1;  // freeze (while-cond fails)
    }
  }
}

// ---------------- post-processing ----------------
__global__ __launch_bounds__(256) void k_members(const int* __restrict__ ixs, int* __restrict__ g,
                                                 int* __restrict__ cnt, int* __restrict__ off5,
                                                 int* __restrict__ boff) {
  int s = blockIdx.x, t = threadIdx.x;
  __shared__ int sc[NK][256];
  __shared__ int base[NK];
  const int* ix = ixs + s * NA;
  int my[4];
  int lc[NK] = {0, 0, 0, 0, 0};
#pragma unroll
  for (int q = 0; q < 4; q++) { my[q] = ix[t * 4 + q]; lc[my[q]]++; }
#pragma unroll
  for (int k = 0; k < NK; k++) sc[k][t] = lc[k];
  __syncthreads();
  for (int off = 1; off < 256; off <<= 1) {
    int v[NK];
#pragma unroll
    for (int k = 0; k < NK; k++) v[k] = (t >= off) ? sc[k][t - off] : 0;
    __syncthreads();
#pragma unroll
    for (int k = 0; k < NK; k++) sc[k][t] += v[k];
    __syncthreads();
  }
  if (t == 0) {
    int b = 0, bo = 0;
    for (int k = 0; k < NK; k++) {
      int tot = sc[k][255];
      base[k] = b;
      cnt[s * NK + k] = tot;
      off5[s * NK + k] = b;
      boff[s * NK + k] = bo;
      b += tot;
      bo += tot * ((tot + 63) & ~63);  // padded: lda = align64(n)
    }
  }
  __syncthreads();
  int pos[NK];
#pragma unroll
  for (int k = 0; k < NK; k++) pos[k] = base[k] + sc[k][t] - lc[k];
#pragma unroll
  for (int q = 0; q < 4; q++) {
    int k = my[q];
    int p = pos[k]++;
    g[s * NA + p] = t * 4 + q;  // stable ascending asset order within cluster
  }
}

// Compact gather, PADDED: lda = align64(n), zero-filled COLUMN pad, rows i<n
// only (R6 post-mortem: writing pad rows overflowed the n*lda per-cluster
// allocation into the next cluster's block -> data race -> absmax 2e-2).
__global__ __launch_bounds__(1024) void k_gatherB(const float* __restrict__ cov, const int* __restrict__ g,
                                                  const int* __restrict__ cnt, const int* __restrict__ off5,
                                                  const int* __restrict__ boff, float* __restrict__ B) {
  int w = blockIdx.x;  // 40
  int s = w / NK, k = w % NK;
  int n = cnt[s * NK + k];
  if (n == 0) return;
  int lda = (n + 63) & ~63;
  int off = off5[s * NK + k];
  __shared__ int gs[NA];
  int t = threadIdx.x, lane = t & 63, wid = t >> 6;
  if (t < n) gs[t] = g[s * NA + off + t];
  __syncthreads();
  const float* covS = cov + (size_t)s * NA * NA;
  float* Bk = B + (size_t)s * SSTRIDE + (size_t)boff[s * NK + k];
  for (int i = wid; i < n; i += 16) {
    const float* row = covS + (size_t)gs[i] * NA;
    float* out = Bk + (size_t)i * lda;
    for (int j = lane; j < lda; j += 64) out[j] = (j < n) ? row[gs[j]] : 0.0f;
  }
}

// Chronopoulos-Gear CG on padded compact block. Sigma_cc x = 1.
// R5 post-mortem: bottleneck is the per-row 64-lane f64 butterfly (~192
// ds_bpermute/thread/matvec), not loads. n<=256 path exploits SYMMETRY
// (B[i][j]=B[j][i]): w_i = sum_j A[j][i] r_j, j iterated with a UNIFORM
// runtime bound nrem = min(64, n - jbeg) (no pad-row reads -> stays inside
// the n*lda allocation; fixes R6's overflow), i = coalesced column index ->
// per-output register accumulation, zero cross-lane reduce in the matvec.
// CG state in owner-thread registers; 3 barriers/iter; ~24 bpermutes/iter.
// Deterministic (ascending j, fixed chunk-combine order). n>256 falls back
// to the verified global-load path.
__global__ __launch_bounds__(1024) void k_cg_comp(const float* __restrict__ B, const int* __restrict__ g,
                                                  const int* __restrict__ cnt, const int* __restrict__ off5,
                                                  const int* __restrict__ boff, double* __restrict__ walloc) {
  int w = blockIdx.x;  // 40
  int s = w / NK, k = w % NK;
  int n = cnt[s * NK + k];
  if (n == 0) return;
  int lda = (n + 63) & ~63;
  int nch = lda >> 6;
  int off = off5[s * NK + k];
  const float* A = B + (size_t)s * SSTRIDE + (size_t)boff[s * NK + k];
  __shared__ double xv[NA], rv[NA], pv[NA], sv[NA], wv[NA];
  __shared__ int gs[NA];
  __shared__ double redA[16], redB[16];
  __shared__ __align__(16) double rvs[256];
  __shared__ double pw[4][256];
  __shared__ double redC[4], redD[4];
  int t = threadIdx.x, lane = t & 63, wid = t >> 6;
  const double tol = 1e-10 * (double)n;  // rel resid 1e-5: err ~ kappa*1e-5*|w| << floor

  if (n <= 256) {
    // -------- symmetric column-coalesced matvec, no cross-lane reduce --------
    int ic = t & 255, gchunk = t >> 8;   // output column, j-chunk (0..3)
    int jbeg = gchunk << 6;
    bool owner = (t < 256);
    int nrem = n - jbeg;                 // rows in this chunk (uniform per chunk)
    if (nrem > 64) nrem = 64;
    bool act = (ic < lda) && (nrem > 0);
    const float* colp = A + (size_t)jbeg * lda + ic;  // only deref'd when act

#define MV_SYM()                                                            \
    do {                                                                    \
      double part_ = 0.0;                                                   \
      if (act) {                                                            \
        _Pragma("unroll 8")                                                 \
        for (int u_ = 0; u_ < nrem; u_++)                                   \
          part_ += (double)colp[(size_t)u_ * lda] * rvs[jbeg + u_];         \
      }                                                                     \
      pw[gchunk][ic] = part_;                                               \
    } while (0)

    // owner-register CG state
    double xr = 0.0, rr = 0.0, pr = 0.0, sr = 0.0, wr = 0.0;
    int gi = 0;
    if (owner) {
      rr = (ic < n) ? 1.0 : 0.0;
      if (ic < n) gi = g[s * NA + off + ic];
      rvs[ic] = rr;
    }
    __syncthreads();

    // w = A r (r = 1)
    MV_SYM();
    __syncthreads();
    if (owner) {
      wr = ((pw[0][ic] + pw[1][ic]) + pw[2][ic]) + pw[3][ic];
      double g1 = 0.0, g2 = 0.0;
      if (ic < n) { g1 = rr * rr; g2 = rr * wr; }
#pragma unroll
      for (int m = 32; m > 0; m >>= 1) {
        g1 += __shfl_xor(g1, m, 64);
        g2 += __shfl_xor(g2, m, 64);
      }
      if (lane == 0) { redC[wid] = g1; redD[wid] = g2; }
    }
    __syncthreads();
    double gam = (double)n;
    double d1 = ((redD[0] + redD[1]) + redD[2]) + redD[3];  // (w,r), r=1
    double alpha = gam / d1;
    if (owner && ic < n) { pr = rr; sr = wr; }

    for (int iter = 0; iter < 50; iter++) {
      if (owner && ic < n) {
        xr += alpha * pr;
        rr -= alpha * sr;
        rvs[ic] = rr;
      }
      __syncthreads();      // rvs ready
      MV_SYM();
      __syncthreads();      // pw ready
      if (owner) {
        wr = ((pw[0][ic] + pw[1][ic]) + pw[2][ic]) + pw[3][ic];
        double g1 = 0.0, g2 = 0.0;
        if (ic < n) { g1 = rr * rr; g2 = rr * wr; }
#pragma unroll
        for (int m = 32; m > 0; m >>= 1) {
          g1 += __shfl_xor(g1, m, 64);
          g2 += __shfl_xor(g2, m, 64);
        }
        if (lane == 0) { redC[wid] = g1; redD[wid] = g2; }
      }
      __syncthreads();      // red ready
      double gamn = ((redC[0] + redC[1]) + redC[2]) + redC[3];
      double delt = ((redD[0] + redD[1]) + redD[2]) + redD[3];
      if (gamn < tol) break;  // uniform across block
      double beta = gamn / gam;
      alpha = gamn / (delt - beta * gamn / alpha);
      gam = gamn;
      if (owner && ic < n) {
        pr = rr + beta * pr;
        sr = wr + beta * sr;
      }
    }
    __syncthreads();  // protect redC reuse (all (g)-phase readers done)
    if (owner) {
      double dp = (ic < n) ? xr : 0.0;
#pragma unroll
      for (int m = 32; m > 0; m >>= 1) dp += __shfl_xor(dp, m, 64);
      if (lane == 0) redC[wid] = dp;
    }
    __syncthreads();
    double denom = ((redC[0] + redC[1]) + redC[2]) + redC[3];
    if (owner && ic < n) walloc[s * NA + gi] = xr / denom;
#undef MV_SYM
  } else {
    // -------- fallback: global-load matvec (verified path) --------
    if (t < n) gs[t] = g[s * NA + off + t];
    rv[t] = (t < n) ? 1.0 : 0.0;  // pad region zeroed: matvec reads rv up to lda
    if (t < n) xv[t] = 0.0;
    __syncthreads();
    // w = A r
    for (int i = wid; i < n; i += 16) {
      const float* row = A + (size_t)i * lda;
      double acc = 0.0;
      for (int c = 0; c < nch; c++) {
        int j = lane + (c << 6);
        acc += (double)row[j] * rv[j];
      }
      acc = wave_reduce64(acc);
      if (lane == 0) wv[i] = acc;
    }
    __syncthreads();
    double gam = (double)n;  // (r,r) with r=1
    double d1, d2;
    blk_sum2_1024((t < n) ? wv[t] : 0.0, 0.0, redA, redB, d1, d2);  // (w,r) with r=1
    double alpha = gam / d1;
    if (t < n) { pv[t] = rv[t]; sv[t] = wv[t]; }
    for (int iter = 0; iter < 50; iter++) {
      if (t < n) {
        xv[t] += alpha * pv[t];
        rv[t] -= alpha * sv[t];
      }
      __syncthreads();
      // w = A r
      for (int i = wid; i < n; i += 16) {
        const float* row = A + (size_t)i * lda;
        double acc = 0.0;
        for (int c = 0; c < nch; c++) {
          int j = lane + (c << 6);
          acc += (double)row[j] * rv[j];
        }
        acc = wave_reduce64(acc);
        if (lane == 0) wv[i] = acc;
      }
      __syncthreads();
      double g1 = 0.0, g2 = 0.0;
      if (t < n) {
        double rt = rv[t];
        g1 = rt * rt;
        g2 = rt * wv[t];
      }
      double gamn, delt;
      blk_sum2_1024(g1, g2, redA, redB, gamn, delt);
      if (gamn < tol) break;  // uniform across block
      double beta = gamn / gam;
      alpha = gamn / (delt - beta * gamn / alpha);
      gam = gamn;
      if (t < n) {
        pv[t] = rv[t] + beta * pv[t];
        sv[t] = wv[t] + beta * sv[t];
      }
    }
    double dp = (t < n) ? xv[t] : 0.0;
    double d3, d4;
    blk_sum2_1024(dp, 0.0, redA, redB, d3, d4);
    if (t < n) walloc[s * NA + gs[t]] = xv[t] / d3;
  }
}

// Fallback (ws too small for compact B): R5's full-row CG — verified PASS.
__global__ __launch_bounds__(1024) void k_cg_full(const float* __restrict__ cov,
                                                  const int* __restrict__ g, const int* __restrict__ cnt,
                                                  const int* __restrict__ off5, double* __restrict__ walloc) {
  int w = blockIdx.x;
  int s = w / NK, k = w % NK;
  int n = cnt[s * NK + k];
  if (n == 0) return;
  int off = off5[s * NK + k];
  const float* covS = cov + (size_t)s * NA * NA;
  __shared__ double pfull[NA];
  __shared__ double xv[NA], rv[NA], pv[NA], ap[NA];
  __shared__ int gs[NA];
  __shared__ double red16[16];
  int t = threadIdx.x, lane = t & 63, wid = t >> 6;
  if (t < n) {
    gs[t] = g[s * NA + off + t];
    xv[t] = 0.0; rv[t] = 1.0; pv[t] = 1.0;
  }
  double rr = (double)n;
  __syncthreads();
  for (int iter = 0; iter < 100; iter++) {
    pfull[t] = 0.0;
    __syncthreads();
    if (t < n) pfull[gs[t]] = pv[t];
    __syncthreads();
    for (int i = wid; i < n; i += 16) {
      const float* row = covS + (size_t)gs[i] * NA;
      double acc = 0.0;
#pragma unroll
      for (int c = 0; c < 16; c++) {
        int j = lane + (c << 6);
        acc += (double)row[j] * pfull[j];
      }
      acc = wave_reduce64(acc);
      if (lane == 0) ap[i] = acc;
    }
    __syncthreads();
    double pp = (t < n) ? pv[t] * ap[t] : 0.0;
    double pap = blk_sum_1024(pp, red16);
    double alpha = rr / pap;
    double rp = 0.0;
    if (t < n) {
      xv[t] += alpha * pv[t];
      double rn = rv[t] - alpha * ap[t];
      rv[t] = rn;
      rp = rn * rn;
    }
    double rrn = blk_sum_1024(rp, red16);
    if (rrn < 1e-20 * (double)n) break;
    double beta = rrn / rr;
    rr = rrn;
    if (t < n) pv[t] = rv[t] + beta * pv[t];
    __syncthreads();
  }
  double dp = (t < n) ? xv[t] : 0.0;
  double denom = blk_sum_1024(dp, red16);
  if (t < n) walloc[s * NA + gs[t]] = xv[t] / denom;
}

__global__ __launch_bounds__(256) void k_intery(const float* __restrict__ cov, const double* __restrict__ walloc,
                                                const int* __restrict__ g, const int* __restrict__ cnt,
                                                const int* __restrict__ off5, double* __restrict__ y2) {
  int w = blockIdx.x;  // 160
  int s = w / 20, rem = w % 20, k = rem / 4, seg = rem % 4;
  int n = cnt[s * NK + k], off = off5[s * NK + k];
  int t = threadIdx.x;
  __shared__ int gsl[NA];
  __shared__ double wl[NA];
  for (int i = t; i < n; i += 256) {
    int a = g[s * NA + off + i];
    gsl[i] = a;
    wl[i] = walloc[s * NA + a];
  }
  __syncthreads();
  int j = seg * 256 + t;
  const float* covS = cov + (size_t)s * NA * NA;
  double acc = 0.0;
  for (int i = 0; i < n; i++) acc += wl[i] * (double)covS[(size_t)gsl[i] * NA + j];
  y2[((size_t)s * NK + k) * NA + j] = acc;
}

__global__ __launch_bounds__(256) void k_icov(const double* __restrict__ y2, const double* __restrict__ walloc,
                                              const int* __restrict__ ixs, double* __restrict__ w_inter) {
  int s = blockIdx.x, t = threadIdx.x;
  __shared__ double red4[4];
  __shared__ double ic[NK * NK];
  for (int k = 0; k < NK; k++) {
    double p0 = 0, p1 = 0, p2 = 0, p3 = 0, p4 = 0;
    for (int j = t; j < NA; j += 256) {
      double v = y2[((size_t)s * NK + k) * NA + j] * walloc[s * NA + j];
      int c = ixs[s * NA + j];
      p0 += (c == 0) ? v : 0.0;
      p1 += (c == 1) ? v : 0.0;
      p2 += (c == 2) ? v : 0.0;
      p3 += (c == 3) ? v : 0.0;
      p4 += (c == 4) ? v : 0.0;
    }
    double q0 = blk_sum_256(p0, red4);
    double q1 = blk_sum_256(p1, red4);
    double q2 = blk_sum_256(p2, red4);
    double q3 = blk_sum_256(p3, red4);
    double q4 = blk_sum_256(p4, red4);
    if (t == 0) {
      ic[k * NK + 0] = q0; ic[k * NK + 1] = q1; ic[k * NK + 2] = q2;
      ic[k * NK + 3] = q3; ic[k * NK + 4] = q4;
    }
  }
  __syncthreads();
  if (t == 0) {
    double M[NK * NK], b[NK], z[NK];
    for (int i = 0; i < NK * NK; i++) M[i] = ic[i];
    for (int i = 0; i < NK; i++) b[i] = 1.0;
    for (int c = 0; c < NK; c++) {
      int pr = c;
      double mb = fabs(M[c * NK + c]);
      for (int r = c + 1; r < NK; r++) {
        double a = fabs(M[r * NK + c]);
        if (a > mb) { mb = a; pr = r; }
      }
      if (pr != c) {
        for (int cc = 0; cc < NK; cc++) {
          double tmp = M[c * NK + cc]; M[c * NK + cc] = M[pr * NK + cc]; M[pr * NK + cc] = tmp;
        }
        double tb = b[c]; b[c] = b[pr]; b[pr] = tb;
      }
      double piv = M[c * NK + c];
      for (int r = c + 1; r < NK; r++) {
        double f = M[r * NK + c] / piv;
        for (int cc = c; cc < NK; cc++) M[r * NK + cc] -= f * M[c * NK + cc];
        b[r] -= f * b[c];
      }
    }
    for (int r = NK - 1; r >= 0; r--) {
      double acc = b[r];
      for (int cc = r + 1; cc < NK; cc++) acc -= M[r * NK + cc] * z[cc];
      z[r] = acc / M[r * NK + r];
    }
    double ssum = z[0] + z[1] + z[2] + z[3] + z[4];
    for (int k = 0; k < NK; k++) w_inter[s * NK + k] = z[k] / ssum;
  }
}

__global__ __launch_bounds__(256) void k_final(const double* __restrict__ walloc, const double* __restrict__ w_inter,
                                               const int* __restrict__ ixs, float* __restrict__ out) {
  int gid = blockIdx.x * 256 + threadIdx.x;
  if (gid >= NS * NA) return;
  int s = gid >> 10;
  out[gid] = (float)(walloc[gid] * w_inter[s * NK + ixs[gid]]);
}

// ---------------- launch ----------------
extern "C" void kernel_launch(void* const* d_in, const int* in_sizes, int n_in,
                              void* d_out, int out_size, void* d_ws, size_t ws_size,
                              hipStream_t stream) {
  const float* cov = (const float*)d_in[0];
  float* out = (float*)d_out;
  char* ws = (char*)d_ws;
  size_t o = 0;
  auto alloc = [&](size_t bytes) {
    size_t cur = o;
    o += (bytes + 255) & ~(size_t)255;
    return cur;
  };
  double* C = (double*)(ws + alloc((size_t)NS * NK * NA * 8));
  double* y2 = (double*)(ws + alloc((size_t)NS * NK * NA * 8));
  double* pU = (double*)(ws + alloc((size_t)256 * NK * NA * 8));  // 10.5 MB partials
  double* rstd = (double*)(ws + alloc((size_t)NS * NA * 8));
  double* xn = (double*)(ws + alloc((size_t)NS * NA * 8));
  double* mind = (double*)(ws + alloc((size_t)NS * NA * 8));
  double* walloc = (double*)(ws + alloc((size_t)NS * NA * 8));
  int* ixs = (int*)(ws + alloc((size_t)NS * NA * 4));
  int* g = (int*)(ws + alloc((size_t)NS * NA * 4));
  int* cnt = (int*)(ws + alloc((size_t)NS * NK * 4));
  int* off5 = (int*)(ws + alloc((size_t)NS * NK * 4));
  int* boff = (int*)(ws + alloc((size_t)NS * NK * 4));
  int* conv = (int*)(ws + alloc((size_t)NS * 4));
  double* pot = (double*)(ws + alloc((size_t)NS * 8));
  double* w_inter = (double*)(ws + alloc((size_t)NS * NK * 8));
  size_t bcomp_off = alloc(NS * SSTRIDE * 4);  // 35.7 MB padded blocks, guarded
  float* Bcomp = (float*)(ws + bcomp_off);
  bool use_compact = (ws_size >= o);  // launch-time constant: same graph every call
  (void)in_sizes; (void)n_in; (void)out_size;

  InitIdx ii;
  compute_init_indices(ii);  // data-independent, identical every call

  k_pre<<<553, 256, 0, stream>>>(cov, rstd, xn, C, ii, pot, conv);
  for (int it = 0; it < MAXIT; it++) {
    k_assignA<<<256, 1024, 0, stream>>>(cov, rstd, xn, C, conv, ixs, mind, pU);
    k_updateB<<<32, 256, 0, stream>>>(pU, rstd, ixs, mind, C, pot, conv);
  }
  k_members<<<8, 256, 0, stream>>>(ixs, g, cnt, off5, boff);
  if (use_compact) {
    k_gatherB<<<40, 1024, 0, stream>>>(cov, g, cnt, off5, boff, Bcomp);
    k_cg_comp<<<40, 1024, 0, stream>>>(Bcomp, g, cnt, off5, boff, walloc);
  } else {
    k_cg_full<<<40, 1024, 0, stream>>>(cov, g, cnt, off5, walloc);
  }
  k_intery<<<160, 256, 0, stream>>>(cov, walloc, g, cnt, off5, y2);
  k_icov<<<8, 256, 0, stream>>>(y2, walloc, ixs, w_inter);
  k_final<<<32, 256, 0, stream>>>(walloc, w_inter, ixs, out);
}

// Round 8
// 1011.215 us; speedup vs baseline: 1.0609x; 1.0530x over previous
//
#include <hip/hip_runtime.h>
#include <stdint.h>
#include <math.h>
#include <algorithm>

#define NS 8
#define NA 1024
#define NK 5
#define MAXIT 30
#define TOLER 1e-5
#define SSTRIDE ((size_t)NA * NA + 64 * NA)  // padded per-sample Bcomp stride (floats)

// ---------------- host-side threefry-2x32 (JAX-compatible) ----------------
static inline void tf2x32(uint32_t k0, uint32_t k1, uint32_t c0, uint32_t c1,
                          uint32_t& o0, uint32_t& o1) {
  uint32_t ks2 = k0 ^ k1 ^ 0x1BD11BDAu;
  uint32_t x0 = c0 + k0, x1 = c1 + k1;
  auto rot = [](uint32_t x, int r) { return (x << r) | (x >> (32 - r)); };
  auto R4 = [&](int r0, int r1, int r2, int r3) {
    x0 += x1; x1 = rot(x1, r0); x1 ^= x0;
    x0 += x1; x1 = rot(x1, r1); x1 ^= x0;
    x0 += x1; x1 = rot(x1, r2); x1 ^= x0;
    x0 += x1; x1 = rot(x1, r3); x1 ^= x0;
  };
  R4(13, 15, 26, 6);  x0 += k1;  x1 += ks2 + 1u;
  R4(17, 29, 16, 24); x0 += ks2; x1 += k0 + 2u;
  R4(13, 15, 26, 6);  x0 += k0;  x1 += k1 + 3u;
  R4(17, 29, 16, 24); x0 += k1;  x1 += ks2 + 4u;
  R4(13, 15, 26, 6);  x0 += ks2; x1 += k0 + 5u;
  o0 = x0; o1 = x1;
}

struct InitIdx { int v[NS * NK]; };

// jax_threefry_partitionable=True semantics (verified R3/R5-R8: PASS)
static void compute_init_indices(InitIdx& out) {
  const uint32_t rk0 = 0, rk1 = 42;
  for (int s = 0; s < NS; s++) {
    uint32_t k0, k1;
    tf2x32(rk0, rk1, 0u, (uint32_t)s, k0, k1);
    uint32_t sk0, sk1;
    tf2x32(k0, k1, 0u, 1u, sk0, sk1);
    uint32_t bits[NA];
    for (int i = 0; i < NA; i++) {
      uint32_t b0, b1;
      tf2x32(sk0, sk1, 0u, (uint32_t)i, b0, b1);
      bits[i] = b0 ^ b1;
    }
    int idx[NA];
    for (int i = 0; i < NA; i++) idx[i] = i;
    std::stable_sort(idx, idx + NA, [&](int x, int y) { return bits[x] < bits[y]; });
    for (int c = 0; c < NK; c++) out.v[s * NK + c] = idx[c];
  }
}

// ---------------- device helpers ----------------
__device__ __forceinline__ double wave_reduce64(double v) {
#pragma unroll
  for (int m = 32; m > 0; m >>= 1) v += __shfl_xor(v, m, 64);
  return v;
}

__device__ __forceinline__ double blk_sum_1024(double v, double* red16) {
  double w = wave_reduce64(v);
  if ((threadIdx.x & 63) == 0) red16[threadIdx.x >> 6] = w;
  __syncthreads();
  double tot = 0.0;
#pragma unroll
  for (int i = 0; i < 16; i++) tot += red16[i];
  __syncthreads();
  return tot;
}

__device__ __forceinline__ double blk_sum_256(double v, double* red4) {
  double w = wave_reduce64(v);
  if ((threadIdx.x & 63) == 0) red4[threadIdx.x >> 6] = w;
  __syncthreads();
  double tot = red4[0] + red4[1] + red4[2] + red4[3];
  __syncthreads();
  return tot;
}

// Fused dual block-sum (1024 thr): one LDS pass, one barrier pair, deterministic.
__device__ __forceinline__ void blk_sum2_1024(double a, double b, double* redA, double* redB,
                                              double& ra, double& rb) {
#pragma unroll
  for (int m = 32; m > 0; m >>= 1) {
    a += __shfl_xor(a, m, 64);
    b += __shfl_xor(b, m, 64);
  }
  if ((threadIdx.x & 63) == 0) {
    redA[threadIdx.x >> 6] = a;
    redB[threadIdx.x >> 6] = b;
  }
  __syncthreads();
  ra = 0.0; rb = 0.0;
#pragma unroll
  for (int i = 0; i < 16; i++) { ra += redA[i]; rb += redB[i]; }
  __syncthreads();
}

// ---------------- fused pre-kernel: xn + centers_init + rstd array + state ----------------
// blocks 0..511: xn (inline rstd); 512..551: centers_init; 552: rstd[]+pot+conv.
__global__ __launch_bounds__(256) void k_pre(const float* __restrict__ cov, double* __restrict__ rstd,
                                             double* __restrict__ xn, double* __restrict__ C,
                                             InitIdx ii, double* __restrict__ pot, int* __restrict__ conv) {
  int w = blockIdx.x;
  if (w < 512) {
    int s = w >> 6;
    __shared__ double rsh[NA];
    const float* covS = cov + (size_t)s * NA * NA;
    for (int j = threadIdx.x; j < NA; j += 256)
      rsh[j] = 1.0 / sqrt((double)covS[(size_t)j * NA + j]);
    __syncthreads();
    int lane = threadIdx.x & 63, wave = threadIdx.x >> 6;
    for (int q = 0; q < 4; q++) {
      int i = (w & 63) * 16 + wave * 4 + q;
      const float* row = covS + (size_t)i * NA;
      double acc = 0.0;
      for (int j = lane; j < NA; j += 64) {
        double v = (double)row[j] * rsh[j];
        acc += v * v;
      }
      acc = wave_reduce64(acc);
      if (lane == 0) {
        double ri = rsh[i];
        xn[s * NA + i] = acc * ri * ri;
      }
    }
  } else if (w < 552) {
    int w2 = w - 512;
    int s = w2 / NK, k = w2 % NK;
    int idx = ii.v[s * NK + k];
    const float* covS = cov + (size_t)s * NA * NA;
    double ri = 1.0 / sqrt((double)covS[(size_t)idx * NA + idx]);
    const float* row = covS + (size_t)idx * NA;
    for (int j = threadIdx.x; j < NA; j += 256) {
      double rj = 1.0 / sqrt((double)covS[(size_t)j * NA + j]);
      C[((size_t)s * NK + k) * NA + j] = (double)row[j] * ri * rj;
    }
  } else {
    int t = threadIdx.x;
    for (int gid = t; gid < NS * NA; gid += 256) {
      int s = gid >> 10, a = gid & 1023;
      rstd[gid] = 1.0 / sqrt((double)cov[(size_t)s * NA * NA + (size_t)a * NA + a]);
    }
    if (t < NS) { pot[t] = INFINITY; conv[t] = 0; }
  }
}

// ---------------- KMeans iteration: 2 launches, fused single cov pass ----------------
__global__ __launch_bounds__(1024) void k_assignA(const float* __restrict__ cov, const double* __restrict__ rstd,
                                                  const double* __restrict__ xn, const double* __restrict__ C,
                                                  const int* __restrict__ conv, int* __restrict__ ixs,
                                                  double* __restrict__ mind, double* __restrict__ pU) {
  int blk = blockIdx.x, s = blk >> 5, rblk = blk & 31;
  if (conv[s]) return;  // frozen: coherent via kernel-boundary ordering
  __shared__ double Cs[NK][NA];  // rstd_j-scaled centers, 40 KB
  __shared__ double red16[16];
  __shared__ int bks[32];
  __shared__ double rloc[32];
  int t = threadIdx.x, lane = t & 63, wid = t >> 6;
  double rj = rstd[s * NA + t];
  double sq[NK];
#pragma unroll
  for (int k = 0; k < NK; k++) {
    double c = C[((size_t)s * NK + k) * NA + t];
    Cs[k][t] = c * rj;
    sq[k] = c * c;
  }
  double cn[NK];
#pragma unroll
  for (int k = 0; k < NK; k++) cn[k] = blk_sum_1024(sq[k], red16);
  const float* covS = cov + (size_t)s * NA * NA;
#pragma unroll
  for (int r2 = 0; r2 < 2; r2++) {
    int il = wid * 2 + r2;          // 0..31
    int i = rblk * 32 + il;
    const float* row = covS + (size_t)i * NA;
    double xi = xn[s * NA + i];
    double ri = rstd[s * NA + i];
    double a0 = 0, a1 = 0, a2 = 0, a3 = 0, a4 = 0;
#pragma unroll
    for (int c = 0; c < 16; c++) {
      int j = lane + (c << 6);
      double cv = (double)row[j];
      a0 += cv * Cs[0][j]; a1 += cv * Cs[1][j]; a2 += cv * Cs[2][j];
      a3 += cv * Cs[3][j]; a4 += cv * Cs[4][j];
    }
    a0 = wave_reduce64(a0); a1 = wave_reduce64(a1); a2 = wave_reduce64(a2);
    a3 = wave_reduce64(a3); a4 = wave_reduce64(a4);
    if (lane == 0) {
      double dots[5] = {a0, a1, a2, a3, a4};
      double best = INFINITY;
      int bk = 0;
#pragma unroll
      for (int k = 0; k < NK; k++) {
        double d = xi + cn[k] - 2.0 * ri * dots[k];
        if (d < 0.0) d = 0.0;
        if (d < best) { best = d; bk = k; }  // first-min like jnp.argmin
      }
      ixs[s * NA + i] = bk;
      mind[s * NA + i] = best;
      bks[il] = bk;
      rloc[il] = ri;
    }
  }
  __syncthreads();
  // partial center sums: thread t owns column t; ascending il -> deterministic
  double c0 = 0, c1 = 0, c2 = 0, c3 = 0, c4 = 0;
#pragma unroll
  for (int il = 0; il < 32; il++) {
    int i = rblk * 32 + il;
    double v = (double)covS[(size_t)i * NA + t] * rloc[il];  // L2-hot coalesced re-read
    int k = bks[il];
    c0 += (k == 0) ? v : 0.0;
    c1 += (k == 1) ? v : 0.0;
    c2 += (k == 2) ? v : 0.0;
    c3 += (k == 3) ? v : 0.0;
    c4 += (k == 4) ? v : 0.0;
  }
  double* p = pU + ((size_t)blk * NK) * NA;
  p[0 * NA + t] = c0; p[1 * NA + t] = c1; p[2 * NA + t] = c2;
  p[3 * NA + t] = c3; p[4 * NA + t] = c4;
}

__global__ __launch_bounds__(256) void k_updateB(const double* __restrict__ pU, const double* __restrict__ rstd,
                                                 const int* __restrict__ ixs, const double* __restrict__ mind,
                                                 double* __restrict__ C, double* __restrict__ pot,
                                                 int* __restrict__ conv) {
  int w = blockIdx.x, s = w >> 2, seg = w & 3, t = threadIdx.x;
  if (conv[s]) return;
  __shared__ double red4[4];
  double lc[NK] = {0, 0, 0, 0, 0};
#pragma unroll
  for (int q = 0; q < 4; q++) {
    int c = ixs[s * NA + q * 256 + t];
    lc[0] += (c == 0) ? 1.0 : 0.0;
    lc[1] += (c == 1) ? 1.0 : 0.0;
    lc[2] += (c == 2) ? 1.0 : 0.0;
    lc[3] += (c == 3) ? 1.0 : 0.0;
    lc[4] += (c == 4) ? 1.0 : 0.0;
  }
  double cntk[NK];
#pragma unroll
  for (int k = 0; k < NK; k++) cntk[k] = blk_sum_256(lc[k], red4);
  int j = seg * 256 + t;
  double rjj = rstd[s * NA + j];
  double* CS = C + (size_t)s * NK * NA;
#pragma unroll
  for (int k = 0; k < NK; k++) {
    double a = 0.0;
#pragma unroll
    for (int b = 0; b < 32; b++) {  // ascending b == ascending i: deterministic
      int blk = (s << 5) | b;
      a += pU[((size_t)blk * NK + k) * NA + j];
    }
    if (cntk[k] > 0.0) CS[(size_t)k * NA + j] = a * rjj / cntk[k];
    // empty cluster: keep previous center
  }
  if (seg == 0) {
    double v = mind[s * NA + t] + mind[s * NA + 256 + t] +
               mind[s * NA + 512 + t] + mind[s * NA + 768 + t];
    double p = blk_sum_256(v, red4);
    if (t == 0) {
      double prev = pot[s];
      pot[s] = p;
      if (!(fabs(p - prev) >= TOLER)) conv[s] = 1;  // freeze (while-cond fails)
    }
  }
}

// ---------------- post-processing ----------------
__global__ __launch_bounds__(256) void k_members(const int* __restrict__ ixs, int* __restrict__ g,
                                                 int* __restrict__ cnt, int* __restrict__ off5,
                                                 int* __restrict__ boff) {
  int s = blockIdx.x, t = threadIdx.x;
  __shared__ int sc[NK][256];
  __shared__ int base[NK];
  const int* ix = ixs + s * NA;
  int my[4];
  int lc[NK] = {0, 0, 0, 0, 0};
#pragma unroll
  for (int q = 0; q < 4; q++) { my[q] = ix[t * 4 + q]; lc[my[q]]++; }
#pragma unroll
  for (int k = 0; k < NK; k++) sc[k][t] = lc[k];
  __syncthreads();
  for (int off = 1; off < 256; off <<= 1) {
    int v[NK];
#pragma unroll
    for (int k = 0; k < NK; k++) v[k] = (t >= off) ? sc[k][t - off] : 0;
    __syncthreads();
#pragma unroll
    for (int k = 0; k < NK; k++) sc[k][t] += v[k];
    __syncthreads();
  }
  if (t == 0) {
    int b = 0, bo = 0;
    for (int k = 0; k < NK; k++) {
      int tot = sc[k][255];
      base[k] = b;
      cnt[s * NK + k] = tot;
      off5[s * NK + k] = b;
      boff[s * NK + k] = bo;
      b += tot;
      bo += tot * ((tot + 63) & ~63);  // padded: lda = align64(n)
    }
  }
  __syncthreads();
  int pos[NK];
#pragma unroll
  for (int k = 0; k < NK; k++) pos[k] = base[k] + sc[k][t] - lc[k];
#pragma unroll
  for (int q = 0; q < 4; q++) {
    int k = my[q];
    int p = pos[k]++;
    g[s * NA + p] = t * 4 + q;  // stable ascending asset order within cluster
  }
}

// Compact gather, PADDED: lda = align64(n), zero-filled COLUMN pad, rows i<n only.
__global__ __launch_bounds__(1024) void k_gatherB(const float* __restrict__ cov, const int* __restrict__ g,
                                                  const int* __restrict__ cnt, const int* __restrict__ off5,
                                                  const int* __restrict__ boff, float* __restrict__ B) {
  int w = blockIdx.x;  // 40
  int s = w / NK, k = w % NK;
  int n = cnt[s * NK + k];
  if (n == 0) return;
  int lda = (n + 63) & ~63;
  int off = off5[s * NK + k];
  __shared__ int gs[NA];
  int t = threadIdx.x, lane = t & 63, wid = t >> 6;
  if (t < n) gs[t] = g[s * NA + off + t];
  __syncthreads();
  const float* covS = cov + (size_t)s * NA * NA;
  float* Bk = B + (size_t)s * SSTRIDE + (size_t)boff[s * NK + k];
  for (int i = wid; i < n; i += 16) {
    const float* row = covS + (size_t)gs[i] * NA;
    float* out = Bk + (size_t)i * lda;
    for (int j = lane; j < lda; j += 64) out[j] = (j < n) ? row[gs[j]] : 0.0f;
  }
}

// Chronopoulos-Gear CG on padded compact block. Sigma_cc x = 1.
// R7 post-mortem: kernel dur == MAX over 40 blocks; OccupancyPercent dropped
// 5.8->1.75 when most blocks got fast, yet dur held 253us -> the largest
// cluster(s) have n>256 and take the FALLBACK, which was still the original
// row-serialized path (~1 L2 latency per row: n~560 -> 12.1K cyc/iter).
// Fix: 4-row grouped-ILP fallback matvec — all 4*nch loads of a group issued
// via unroll-4 j-loop before consumption, 4 FMA chains, 4-way-ILP butterfly.
// Per-row accumulation order (ascending c) and butterfly tree BITWISE
// IDENTICAL to the verified fallback; rows >= n clamp to row 0 (in-bounds,
// discarded — the R5-verified pattern). n<=256 keeps R7's symmetric path.
#define FB_MATVEC()                                                         \
    do {                                                                    \
      for (int i0_ = wid; i0_ < n; i0_ += 64) {                             \
        int i1_ = i0_ + 16, i2_ = i0_ + 32, i3_ = i0_ + 48;                 \
        const float* r0_ = A + (size_t)i0_ * lda;                           \
        const float* r1_ = A + (size_t)(i1_ < n ? i1_ : 0) * lda;           \
        const float* r2_ = A + (size_t)(i2_ < n ? i2_ : 0) * lda;           \
        const float* r3_ = A + (size_t)(i3_ < n ? i3_ : 0) * lda;           \
        double a0_ = 0.0, a1_ = 0.0, a2_ = 0.0, a3_ = 0.0;                  \
        _Pragma("unroll 4")                                                 \
        for (int c_ = 0; c_ < nch; c_++) {                                  \
          int j_ = lane + (c_ << 6);                                        \
          float f0_ = r0_[j_], f1_ = r1_[j_], f2_ = r2_[j_], f3_ = r3_[j_]; \
          double rj_ = rv[j_];                                              \
          a0_ += (double)f0_ * rj_; a1_ += (double)f1_ * rj_;               \
          a2_ += (double)f2_ * rj_; a3_ += (double)f3_ * rj_;               \
        }                                                                   \
        _Pragma("unroll")                                                   \
        for (int mm_ = 32; mm_ > 0; mm_ >>= 1) {                            \
          a0_ += __shfl_xor(a0_, mm_, 64);                                  \
          a1_ += __shfl_xor(a1_, mm_, 64);                                  \
          a2_ += __shfl_xor(a2_, mm_, 64);                                  \
          a3_ += __shfl_xor(a3_, mm_, 64);                                  \
        }                                                                   \
        if (lane == 0) {                                                    \
          wv[i0_] = a0_;                                                    \
          if (i1_ < n) wv[i1_] = a1_;                                       \
          if (i2_ < n) wv[i2_] = a2_;                                       \
          if (i3_ < n) wv[i3_] = a3_;                                       \
        }                                                                   \
      }                                                                     \
    } while (0)

__global__ __launch_bounds__(1024) void k_cg_comp(const float* __restrict__ B, const int* __restrict__ g,
                                                  const int* __restrict__ cnt, const int* __restrict__ off5,
                                                  const int* __restrict__ boff, double* __restrict__ walloc) {
  int w = blockIdx.x;  // 40
  int s = w / NK, k = w % NK;
  int n = cnt[s * NK + k];
  if (n == 0) return;
  int lda = (n + 63) & ~63;
  int nch = lda >> 6;
  int off = off5[s * NK + k];
  const float* A = B + (size_t)s * SSTRIDE + (size_t)boff[s * NK + k];
  __shared__ double xv[NA], rv[NA], pv[NA], sv[NA], wv[NA];
  __shared__ int gs[NA];
  __shared__ double redA[16], redB[16];
  __shared__ __align__(16) double rvs[256];
  __shared__ double pw[4][256];
  __shared__ double redC[4], redD[4];
  int t = threadIdx.x, lane = t & 63, wid = t >> 6;
  const double tol = 1e-10 * (double)n;  // rel resid 1e-5: err ~ kappa*1e-5*|w| << floor

  if (n <= 256) {
    // -------- symmetric column-coalesced matvec, no cross-lane reduce --------
    int ic = t & 255, gchunk = t >> 8;   // output column, j-chunk (0..3)
    int jbeg = gchunk << 6;
    bool owner = (t < 256);
    int nrem = n - jbeg;                 // rows in this chunk (uniform per chunk)
    if (nrem > 64) nrem = 64;
    bool act = (ic < lda) && (nrem > 0);
    const float* colp = A + (size_t)jbeg * lda + ic;  // only deref'd when act

#define MV_SYM()                                                            \
    do {                                                                    \
      double part_ = 0.0;                                                   \
      if (act) {                                                            \
        _Pragma("unroll 8")                                                 \
        for (int u_ = 0; u_ < nrem; u_++)                                   \
          part_ += (double)colp[(size_t)u_ * lda] * rvs[jbeg + u_];         \
      }                                                                     \
      pw[gchunk][ic] = part_;                                               \
    } while (0)

    // owner-register CG state
    double xr = 0.0, rr = 0.0, pr = 0.0, sr = 0.0, wr = 0.0;
    int gi = 0;
    if (owner) {
      rr = (ic < n) ? 1.0 : 0.0;
      if (ic < n) gi = g[s * NA + off + ic];
      rvs[ic] = rr;
    }
    __syncthreads();

    // w = A r (r = 1)
    MV_SYM();
    __syncthreads();
    if (owner) {
      wr = ((pw[0][ic] + pw[1][ic]) + pw[2][ic]) + pw[3][ic];
      double g1 = 0.0, g2 = 0.0;
      if (ic < n) { g1 = rr * rr; g2 = rr * wr; }
#pragma unroll
      for (int m = 32; m > 0; m >>= 1) {
        g1 += __shfl_xor(g1, m, 64);
        g2 += __shfl_xor(g2, m, 64);
      }
      if (lane == 0) { redC[wid] = g1; redD[wid] = g2; }
    }
    __syncthreads();
    double gam = (double)n;
    double d1 = ((redD[0] + redD[1]) + redD[2]) + redD[3];  // (w,r), r=1
    double alpha = gam / d1;
    if (owner && ic < n) { pr = rr; sr = wr; }

    for (int iter = 0; iter < 50; iter++) {
      if (owner && ic < n) {
        xr += alpha * pr;
        rr -= alpha * sr;
        rvs[ic] = rr;
      }
      __syncthreads();      // rvs ready
      MV_SYM();
      __syncthreads();      // pw ready
      if (owner) {
        wr = ((pw[0][ic] + pw[1][ic]) + pw[2][ic]) + pw[3][ic];
        double g1 = 0.0, g2 = 0.0;
        if (ic < n) { g1 = rr * rr; g2 = rr * wr; }
#pragma unroll
        for (int m = 32; m > 0; m >>= 1) {
          g1 += __shfl_xor(g1, m, 64);
          g2 += __shfl_xor(g2, m, 64);
        }
        if (lane == 0) { redC[wid] = g1; redD[wid] = g2; }
      }
      __syncthreads();      // red ready
      double gamn = ((redC[0] + redC[1]) + redC[2]) + redC[3];
      double delt = ((redD[0] + redD[1]) + redD[2]) + redD[3];
      if (gamn < tol) break;  // uniform across block
      double beta = gamn / gam;
      alpha = gamn / (delt - beta * gamn / alpha);
      gam = gamn;
      if (owner && ic < n) {
        pr = rr + beta * pr;
        sr = wr + beta * sr;
      }
    }
    __syncthreads();  // protect redC reuse (all (g)-phase readers done)
    if (owner) {
      double dp = (ic < n) ? xr : 0.0;
#pragma unroll
      for (int m = 32; m > 0; m >>= 1) dp += __shfl_xor(dp, m, 64);
      if (lane == 0) redC[wid] = dp;
    }
    __syncthreads();
    double denom = ((redC[0] + redC[1]) + redC[2]) + redC[3];
    if (owner && ic < n) walloc[s * NA + gi] = xr / denom;
#undef MV_SYM
  } else {
    // -------- fallback: 4-row grouped-ILP matvec (bitwise == old fallback) --------
    if (t < n) gs[t] = g[s * NA + off + t];
    rv[t] = (t < n) ? 1.0 : 0.0;  // pad region zeroed: matvec reads rv up to lda
    if (t < n) xv[t] = 0.0;
    __syncthreads();
    // w = A r
    FB_MATVEC();
    __syncthreads();
    double gam = (double)n;  // (r,r) with r=1
    double d1, d2;
    blk_sum2_1024((t < n) ? wv[t] : 0.0, 0.0, redA, redB, d1, d2);  // (w,r) with r=1
    double alpha = gam / d1;
    if (t < n) { pv[t] = rv[t]; sv[t] = wv[t]; }
    for (int iter = 0; iter < 50; iter++) {
      if (t < n) {
        xv[t] += alpha * pv[t];
        rv[t] -= alpha * sv[t];
      }
      __syncthreads();
      // w = A r
      FB_MATVEC();
      __syncthreads();
      double g1 = 0.0, g2 = 0.0;
      if (t < n) {
        double rt = rv[t];
        g1 = rt * rt;
        g2 = rt * wv[t];
      }
      double gamn, delt;
      blk_sum2_1024(g1, g2, redA, redB, gamn, delt);
      if (gamn < tol) break;  // uniform across block
      double beta = gamn / gam;
      alpha = gamn / (delt - beta * gamn / alpha);
      gam = gamn;
      if (t < n) {
        pv[t] = rv[t] + beta * pv[t];
        sv[t] = wv[t] + beta * sv[t];
      }
    }
    double dp = (t < n) ? xv[t] : 0.0;
    double d3, d4;
    blk_sum2_1024(dp, 0.0, redA, redB, d3, d4);
    if (t < n) walloc[s * NA + gs[t]] = xv[t] / d3;
  }
}

// Fallback (ws too small for compact B): R5's full-row CG — verified PASS.
__global__ __launch_bounds__(1024) void k_cg_full(const float* __restrict__ cov,
                                                  const int* __restrict__ g, const int* __restrict__ cnt,
                                                  const int* __restrict__ off5, double* __restrict__ walloc) {
  int w = blockIdx.x;
  int s = w / NK, k = w % NK;
  int n = cnt[s * NK + k];
  if (n == 0) return;
  int off = off5[s * NK + k];
  const float* covS = cov + (size_t)s * NA * NA;
  __shared__ double pfull[NA];
  __shared__ double xv[NA], rv[NA], pv[NA], ap[NA];
  __shared__ int gs[NA];
  __shared__ double red16[16];
  int t = threadIdx.x, lane = t & 63, wid = t >> 6;
  if (t < n) {
    gs[t] = g[s * NA + off + t];
    xv[t] = 0.0; rv[t] = 1.0; pv[t] = 1.0;
  }
  double rr = (double)n;
  __syncthreads();
  for (int iter = 0; iter < 100; iter++) {
    pfull[t] = 0.0;
    __syncthreads();
    if (t < n) pfull[gs[t]] = pv[t];
    __syncthreads();
    for (int i = wid; i < n; i += 16) {
      const float* row = covS + (size_t)gs[i] * NA;
      double acc = 0.0;
#pragma unroll
      for (int c = 0; c < 16; c++) {
        int j = lane + (c << 6);
        acc += (double)row[j] * pfull[j];
      }
      acc = wave_reduce64(acc);
      if (lane == 0) ap[i] = acc;
    }
    __syncthreads();
    double pp = (t < n) ? pv[t] * ap[t] : 0.0;
    double pap = blk_sum_1024(pp, red16);
    double alpha = rr / pap;
    double rp = 0.0;
    if (t < n) {
      xv[t] += alpha * pv[t];
      double rn = rv[t] - alpha * ap[t];
      rv[t] = rn;
      rp = rn * rn;
    }
    double rrn = blk_sum_1024(rp, red16);
    if (rrn < 1e-20 * (double)n) break;
    double beta = rrn / rr;
    rr = rrn;
    if (t < n) pv[t] = rv[t] + beta * pv[t];
    __syncthreads();
  }
  double dp = (t < n) ? xv[t] : 0.0;
  double denom = blk_sum_1024(dp, red16);
  if (t < n) walloc[s * NA + gs[t]] = xv[t] / denom;
}

__global__ __launch_bounds__(256) void k_intery(const float* __restrict__ cov, const double* __restrict__ walloc,
                                                const int* __restrict__ g, const int* __restrict__ cnt,
                                                const int* __restrict__ off5, double* __restrict__ y2) {
  int w = blockIdx.x;  // 160
  int s = w / 20, rem = w % 20, k = rem / 4, seg = rem % 4;
  int n = cnt[s * NK + k], off = off5[s * NK + k];
  int t = threadIdx.x;
  __shared__ int gsl[NA];
  __shared__ double wl[NA];
  for (int i = t; i < n; i += 256) {
    int a = g[s * NA + off + i];
    gsl[i] = a;
    wl[i] = walloc[s * NA + a];
  }
  __syncthreads();
  int j = seg * 256 + t;
  const float* covS = cov + (size_t)s * NA * NA;
  double acc = 0.0;
  for (int i = 0; i < n; i++) acc += wl[i] * (double)covS[(size_t)gsl[i] * NA + j];
  y2[((size_t)s * NK + k) * NA + j] = acc;
}

__global__ __launch_bounds__(256) void k_icov(const double* __restrict__ y2, const double* __restrict__ walloc,
                                              const int* __restrict__ ixs, double* __restrict__ w_inter) {
  int s = blockIdx.x, t = threadIdx.x;
  __shared__ double red4[4];
  __shared__ double ic[NK * NK];
  for (int k = 0; k < NK; k++) {
    double p0 = 0, p1 = 0, p2 = 0, p3 = 0, p4 = 0;
    for (int j = t; j < NA; j += 256) {
      double v = y2[((size_t)s * NK + k) * NA + j] * walloc[s * NA + j];
      int c = ixs[s * NA + j];
      p0 += (c == 0) ? v : 0.0;
      p1 += (c == 1) ? v : 0.0;
      p2 += (c == 2) ? v : 0.0;
      p3 += (c == 3) ? v : 0.0;
      p4 += (c == 4) ? v : 0.0;
    }
    double q0 = blk_sum_256(p0, red4);
    double q1 = blk_sum_256(p1, red4);
    double q2 = blk_sum_256(p2, red4);
    double q3 = blk_sum_256(p3, red4);
    double q4 = blk_sum_256(p4, red4);
    if (t == 0) {
      ic[k * NK + 0] = q0; ic[k * NK + 1] = q1; ic[k * NK + 2] = q2;
      ic[k * NK + 3] = q3; ic[k * NK + 4] = q4;
    }
  }
  __syncthreads();
  if (t == 0) {
    double M[NK * NK], b[NK], z[NK];
    for (int i = 0; i < NK * NK; i++) M[i] = ic[i];
    for (int i = 0; i < NK; i++) b[i] = 1.0;
    for (int c = 0; c < NK; c++) {
      int pr = c;
      double mb = fabs(M[c * NK + c]);
      for (int r = c + 1; r < NK; r++) {
        double a = fabs(M[r * NK + c]);
        if (a > mb) { mb = a; pr = r; }
      }
      if (pr != c) {
        for (int cc = 0; cc < NK; cc++) {
          double tmp = M[c * NK + cc]; M[c * NK + cc] = M[pr * NK + cc]; M[pr * NK + cc] = tmp;
        }
        double tb = b[c]; b[c] = b[pr]; b[pr] = tb;
      }
      double piv = M[c * NK + c];
      for (int r = c + 1; r < NK; r++) {
        double f = M[r * NK + c] / piv;
        for (int cc = c; cc < NK; cc++) M[r * NK + cc] -= f * M[c * NK + cc];
        b[r] -= f * b[c];
      }
    }
    for (int r = NK - 1; r >= 0; r--) {
      double acc = b[r];
      for (int cc = r + 1; cc < NK; cc++) acc -= M[r * NK + cc] * z[cc];
      z[r] = acc / M[r * NK + r];
    }
    double ssum = z[0] + z[1] + z[2] + z[3] + z[4];
    for (int k = 0; k < NK; k++) w_inter[s * NK + k] = z[k] / ssum;
  }
}

__global__ __launch_bounds__(256) void k_final(const double* __restrict__ walloc, const double* __restrict__ w_inter,
                                               const int* __restrict__ ixs, float* __restrict__ out) {
  int gid = blockIdx.x * 256 + threadIdx.x;
  if (gid >= NS * NA) return;
  int s = gid >> 10;
  out[gid] = (float)(walloc[gid] * w_inter[s * NK + ixs[gid]]);
}

// ---------------- launch ----------------
extern "C" void kernel_launch(void* const* d_in, const int* in_sizes, int n_in,
                              void* d_out, int out_size, void* d_ws, size_t ws_size,
                              hipStream_t stream) {
  const float* cov = (const float*)d_in[0];
  float* out = (float*)d_out;
  char* ws = (char*)d_ws;
  size_t o = 0;
  auto alloc = [&](size_t bytes) {
    size_t cur = o;
    o += (bytes + 255) & ~(size_t)255;
    return cur;
  };
  double* C = (double*)(ws + alloc((size_t)NS * NK * NA * 8));
  double* y2 = (double*)(ws + alloc((size_t)NS * NK * NA * 8));
  double* pU = (double*)(ws + alloc((size_t)256 * NK * NA * 8));  // 10.5 MB partials
  double* rstd = (double*)(ws + alloc((size_t)NS * NA * 8));
  double* xn = (double*)(ws + alloc((size_t)NS * NA * 8));
  double* mind = (double*)(ws + alloc((size_t)NS * NA * 8));
  double* walloc = (double*)(ws + alloc((size_t)NS * NA * 8));
  int* ixs = (int*)(ws + alloc((size_t)NS * NA * 4));
  int* g = (int*)(ws + alloc((size_t)NS * NA * 4));
  int* cnt = (int*)(ws + alloc((size_t)NS * NK * 4));
  int* off5 = (int*)(ws + alloc((size_t)NS * NK * 4));
  int* boff = (int*)(ws + alloc((size_t)NS * NK * 4));
  int* conv = (int*)(ws + alloc((size_t)NS * 4));
  double* pot = (double*)(ws + alloc((size_t)NS * 8));
  double* w_inter = (double*)(ws + alloc((size_t)NS * NK * 8));
  size_t bcomp_off = alloc(NS * SSTRIDE * 4);  // 35.7 MB padded blocks, guarded
  float* Bcomp = (float*)(ws + bcomp_off);
  bool use_compact = (ws_size >= o);  // launch-time constant: same graph every call
  (void)in_sizes; (void)n_in; (void)out_size;

  InitIdx ii;
  compute_init_indices(ii);  // data-independent, identical every call

  k_pre<<<553, 256, 0, stream>>>(cov, rstd, xn, C, ii, pot, conv);
  for (int it = 0; it < MAXIT; it++) {
    k_assignA<<<256, 1024, 0, stream>>>(cov, rstd, xn, C, conv, ixs, mind, pU);
    k_updateB<<<32, 256, 0, stream>>>(pU, rstd, ixs, mind, C, pot, conv);
  }
  k_members<<<8, 256, 0, stream>>>(ixs, g, cnt, off5, boff);
  if (use_compact) {
    k_gatherB<<<40, 1024, 0, stream>>>(cov, g, cnt, off5, boff, Bcomp);
    k_cg_comp<<<40, 1024, 0, stream>>>(Bcomp, g, cnt, off5, boff, walloc);
  } else {
    k_cg_full<<<40, 1024, 0, stream>>>(cov, g, cnt, off5, walloc);
  }
  k_intery<<<160, 256, 0, stream>>>(cov, walloc, g, cnt, off5, y2);
  k_icov<<<8, 256, 0, stream>>>(y2, walloc, ixs, w_inter);
  k_final<<<32, 256, 0, stream>>>(walloc, w_inter, ixs, out);
}

// Round 9
// 939.129 us; speedup vs baseline: 1.1424x; 1.0768x over previous
//
#include <hip/hip_runtime.h>
#include <stdint.h>
#include <math.h>
#include <algorithm>

#define NS 8
#define NA 1024
#define NK 5
#define MAXIT 30
#define TOLER 1e-5
#define SSTRIDE ((size_t)NA * NA + 64 * NA)  // padded per-sample Bcomp stride (floats)

// ---------------- host-side threefry-2x32 (JAX-compatible) ----------------
static inline void tf2x32(uint32_t k0, uint32_t k1, uint32_t c0, uint32_t c1,
                          uint32_t& o0, uint32_t& o1) {
  uint32_t ks2 = k0 ^ k1 ^ 0x1BD11BDAu;
  uint32_t x0 = c0 + k0, x1 = c1 + k1;
  auto rot = [](uint32_t x, int r) { return (x << r) | (x >> (32 - r)); };
  auto R4 = [&](int r0, int r1, int r2, int r3) {
    x0 += x1; x1 = rot(x1, r0); x1 ^= x0;
    x0 += x1; x1 = rot(x1, r1); x1 ^= x0;
    x0 += x1; x1 = rot(x1, r2); x1 ^= x0;
    x0 += x1; x1 = rot(x1, r3); x1 ^= x0;
  };
  R4(13, 15, 26, 6);  x0 += k1;  x1 += ks2 + 1u;
  R4(17, 29, 16, 24); x0 += ks2; x1 += k0 + 2u;
  R4(13, 15, 26, 6);  x0 += k0;  x1 += k1 + 3u;
  R4(17, 29, 16, 24); x0 += k1;  x1 += ks2 + 4u;
  R4(13, 15, 26, 6);  x0 += ks2; x1 += k0 + 5u;
  o0 = x0; o1 = x1;
}

struct InitIdx { int v[NS * NK]; };

// jax_threefry_partitionable=True semantics (verified R3/R5-R8: PASS)
static void compute_init_indices(InitIdx& out) {
  const uint32_t rk0 = 0, rk1 = 42;
  for (int s = 0; s < NS; s++) {
    uint32_t k0, k1;
    tf2x32(rk0, rk1, 0u, (uint32_t)s, k0, k1);
    uint32_t sk0, sk1;
    tf2x32(k0, k1, 0u, 1u, sk0, sk1);
    uint32_t bits[NA];
    for (int i = 0; i < NA; i++) {
      uint32_t b0, b1;
      tf2x32(sk0, sk1, 0u, (uint32_t)i, b0, b1);
      bits[i] = b0 ^ b1;
    }
    int idx[NA];
    for (int i = 0; i < NA; i++) idx[i] = i;
    std::stable_sort(idx, idx + NA, [&](int x, int y) { return bits[x] < bits[y]; });
    for (int c = 0; c < NK; c++) out.v[s * NK + c] = idx[c];
  }
}

// ---------------- device helpers ----------------
__device__ __forceinline__ double wave_reduce64(double v) {
#pragma unroll
  for (int m = 32; m > 0; m >>= 1) v += __shfl_xor(v, m, 64);
  return v;
}

__device__ __forceinline__ double blk_sum_1024(double v, double* red16) {
  double w = wave_reduce64(v);
  if ((threadIdx.x & 63) == 0) red16[threadIdx.x >> 6] = w;
  __syncthreads();
  double tot = 0.0;
#pragma unroll
  for (int i = 0; i < 16; i++) tot += red16[i];
  __syncthreads();
  return tot;
}

__device__ __forceinline__ double blk_sum_256(double v, double* red4) {
  double w = wave_reduce64(v);
  if ((threadIdx.x & 63) == 0) red4[threadIdx.x >> 6] = w;
  __syncthreads();
  double tot = red4[0] + red4[1] + red4[2] + red4[3];
  __syncthreads();
  return tot;
}

// Fused dual block-sum (1024 thr): one LDS pass, one barrier pair, deterministic.
__device__ __forceinline__ void blk_sum2_1024(double a, double b, double* redA, double* redB,
                                              double& ra, double& rb) {
#pragma unroll
  for (int m = 32; m > 0; m >>= 1) {
    a += __shfl_xor(a, m, 64);
    b += __shfl_xor(b, m, 64);
  }
  if ((threadIdx.x & 63) == 0) {
    redA[threadIdx.x >> 6] = a;
    redB[threadIdx.x >> 6] = b;
  }
  __syncthreads();
  ra = 0.0; rb = 0.0;
#pragma unroll
  for (int i = 0; i < 16; i++) { ra += redA[i]; rb += redB[i]; }
  __syncthreads();
}

// ---------------- fused pre-kernel: xn + centers_init + rstd array + state ----------------
// blocks 0..511: xn (inline rstd); 512..551: centers_init; 552: rstd[]+pot+conv.
__global__ __launch_bounds__(256) void k_pre(const float* __restrict__ cov, double* __restrict__ rstd,
                                             double* __restrict__ xn, double* __restrict__ C,
                                             InitIdx ii, double* __restrict__ pot, int* __restrict__ conv) {
  int w = blockIdx.x;
  if (w < 512) {
    int s = w >> 6;
    __shared__ double rsh[NA];
    const float* covS = cov + (size_t)s * NA * NA;
    for (int j = threadIdx.x; j < NA; j += 256)
      rsh[j] = 1.0 / sqrt((double)covS[(size_t)j * NA + j]);
    __syncthreads();
    int lane = threadIdx.x & 63, wave = threadIdx.x >> 6;
    for (int q = 0; q < 4; q++) {
      int i = (w & 63) * 16 + wave * 4 + q;
      const float* row = covS + (size_t)i * NA;
      double acc = 0.0;
      for (int j = lane; j < NA; j += 64) {
        double v = (double)row[j] * rsh[j];
        acc += v * v;
      }
      acc = wave_reduce64(acc);
      if (lane == 0) {
        double ri = rsh[i];
        xn[s * NA + i] = acc * ri * ri;
      }
    }
  } else if (w < 552) {
    int w2 = w - 512;
    int s = w2 / NK, k = w2 % NK;
    int idx = ii.v[s * NK + k];
    const float* covS = cov + (size_t)s * NA * NA;
    double ri = 1.0 / sqrt((double)covS[(size_t)idx * NA + idx]);
    const float* row = covS + (size_t)idx * NA;
    for (int j = threadIdx.x; j < NA; j += 256) {
      double rj = 1.0 / sqrt((double)covS[(size_t)j * NA + j]);
      C[((size_t)s * NK + k) * NA + j] = (double)row[j] * ri * rj;
    }
  } else {
    int t = threadIdx.x;
    for (int gid = t; gid < NS * NA; gid += 256) {
      int s = gid >> 10, a = gid & 1023;
      rstd[gid] = 1.0 / sqrt((double)cov[(size_t)s * NA * NA + (size_t)a * NA + a]);
    }
    if (t < NS) { pot[t] = INFINITY; conv[t] = 0; }
  }
}

// ---------------- KMeans iteration: 2 launches, fused single cov pass ----------------
__global__ __launch_bounds__(1024) void k_assignA(const float* __restrict__ cov, const double* __restrict__ rstd,
                                                  const double* __restrict__ xn, const double* __restrict__ C,
                                                  const int* __restrict__ conv, int* __restrict__ ixs,
                                                  double* __restrict__ mind, double* __restrict__ pU) {
  int blk = blockIdx.x, s = blk >> 5, rblk = blk & 31;
  if (conv[s]) return;  // frozen: coherent via kernel-boundary ordering
  __shared__ double Cs[NK][NA];  // rstd_j-scaled centers, 40 KB
  __shared__ double red16[16];
  __shared__ int bks[32];
  __shared__ double rloc[32];
  int t = threadIdx.x, lane = t & 63, wid = t >> 6;
  double rj = rstd[s * NA + t];
  double sq[NK];
#pragma unroll
  for (int k = 0; k < NK; k++) {
    double c = C[((size_t)s * NK + k) * NA + t];
    Cs[k][t] = c * rj;
    sq[k] = c * c;
  }
  double cn[NK];
#pragma unroll
  for (int k = 0; k < NK; k++) cn[k] = blk_sum_1024(sq[k], red16);
  const float* covS = cov + (size_t)s * NA * NA;
#pragma unroll
  for (int r2 = 0; r2 < 2; r2++) {
    int il = wid * 2 + r2;          // 0..31
    int i = rblk * 32 + il;
    const float* row = covS + (size_t)i * NA;
    double xi = xn[s * NA + i];
    double ri = rstd[s * NA + i];
    double a0 = 0, a1 = 0, a2 = 0, a3 = 0, a4 = 0;
#pragma unroll
    for (int c = 0; c < 16; c++) {
      int j = lane + (c << 6);
      double cv = (double)row[j];
      a0 += cv * Cs[0][j]; a1 += cv * Cs[1][j]; a2 += cv * Cs[2][j];
      a3 += cv * Cs[3][j]; a4 += cv * Cs[4][j];
    }
    a0 = wave_reduce64(a0); a1 = wave_reduce64(a1); a2 = wave_reduce64(a2);
    a3 = wave_reduce64(a3); a4 = wave_reduce64(a4);
    if (lane == 0) {
      double dots[5] = {a0, a1, a2, a3, a4};
      double best = INFINITY;
      int bk = 0;
#pragma unroll
      for (int k = 0; k < NK; k++) {
        double d = xi + cn[k] - 2.0 * ri * dots[k];
        if (d < 0.0) d = 0.0;
        if (d < best) { best = d; bk = k; }  // first-min like jnp.argmin
      }
      ixs[s * NA + i] = bk;
      mind[s * NA + i] = best;
      bks[il] = bk;
      rloc[il] = ri;
    }
  }
  __syncthreads();
  // partial center sums: thread t owns column t; ascending il -> deterministic
  double c0 = 0, c1 = 0, c2 = 0, c3 = 0, c4 = 0;
#pragma unroll
  for (int il = 0; il < 32; il++) {
    int i = rblk * 32 + il;
    double v = (double)covS[(size_t)i * NA + t] * rloc[il];  // L2-hot coalesced re-read
    int k = bks[il];
    c0 += (k == 0) ? v : 0.0;
    c1 += (k == 1) ? v : 0.0;
    c2 += (k == 2) ? v : 0.0;
    c3 += (k == 3) ? v : 0.0;
    c4 += (k == 4) ? v : 0.0;
  }
  double* p = pU + ((size_t)blk * NK) * NA;
  p[0 * NA + t] = c0; p[1 * NA + t] = c1; p[2 * NA + t] = c2;
  p[3 * NA + t] = c3; p[4 * NA + t] = c4;
}

__global__ __launch_bounds__(256) void k_updateB(const double* __restrict__ pU, const double* __restrict__ rstd,
                                                 const int* __restrict__ ixs, const double* __restrict__ mind,
                                                 double* __restrict__ C, double* __restrict__ pot,
                                                 int* __restrict__ conv) {
  int w = blockIdx.x, s = w >> 2, seg = w & 3, t = threadIdx.x;
  if (conv[s]) return;
  __shared__ double red4[4];
  double lc[NK] = {0, 0, 0, 0, 0};
#pragma unroll
  for (int q = 0; q < 4; q++) {
    int c = ixs[s * NA + q * 256 + t];
    lc[0] += (c == 0) ? 1.0 : 0.0;
    lc[1] += (c == 1) ? 1.0 : 0.0;
    lc[2] += (c == 2) ? 1.0 : 0.0;
    lc[3] += (c == 3) ? 1.0 : 0.0;
    lc[4] += (c == 4) ? 1.0 : 0.0;
  }
  double cntk[NK];
#pragma unroll
  for (int k = 0; k < NK; k++) cntk[k] = blk_sum_256(lc[k], red4);
  int j = seg * 256 + t;
  double rjj = rstd[s * NA + j];
  double* CS = C + (size_t)s * NK * NA;
#pragma unroll
  for (int k = 0; k < NK; k++) {
    double a = 0.0;
#pragma unroll
    for (int b = 0; b < 32; b++) {  // ascending b == ascending i: deterministic
      int blk = (s << 5) | b;
      a += pU[((size_t)blk * NK + k) * NA + j];
    }
    if (cntk[k] > 0.0) CS[(size_t)k * NA + j] = a * rjj / cntk[k];
    // empty cluster: keep previous center
  }
  if (seg == 0) {
    double v = mind[s * NA + t] + mind[s * NA + 256 + t] +
               mind[s * NA + 512 + t] + mind[s * NA + 768 + t];
    double p = blk_sum_256(v, red4);
    if (t == 0) {
      double prev = pot[s];
      pot[s] = p;
      if (!(fabs(p - prev) >= TOLER)) conv[s] = 1;  // freeze (while-cond fails)
    }
  }
}

// ---------------- post-processing ----------------
__global__ __launch_bounds__(256) void k_members(const int* __restrict__ ixs, int* __restrict__ g,
                                                 int* __restrict__ cnt, int* __restrict__ off5,
                                                 int* __restrict__ boff) {
  int s = blockIdx.x, t = threadIdx.x;
  __shared__ int sc[NK][256];
  __shared__ int base[NK];
  const int* ix = ixs + s * NA;
  int my[4];
  int lc[NK] = {0, 0, 0, 0, 0};
#pragma unroll
  for (int q = 0; q < 4; q++) { my[q] = ix[t * 4 + q]; lc[my[q]]++; }
#pragma unroll
  for (int k = 0; k < NK; k++) sc[k][t] = lc[k];
  __syncthreads();
  for (int off = 1; off < 256; off <<= 1) {
    int v[NK];
#pragma unroll
    for (int k = 0; k < NK; k++) v[k] = (t >= off) ? sc[k][t - off] : 0;
    __syncthreads();
#pragma unroll
    for (int k = 0; k < NK; k++) sc[k][t] += v[k];
    __syncthreads();
  }
  if (t == 0) {
    int b = 0, bo = 0;
    for (int k = 0; k < NK; k++) {
      int tot = sc[k][255];
      base[k] = b;
      cnt[s * NK + k] = tot;
      off5[s * NK + k] = b;
      boff[s * NK + k] = bo;
      b += tot;
      bo += tot * ((tot + 63) & ~63);  // padded: lda = align64(n)
    }
  }
  __syncthreads();
  int pos[NK];
#pragma unroll
  for (int k = 0; k < NK; k++) pos[k] = base[k] + sc[k][t] - lc[k];
#pragma unroll
  for (int q = 0; q < 4; q++) {
    int k = my[q];
    int p = pos[k]++;
    g[s * NA + p] = t * 4 + q;  // stable ascending asset order within cluster
  }
}

// Compact gather, PADDED: lda = align64(n), zero-filled COLUMN pad, rows i<n only.
__global__ __launch_bounds__(1024) void k_gatherB(const float* __restrict__ cov, const int* __restrict__ g,
                                                  const int* __restrict__ cnt, const int* __restrict__ off5,
                                                  const int* __restrict__ boff, float* __restrict__ B) {
  int w = blockIdx.x;  // 40
  int s = w / NK, k = w % NK;
  int n = cnt[s * NK + k];
  if (n == 0) return;
  int lda = (n + 63) & ~63;
  int off = off5[s * NK + k];
  __shared__ int gs[NA];
  int t = threadIdx.x, lane = t & 63, wid = t >> 6;
  if (t < n) gs[t] = g[s * NA + off + t];
  __syncthreads();
  const float* covS = cov + (size_t)s * NA * NA;
  float* Bk = B + (size_t)s * SSTRIDE + (size_t)boff[s * NK + k];
  for (int i = wid; i < n; i += 16) {
    const float* row = covS + (size_t)gs[i] * NA;
    float* out = Bk + (size_t)i * lda;
    for (int j = lane; j < lda; j += 64) out[j] = (j < n) ? row[gs[j]] : 0.0f;
  }
}

// Chronopoulos-Gear CG on padded compact block. Sigma_cc x = 1.
// R8 post-mortem: the big-cluster block (n~560, one CU) is f64-VALU-issue-
// bound: ~5.2K wave-instrs each of {load, cvt_f64_f32, fma_f64} per matvec
// matches the measured 3.96us/iter floor. Fix: FP32 vectors (x,r,p,s,w; A is
// already f32) — kills the cvt, halves fma and shuffle issue cost. CG
// SCALARS (gamma/delta/alpha/beta) and all block-level dot reductions stay
// f64 (1-2 values/thread/iter). Precision: reference inv is itself float32;
// CG needs rel resid 1e-5 >> f32's ~1e-6 floor; per-lane chains are <=16
// terms + 6-stage butterfly. Both paths converted. Structure (4-row grouped
// fallback, symmetric n<=256 path) unchanged from R8 (PASS, 197.8us).
#define FB_MATVEC()                                                         \
    do {                                                                    \
      for (int i0_ = wid; i0_ < n; i0_ += 64) {                             \
        int i1_ = i0_ + 16, i2_ = i0_ + 32, i3_ = i0_ + 48;                 \
        const float* r0_ = A + (size_t)i0_ * lda;                           \
        const float* r1_ = A + (size_t)(i1_ < n ? i1_ : 0) * lda;           \
        const float* r2_ = A + (size_t)(i2_ < n ? i2_ : 0) * lda;           \
        const float* r3_ = A + (size_t)(i3_ < n ? i3_ : 0) * lda;           \
        float a0_ = 0.0f, a1_ = 0.0f, a2_ = 0.0f, a3_ = 0.0f;               \
        _Pragma("unroll 4")                                                 \
        for (int c_ = 0; c_ < nch; c_++) {                                  \
          int j_ = lane + (c_ << 6);                                        \
          float f0_ = r0_[j_], f1_ = r1_[j_], f2_ = r2_[j_], f3_ = r3_[j_]; \
          float rj_ = rv[j_];                                               \
          a0_ += f0_ * rj_; a1_ += f1_ * rj_;                               \
          a2_ += f2_ * rj_; a3_ += f3_ * rj_;                               \
        }                                                                   \
        _Pragma("unroll")                                                   \
        for (int mm_ = 32; mm_ > 0; mm_ >>= 1) {                            \
          a0_ += __shfl_xor(a0_, mm_, 64);                                  \
          a1_ += __shfl_xor(a1_, mm_, 64);                                  \
          a2_ += __shfl_xor(a2_, mm_, 64);                                  \
          a3_ += __shfl_xor(a3_, mm_, 64);                                  \
        }                                                                   \
        if (lane == 0) {                                                    \
          wv[i0_] = a0_;                                                    \
          if (i1_ < n) wv[i1_] = a1_;                                       \
          if (i2_ < n) wv[i2_] = a2_;                                       \
          if (i3_ < n) wv[i3_] = a3_;                                       \
        }                                                                   \
      }                                                                     \
    } while (0)

__global__ __launch_bounds__(1024) void k_cg_comp(const float* __restrict__ B, const int* __restrict__ g,
                                                  const int* __restrict__ cnt, const int* __restrict__ off5,
                                                  const int* __restrict__ boff, double* __restrict__ walloc) {
  int w = blockIdx.x;  // 40
  int s = w / NK, k = w % NK;
  int n = cnt[s * NK + k];
  if (n == 0) return;
  int lda = (n + 63) & ~63;
  int nch = lda >> 6;
  int off = off5[s * NK + k];
  const float* A = B + (size_t)s * SSTRIDE + (size_t)boff[s * NK + k];
  __shared__ float xv[NA], rv[NA], pv[NA], sv[NA], wv[NA];
  __shared__ int gs[NA];
  __shared__ double redA[16], redB[16];
  __shared__ float rvs[256];
  __shared__ float pw[4][256];
  __shared__ double redC[4], redD[4];
  int t = threadIdx.x, lane = t & 63, wid = t >> 6;
  const double tol = 1e-10 * (double)n;  // rel resid 1e-5: err ~ kappa*1e-5*|w| << floor

  if (n <= 256) {
    // -------- symmetric column-coalesced matvec, f32 vectors --------
    int ic = t & 255, gchunk = t >> 8;   // output column, j-chunk (0..3)
    int jbeg = gchunk << 6;
    bool owner = (t < 256);
    int nrem = n - jbeg;                 // rows in this chunk (uniform per chunk)
    if (nrem > 64) nrem = 64;
    bool act = (ic < lda) && (nrem > 0);
    const float* colp = A + (size_t)jbeg * lda + ic;  // only deref'd when act

#define MV_SYM()                                                            \
    do {                                                                    \
      float part_ = 0.0f;                                                   \
      if (act) {                                                            \
        _Pragma("unroll 8")                                                 \
        for (int u_ = 0; u_ < nrem; u_++)                                   \
          part_ += colp[(size_t)u_ * lda] * rvs[jbeg + u_];                 \
      }                                                                     \
      pw[gchunk][ic] = part_;                                               \
    } while (0)

    // owner-register CG state (f64 scalars, tiny per-iter cost)
    double xr = 0.0, rr = 0.0, pr = 0.0, sr = 0.0, wr = 0.0;
    int gi = 0;
    if (owner) {
      rr = (ic < n) ? 1.0 : 0.0;
      if (ic < n) gi = g[s * NA + off + ic];
      rvs[ic] = (float)rr;
    }
    __syncthreads();

    // w = A r (r = 1)
    MV_SYM();
    __syncthreads();
    if (owner) {
      wr = (double)(((pw[0][ic] + pw[1][ic]) + pw[2][ic]) + pw[3][ic]);
      double g1 = 0.0, g2 = 0.0;
      if (ic < n) { g1 = rr * rr; g2 = rr * wr; }
#pragma unroll
      for (int m = 32; m > 0; m >>= 1) {
        g1 += __shfl_xor(g1, m, 64);
        g2 += __shfl_xor(g2, m, 64);
      }
      if (lane == 0) { redC[wid] = g1; redD[wid] = g2; }
    }
    __syncthreads();
    double gam = (double)n;
    double d1 = ((redD[0] + redD[1]) + redD[2]) + redD[3];  // (w,r), r=1
    double alpha = gam / d1;
    if (owner && ic < n) { pr = rr; sr = wr; }

    for (int iter = 0; iter < 50; iter++) {
      if (owner && ic < n) {
        xr += alpha * pr;
        rr -= alpha * sr;
        rvs[ic] = (float)rr;
      }
      __syncthreads();      // rvs ready
      MV_SYM();
      __syncthreads();      // pw ready
      if (owner) {
        wr = (double)(((pw[0][ic] + pw[1][ic]) + pw[2][ic]) + pw[3][ic]);
        double g1 = 0.0, g2 = 0.0;
        if (ic < n) { g1 = rr * rr; g2 = rr * wr; }
#pragma unroll
        for (int m = 32; m > 0; m >>= 1) {
          g1 += __shfl_xor(g1, m, 64);
          g2 += __shfl_xor(g2, m, 64);
        }
        if (lane == 0) { redC[wid] = g1; redD[wid] = g2; }
      }
      __syncthreads();      // red ready
      double gamn = ((redC[0] + redC[1]) + redC[2]) + redC[3];
      double delt = ((redD[0] + redD[1]) + redD[2]) + redD[3];
      if (gamn < tol) break;  // uniform across block
      double beta = gamn / gam;
      alpha = gamn / (delt - beta * gamn / alpha);
      gam = gamn;
      if (owner && ic < n) {
        pr = rr + beta * pr;
        sr = wr + beta * sr;
      }
    }
    __syncthreads();  // protect redC reuse (all (g)-phase readers done)
    if (owner) {
      double dp = (ic < n) ? xr : 0.0;
#pragma unroll
      for (int m = 32; m > 0; m >>= 1) dp += __shfl_xor(dp, m, 64);
      if (lane == 0) redC[wid] = dp;
    }
    __syncthreads();
    double denom = ((redC[0] + redC[1]) + redC[2]) + redC[3];
    if (owner && ic < n) walloc[s * NA + gi] = xr / denom;
#undef MV_SYM
  } else {
    // -------- fallback: 4-row grouped-ILP matvec, f32 vectors --------
    if (t < n) gs[t] = g[s * NA + off + t];
    rv[t] = (t < n) ? 1.0f : 0.0f;  // pad region zeroed: matvec reads rv up to lda
    if (t < n) xv[t] = 0.0f;
    __syncthreads();
    // w = A r
    FB_MATVEC();
    __syncthreads();
    double gam = (double)n;  // (r,r) with r=1
    double d1, d2;
    blk_sum2_1024((t < n) ? (double)wv[t] : 0.0, 0.0, redA, redB, d1, d2);  // (w,r), r=1
    double alpha = gam / d1;
    if (t < n) { pv[t] = rv[t]; sv[t] = wv[t]; }
    for (int iter = 0; iter < 50; iter++) {
      float af = (float)alpha;
      if (t < n) {
        xv[t] += af * pv[t];
        rv[t] -= af * sv[t];
      }
      __syncthreads();
      // w = A r
      FB_MATVEC();
      __syncthreads();
      double g1 = 0.0, g2 = 0.0;
      if (t < n) {
        double rt = (double)rv[t];
        g1 = rt * rt;
        g2 = rt * (double)wv[t];
      }
      double gamn, delt;
      blk_sum2_1024(g1, g2, redA, redB, gamn, delt);
      if (gamn < tol) break;  // uniform across block
      double beta = gamn / gam;
      alpha = gamn / (delt - beta * gamn / alpha);
      gam = gamn;
      float bf = (float)beta;
      if (t < n) {
        pv[t] = rv[t] + bf * pv[t];
        sv[t] = wv[t] + bf * sv[t];
      }
    }
    double dp = (t < n) ? (double)xv[t] : 0.0;
    double d3, d4;
    blk_sum2_1024(dp, 0.0, redA, redB, d3, d4);
    if (t < n) walloc[s * NA + gs[t]] = (double)xv[t] / d3;
  }
}

// Fallback (ws too small for compact B): R5's full-row CG — verified PASS.
__global__ __launch_bounds__(1024) void k_cg_full(const float* __restrict__ cov,
                                                  const int* __restrict__ g, const int* __restrict__ cnt,
                                                  const int* __restrict__ off5, double* __restrict__ walloc) {
  int w = blockIdx.x;
  int s = w / NK, k = w % NK;
  int n = cnt[s * NK + k];
  if (n == 0) return;
  int off = off5[s * NK + k];
  const float* covS = cov + (size_t)s * NA * NA;
  __shared__ double pfull[NA];
  __shared__ double xv[NA], rv[NA], pv[NA], ap[NA];
  __shared__ int gs[NA];
  __shared__ double red16[16];
  int t = threadIdx.x, lane = t & 63, wid = t >> 6;
  if (t < n) {
    gs[t] = g[s * NA + off + t];
    xv[t] = 0.0; rv[t] = 1.0; pv[t] = 1.0;
  }
  double rr = (double)n;
  __syncthreads();
  for (int iter = 0; iter < 100; iter++) {
    pfull[t] = 0.0;
    __syncthreads();
    if (t < n) pfull[gs[t]] = pv[t];
    __syncthreads();
    for (int i = wid; i < n; i += 16) {
      const float* row = covS + (size_t)gs[i] * NA;
      double acc = 0.0;
#pragma unroll
      for (int c = 0; c < 16; c++) {
        int j = lane + (c << 6);
        acc += (double)row[j] * pfull[j];
      }
      acc = wave_reduce64(acc);
      if (lane == 0) ap[i] = acc;
    }
    __syncthreads();
    double pp = (t < n) ? pv[t] * ap[t] : 0.0;
    double pap = blk_sum_1024(pp, red16);
    double alpha = rr / pap;
    double rp = 0.0;
    if (t < n) {
      xv[t] += alpha * pv[t];
      double rn = rv[t] - alpha * ap[t];
      rv[t] = rn;
      rp = rn * rn;
    }
    double rrn = blk_sum_1024(rp, red16);
    if (rrn < 1e-20 * (double)n) break;
    double beta = rrn / rr;
    rr = rrn;
    if (t < n) pv[t] = rv[t] + beta * pv[t];
    __syncthreads();
  }
  double dp = (t < n) ? xv[t] : 0.0;
  double denom = blk_sum_1024(dp, red16);
  if (t < n) walloc[s * NA + gs[t]] = xv[t] / denom;
}

__global__ __launch_bounds__(256) void k_intery(const float* __restrict__ cov, const double* __restrict__ walloc,
                                                const int* __restrict__ g, const int* __restrict__ cnt,
                                                const int* __restrict__ off5, double* __restrict__ y2) {
  int w = blockIdx.x;  // 160
  int s = w / 20, rem = w % 20, k = rem / 4, seg = rem % 4;
  int n = cnt[s * NK + k], off = off5[s * NK + k];
  int t = threadIdx.x;
  __shared__ int gsl[NA];
  __shared__ double wl[NA];
  for (int i = t; i < n; i += 256) {
    int a = g[s * NA + off + i];
    gsl[i] = a;
    wl[i] = walloc[s * NA + a];
  }
  __syncthreads();
  int j = seg * 256 + t;
  const float* covS = cov + (size_t)s * NA * NA;
  double acc = 0.0;
  for (int i = 0; i < n; i++) acc += wl[i] * (double)covS[(size_t)gsl[i] * NA + j];
  y2[((size_t)s * NK + k) * NA + j] = acc;
}

__global__ __launch_bounds__(256) void k_icov(const double* __restrict__ y2, const double* __restrict__ walloc,
                                              const int* __restrict__ ixs, double* __restrict__ w_inter) {
  int s = blockIdx.x, t = threadIdx.x;
  __shared__ double red4[4];
  __shared__ double ic[NK * NK];
  for (int k = 0; k < NK; k++) {
    double p0 = 0, p1 = 0, p2 = 0, p3 = 0, p4 = 0;
    for (int j = t; j < NA; j += 256) {
      double v = y2[((size_t)s * NK + k) * NA + j] * walloc[s * NA + j];
      int c = ixs[s * NA + j];
      p0 += (c == 0) ? v : 0.0;
      p1 += (c == 1) ? v : 0.0;
      p2 += (c == 2) ? v : 0.0;
      p3 += (c == 3) ? v : 0.0;
      p4 += (c == 4) ? v : 0.0;
    }
    double q0 = blk_sum_256(p0, red4);
    double q1 = blk_sum_256(p1, red4);
    double q2 = blk_sum_256(p2, red4);
    double q3 = blk_sum_256(p3, red4);
    double q4 = blk_sum_256(p4, red4);
    if (t == 0) {
      ic[k * NK + 0] = q0; ic[k * NK + 1] = q1; ic[k * NK + 2] = q2;
      ic[k * NK + 3] = q3; ic[k * NK + 4] = q4;
    }
  }
  __syncthreads();
  if (t == 0) {
    double M[NK * NK], b[NK], z[NK];
    for (int i = 0; i < NK * NK; i++) M[i] = ic[i];
    for (int i = 0; i < NK; i++) b[i] = 1.0;
    for (int c = 0; c < NK; c++) {
      int pr = c;
      double mb = fabs(M[c * NK + c]);
      for (int r = c + 1; r < NK; r++) {
        double a = fabs(M[r * NK + c]);
        if (a > mb) { mb = a; pr = r; }
      }
      if (pr != c) {
        for (int cc = 0; cc < NK; cc++) {
          double tmp = M[c * NK + cc]; M[c * NK + cc] = M[pr * NK + cc]; M[pr * NK + cc] = tmp;
        }
        double tb = b[c]; b[c] = b[pr]; b[pr] = tb;
      }
      double piv = M[c * NK + c];
      for (int r = c + 1; r < NK; r++) {
        double f = M[r * NK + c] / piv;
        for (int cc = c; cc < NK; cc++) M[r * NK + cc] -= f * M[c * NK + cc];
        b[r] -= f * b[c];
      }
    }
    for (int r = NK - 1; r >= 0; r--) {
      double acc = b[r];
      for (int cc = r + 1; cc < NK; cc++) acc -= M[r * NK + cc] * z[cc];
      z[r] = acc / M[r * NK + r];
    }
    double ssum = z[0] + z[1] + z[2] + z[3] + z[4];
    for (int k = 0; k < NK; k++) w_inter[s * NK + k] = z[k] / ssum;
  }
}

__global__ __launch_bounds__(256) void k_final(const double* __restrict__ walloc, const double* __restrict__ w_inter,
                                               const int* __restrict__ ixs, float* __restrict__ out) {
  int gid = blockIdx.x * 256 + threadIdx.x;
  if (gid >= NS * NA) return;
  int s = gid >> 10;
  out[gid] = (float)(walloc[gid] * w_inter[s * NK + ixs[gid]]);
}

// ---------------- launch ----------------
extern "C" void kernel_launch(void* const* d_in, const int* in_sizes, int n_in,
                              void* d_out, int out_size, void* d_ws, size_t ws_size,
                              hipStream_t stream) {
  const float* cov = (const float*)d_in[0];
  float* out = (float*)d_out;
  char* ws = (char*)d_ws;
  size_t o = 0;
  auto alloc = [&](size_t bytes) {
    size_t cur = o;
    o += (bytes + 255) & ~(size_t)255;
    return cur;
  };
  double* C = (double*)(ws + alloc((size_t)NS * NK * NA * 8));
  double* y2 = (double*)(ws + alloc((size_t)NS * NK * NA * 8));
  double* pU = (double*)(ws + alloc((size_t)256 * NK * NA * 8));  // 10.5 MB partials
  double* rstd = (double*)(ws + alloc((size_t)NS * NA * 8));
  double* xn = (double*)(ws + alloc((size_t)NS * NA * 8));
  double* mind = (double*)(ws + alloc((size_t)NS * NA * 8));
  double* walloc = (double*)(ws + alloc((size_t)NS * NA * 8));
  int* ixs = (int*)(ws + alloc((size_t)NS * NA * 4));
  int* g = (int*)(ws + alloc((size_t)NS * NA * 4));
  int* cnt = (int*)(ws + alloc((size_t)NS * NK * 4));
  int* off5 = (int*)(ws + alloc((size_t)NS * NK * 4));
  int* boff = (int*)(ws + alloc((size_t)NS * NK * 4));
  int* conv = (int*)(ws + alloc((size_t)NS * 4));
  double* pot = (double*)(ws + alloc((size_t)NS * 8));
  double* w_inter = (double*)(ws + alloc((size_t)NS * NK * 8));
  size_t bcomp_off = alloc(NS * SSTRIDE * 4);  // 35.7 MB padded blocks, guarded
  float* Bcomp = (float*)(ws + bcomp_off);
  bool use_compact = (ws_size >= o);  // launch-time constant: same graph every call
  (void)in_sizes; (void)n_in; (void)out_size;

  InitIdx ii;
  compute_init_indices(ii);  // data-independent, identical every call

  k_pre<<<553, 256, 0, stream>>>(cov, rstd, xn, C, ii, pot, conv);
  for (int it = 0; it < MAXIT; it++) {
    k_assignA<<<256, 1024, 0, stream>>>(cov, rstd, xn, C, conv, ixs, mind, pU);
    k_updateB<<<32, 256, 0, stream>>>(pU, rstd, ixs, mind, C, pot, conv);
  }
  k_members<<<8, 256, 0, stream>>>(ixs, g, cnt, off5, boff);
  if (use_compact) {
    k_gatherB<<<40, 1024, 0, stream>>>(cov, g, cnt, off5, boff, Bcomp);
    k_cg_comp<<<40, 1024, 0, stream>>>(Bcomp, g, cnt, off5, boff, walloc);
  } else {
    k_cg_full<<<40, 1024, 0, stream>>>(cov, g, cnt, off5, walloc);
  }
  k_intery<<<160, 256, 0, stream>>>(cov, walloc, g, cnt, off5, y2);
  k_icov<<<8, 256, 0, stream>>>(y2, walloc, ixs, w_inter);
  k_final<<<32, 256, 0, stream>>>(walloc, w_inter, ixs, out);
}

// Round 10
// 794.427 us; speedup vs baseline: 1.3504x; 1.1821x over previous
//
#include <hip/hip_runtime.h>
#include <stdint.h>
#include <math.h>
#include <algorithm>

#define NS 8
#define NA 1024
#define NK 5
#define MAXIT 30
#define TOLER 1e-5
#define SSTRIDE ((size_t)NA * NA + 64 * NA)  // padded per-sample Bcomp stride (floats)

// ---------------- host-side threefry-2x32 (JAX-compatible) ----------------
static inline void tf2x32(uint32_t k0, uint32_t k1, uint32_t c0, uint32_t c1,
                          uint32_t& o0, uint32_t& o1) {
  uint32_t ks2 = k0 ^ k1 ^ 0x1BD11BDAu;
  uint32_t x0 = c0 + k0, x1 = c1 + k1;
  auto rot = [](uint32_t x, int r) { return (x << r) | (x >> (32 - r)); };
  auto R4 = [&](int r0, int r1, int r2, int r3) {
    x0 += x1; x1 = rot(x1, r0); x1 ^= x0;
    x0 += x1; x1 = rot(x1, r1); x1 ^= x0;
    x0 += x1; x1 = rot(x1, r2); x1 ^= x0;
    x0 += x1; x1 = rot(x1, r3); x1 ^= x0;
  };
  R4(13, 15, 26, 6);  x0 += k1;  x1 += ks2 + 1u;
  R4(17, 29, 16, 24); x0 += ks2; x1 += k0 + 2u;
  R4(13, 15, 26, 6);  x0 += k0;  x1 += k1 + 3u;
  R4(17, 29, 16, 24); x0 += k1;  x1 += ks2 + 4u;
  R4(13, 15, 26, 6);  x0 += ks2; x1 += k0 + 5u;
  o0 = x0; o1 = x1;
}

struct InitIdx { int v[NS * NK]; };

// jax_threefry_partitionable=True semantics (verified R3/R5-R8: PASS)
static void compute_init_indices(InitIdx& out) {
  const uint32_t rk0 = 0, rk1 = 42;
  for (int s = 0; s < NS; s++) {
    uint32_t k0, k1;
    tf2x32(rk0, rk1, 0u, (uint32_t)s, k0, k1);
    uint32_t sk0, sk1;
    tf2x32(k0, k1, 0u, 1u, sk0, sk1);
    uint32_t bits[NA];
    for (int i = 0; i < NA; i++) {
      uint32_t b0, b1;
      tf2x32(sk0, sk1, 0u, (uint32_t)i, b0, b1);
      bits[i] = b0 ^ b1;
    }
    int idx[NA];
    for (int i = 0; i < NA; i++) idx[i] = i;
    std::stable_sort(idx, idx + NA, [&](int x, int y) { return bits[x] < bits[y]; });
    for (int c = 0; c < NK; c++) out.v[s * NK + c] = idx[c];
  }
}

// ---------------- device helpers ----------------
__device__ __forceinline__ double wave_reduce64(double v) {
#pragma unroll
  for (int m = 32; m > 0; m >>= 1) v += __shfl_xor(v, m, 64);
  return v;
}

__device__ __forceinline__ float wave_reduce64f(float v) {
#pragma unroll
  for (int m = 32; m > 0; m >>= 1) v += __shfl_xor(v, m, 64);
  return v;
}

__device__ __forceinline__ double blk_sum_1024(double v, double* red16) {
  double w = wave_reduce64(v);
  if ((threadIdx.x & 63) == 0) red16[threadIdx.x >> 6] = w;
  __syncthreads();
  double tot = 0.0;
#pragma unroll
  for (int i = 0; i < 16; i++) tot += red16[i];
  __syncthreads();
  return tot;
}

__device__ __forceinline__ double blk_sum_256(double v, double* red4) {
  double w = wave_reduce64(v);
  if ((threadIdx.x & 63) == 0) red4[threadIdx.x >> 6] = w;
  __syncthreads();
  double tot = red4[0] + red4[1] + red4[2] + red4[3];
  __syncthreads();
  return tot;
}

// Fused dual block-sum (1024 thr): one LDS pass, one barrier pair, deterministic.
__device__ __forceinline__ void blk_sum2_1024(double a, double b, double* redA, double* redB,
                                              double& ra, double& rb) {
#pragma unroll
  for (int m = 32; m > 0; m >>= 1) {
    a += __shfl_xor(a, m, 64);
    b += __shfl_xor(b, m, 64);
  }
  if ((threadIdx.x & 63) == 0) {
    redA[threadIdx.x >> 6] = a;
    redB[threadIdx.x >> 6] = b;
  }
  __syncthreads();
  ra = 0.0; rb = 0.0;
#pragma unroll
  for (int i = 0; i < 16; i++) { ra += redA[i]; rb += redB[i]; }
  __syncthreads();
}

// ---------------- fused pre-kernel: xn + centers_init + rstd array + state ----------------
// blocks 0..511: xn (inline rstd); 512..551: centers_init; 552: rstd[]+pot+conv.
__global__ __launch_bounds__(256) void k_pre(const float* __restrict__ cov, double* __restrict__ rstd,
                                             double* __restrict__ xn, double* __restrict__ C,
                                             InitIdx ii, double* __restrict__ pot, int* __restrict__ conv) {
  int w = blockIdx.x;
  if (w < 512) {
    int s = w >> 6;
    __shared__ double rsh[NA];
    const float* covS = cov + (size_t)s * NA * NA;
    for (int j = threadIdx.x; j < NA; j += 256)
      rsh[j] = 1.0 / sqrt((double)covS[(size_t)j * NA + j]);
    __syncthreads();
    int lane = threadIdx.x & 63, wave = threadIdx.x >> 6;
    for (int q = 0; q < 4; q++) {
      int i = (w & 63) * 16 + wave * 4 + q;
      const float* row = covS + (size_t)i * NA;
      double acc = 0.0;
      for (int j = lane; j < NA; j += 64) {
        double v = (double)row[j] * rsh[j];
        acc += v * v;
      }
      acc = wave_reduce64(acc);
      if (lane == 0) {
        double ri = rsh[i];
        xn[s * NA + i] = acc * ri * ri;
      }
    }
  } else if (w < 552) {
    int w2 = w - 512;
    int s = w2 / NK, k = w2 % NK;
    int idx = ii.v[s * NK + k];
    const float* covS = cov + (size_t)s * NA * NA;
    double ri = 1.0 / sqrt((double)covS[(size_t)idx * NA + idx]);
    const float* row = covS + (size_t)idx * NA;
    for (int j = threadIdx.x; j < NA; j += 256) {
      double rj = 1.0 / sqrt((double)covS[(size_t)j * NA + j]);
      C[((size_t)s * NK + k) * NA + j] = (double)row[j] * ri * rj;
    }
  } else {
    int t = threadIdx.x;
    for (int gid = t; gid < NS * NA; gid += 256) {
      int s = gid >> 10, a = gid & 1023;
      rstd[gid] = 1.0 / sqrt((double)cov[(size_t)s * NA * NA + (size_t)a * NA + a]);
    }
    if (t < NS) { pot[t] = INFINITY; conv[t] = 0; }
  }
}

// ---------------- KMeans iteration: 2 launches, fused single cov pass ----------------
// R10: dot phase + partial-center-sum phase in FP32 (reference computes this
// entire phase in f32: corr, distances, matmuls). R9's f64 version passed with
// absmax 7.6e-06 -> no argmin decision is within f32 rounding of a tie, so f32
// preserves every assignment. Distances assembled in f64 from the f32 dots;
// cn/xn/mind/pot stay f64. Cs: 40->20 KB LDS. pU: f32 (halves traffic).
__global__ __launch_bounds__(1024) void k_assignA(const float* __restrict__ cov, const double* __restrict__ rstd,
                                                  const double* __restrict__ xn, const double* __restrict__ C,
                                                  const int* __restrict__ conv, int* __restrict__ ixs,
                                                  double* __restrict__ mind, float* __restrict__ pU) {
  int blk = blockIdx.x, s = blk >> 5, rblk = blk & 31;
  if (conv[s]) return;  // frozen: coherent via kernel-boundary ordering
  __shared__ float Cs[NK][NA];  // rstd_j-scaled centers, f32, 20 KB
  __shared__ double red16[16];
  __shared__ int bks[32];
  __shared__ float rlocf[32];
  int t = threadIdx.x, lane = t & 63, wid = t >> 6;
  double rj = rstd[s * NA + t];
  double sq[NK];
#pragma unroll
  for (int k = 0; k < NK; k++) {
    double c = C[((size_t)s * NK + k) * NA + t];
    Cs[k][t] = (float)(c * rj);
    sq[k] = c * c;
  }
  double cn[NK];
#pragma unroll
  for (int k = 0; k < NK; k++) cn[k] = blk_sum_1024(sq[k], red16);
  const float* covS = cov + (size_t)s * NA * NA;
#pragma unroll
  for (int r2 = 0; r2 < 2; r2++) {
    int il = wid * 2 + r2;          // 0..31
    int i = rblk * 32 + il;
    const float* row = covS + (size_t)i * NA;
    double xi = xn[s * NA + i];
    double ri = rstd[s * NA + i];
    float a0 = 0.f, a1 = 0.f, a2 = 0.f, a3 = 0.f, a4 = 0.f;
#pragma unroll
    for (int c = 0; c < 16; c++) {
      int j = lane + (c << 6);
      float cv = row[j];
      a0 += cv * Cs[0][j]; a1 += cv * Cs[1][j]; a2 += cv * Cs[2][j];
      a3 += cv * Cs[3][j]; a4 += cv * Cs[4][j];
    }
    a0 = wave_reduce64f(a0); a1 = wave_reduce64f(a1); a2 = wave_reduce64f(a2);
    a3 = wave_reduce64f(a3); a4 = wave_reduce64f(a4);
    if (lane == 0) {
      double dots[5] = {(double)a0, (double)a1, (double)a2, (double)a3, (double)a4};
      double best = INFINITY;
      int bk = 0;
#pragma unroll
      for (int k = 0; k < NK; k++) {
        double d = xi + cn[k] - 2.0 * ri * dots[k];
        if (d < 0.0) d = 0.0;
        if (d < best) { best = d; bk = k; }  // first-min like jnp.argmin
      }
      ixs[s * NA + i] = bk;
      mind[s * NA + i] = best;
      bks[il] = bk;
      rlocf[il] = (float)ri;
    }
  }
  __syncthreads();
  // partial center sums (f32): thread t owns column t; ascending il -> deterministic
  float c0 = 0.f, c1 = 0.f, c2 = 0.f, c3 = 0.f, c4 = 0.f;
#pragma unroll
  for (int il = 0; il < 32; il++) {
    int i = rblk * 32 + il;
    float v = covS[(size_t)i * NA + t] * rlocf[il];  // L2-hot coalesced re-read
    int k = bks[il];
    c0 += (k == 0) ? v : 0.0f;
    c1 += (k == 1) ? v : 0.0f;
    c2 += (k == 2) ? v : 0.0f;
    c3 += (k == 3) ? v : 0.0f;
    c4 += (k == 4) ? v : 0.0f;
  }
  float* p = pU + ((size_t)blk * NK) * NA;
  p[0 * NA + t] = c0; p[1 * NA + t] = c1; p[2 * NA + t] = c2;
  p[3 * NA + t] = c3; p[4 * NA + t] = c4;
}

__global__ __launch_bounds__(256) void k_updateB(const float* __restrict__ pU, const double* __restrict__ rstd,
                                                 const int* __restrict__ ixs, const double* __restrict__ mind,
                                                 double* __restrict__ C, double* __restrict__ pot,
                                                 int* __restrict__ conv) {
  int w = blockIdx.x, s = w >> 2, seg = w & 3, t = threadIdx.x;
  if (conv[s]) return;
  __shared__ double red4[4];
  double lc[NK] = {0, 0, 0, 0, 0};
#pragma unroll
  for (int q = 0; q < 4; q++) {
    int c = ixs[s * NA + q * 256 + t];
    lc[0] += (c == 0) ? 1.0 : 0.0;
    lc[1] += (c == 1) ? 1.0 : 0.0;
    lc[2] += (c == 2) ? 1.0 : 0.0;
    lc[3] += (c == 3) ? 1.0 : 0.0;
    lc[4] += (c == 4) ? 1.0 : 0.0;
  }
  double cntk[NK];
#pragma unroll
  for (int k = 0; k < NK; k++) cntk[k] = blk_sum_256(lc[k], red4);
  int j = seg * 256 + t;
  double rjj = rstd[s * NA + j];
  double* CS = C + (size_t)s * NK * NA;
#pragma unroll
  for (int k = 0; k < NK; k++) {
    double a = 0.0;
#pragma unroll
    for (int b = 0; b < 32; b++) {  // ascending b == ascending i: deterministic
      int blk = (s << 5) | b;
      a += (double)pU[((size_t)blk * NK + k) * NA + j];
    }
    if (cntk[k] > 0.0) CS[(size_t)k * NA + j] = a * rjj / cntk[k];
    // empty cluster: keep previous center
  }
  if (seg == 0) {
    double v = mind[s * NA + t] + mind[s * NA + 256 + t] +
               mind[s * NA + 512 + t] + mind[s * NA + 768 + t];
    double p = blk_sum_256(v, red4);
    if (t == 0) {
      double prev = pot[s];
      pot[s] = p;
      if (!(fabs(p - prev) >= TOLER)) conv[s] = 1;  // freeze (while-cond fails)
    }
  }
}

// ---------------- post-processing ----------------
__global__ __launch_bounds__(256) void k_members(const int* __restrict__ ixs, int* __restrict__ g,
                                                 int* __restrict__ cnt, int* __restrict__ off5,
                                                 int* __restrict__ boff) {
  int s = blockIdx.x, t = threadIdx.x;
  __shared__ int sc[NK][256];
  __shared__ int base[NK];
  const int* ix = ixs + s * NA;
  int my[4];
  int lc[NK] = {0, 0, 0, 0, 0};
#pragma unroll
  for (int q = 0; q < 4; q++) { my[q] = ix[t * 4 + q]; lc[my[q]]++; }
#pragma unroll
  for (int k = 0; k < NK; k++) sc[k][t] = lc[k];
  __syncthreads();
  for (int off = 1; off < 256; off <<= 1) {
    int v[NK];
#pragma unroll
    for (int k = 0; k < NK; k++) v[k] = (t >= off) ? sc[k][t - off] : 0;
    __syncthreads();
#pragma unroll
    for (int k = 0; k < NK; k++) sc[k][t] += v[k];
    __syncthreads();
  }
  if (t == 0) {
    int b = 0, bo = 0;
    for (int k = 0; k < NK; k++) {
      int tot = sc[k][255];
      base[k] = b;
      cnt[s * NK + k] = tot;
      off5[s * NK + k] = b;
      boff[s * NK + k] = bo;
      b += tot;
      bo += tot * ((tot + 63) & ~63);  // padded: lda = align64(n)
    }
  }
  __syncthreads();
  int pos[NK];
#pragma unroll
  for (int k = 0; k < NK; k++) pos[k] = base[k] + sc[k][t] - lc[k];
#pragma unroll
  for (int q = 0; q < 4; q++) {
    int k = my[q];
    int p = pos[k]++;
    g[s * NA + p] = t * 4 + q;  // stable ascending asset order within cluster
  }
}

// Compact gather, PADDED: lda = align64(n), zero-filled COLUMN pad, rows i<n only.
__global__ __launch_bounds__(1024) void k_gatherB(const float* __restrict__ cov, const int* __restrict__ g,
                                                  const int* __restrict__ cnt, const int* __restrict__ off5,
                                                  const int* __restrict__ boff, float* __restrict__ B) {
  int w = blockIdx.x;  // 40
  int s = w / NK, k = w % NK;
  int n = cnt[s * NK + k];
  if (n == 0) return;
  int lda = (n + 63) & ~63;
  int off = off5[s * NK + k];
  __shared__ int gs[NA];
  int t = threadIdx.x, lane = t & 63, wid = t >> 6;
  if (t < n) gs[t] = g[s * NA + off + t];
  __syncthreads();
  const float* covS = cov + (size_t)s * NA * NA;
  float* Bk = B + (size_t)s * SSTRIDE + (size_t)boff[s * NK + k];
  for (int i = wid; i < n; i += 16) {
    const float* row = covS + (size_t)gs[i] * NA;
    float* out = Bk + (size_t)i * lda;
    for (int j = lane; j < lda; j += 64) out[j] = (j < n) ? row[gs[j]] : 0.0f;
  }
}

// Chronopoulos-Gear CG on padded compact block. Sigma_cc x = 1.
// f32 vectors (R9, PASS 126.9us), f64 scalars/reductions. 4-row grouped-ILP
// fallback for n>256 (R8); symmetric column-coalesced path for n<=256 (R7).
#define FB_MATVEC()                                                         \
    do {                                                                    \
      for (int i0_ = wid; i0_ < n; i0_ += 64) {                             \
        int i1_ = i0_ + 16, i2_ = i0_ + 32, i3_ = i0_ + 48;                 \
        const float* r0_ = A + (size_t)i0_ * lda;                           \
        const float* r1_ = A + (size_t)(i1_ < n ? i1_ : 0) * lda;           \
        const float* r2_ = A + (size_t)(i2_ < n ? i2_ : 0) * lda;           \
        const float* r3_ = A + (size_t)(i3_ < n ? i3_ : 0) * lda;           \
        float a0_ = 0.0f, a1_ = 0.0f, a2_ = 0.0f, a3_ = 0.0f;               \
        _Pragma("unroll 4")                                                 \
        for (int c_ = 0; c_ < nch; c_++) {                                  \
          int j_ = lane + (c_ << 6);                                        \
          float f0_ = r0_[j_], f1_ = r1_[j_], f2_ = r2_[j_], f3_ = r3_[j_]; \
          float rj_ = rv[j_];                                               \
          a0_ += f0_ * rj_; a1_ += f1_ * rj_;                               \
          a2_ += f2_ * rj_; a3_ += f3_ * rj_;                               \
        }                                                                   \
        _Pragma("unroll")                                                   \
        for (int mm_ = 32; mm_ > 0; mm_ >>= 1) {                            \
          a0_ += __shfl_xor(a0_, mm_, 64);                                  \
          a1_ += __shfl_xor(a1_, mm_, 64);                                  \
          a2_ += __shfl_xor(a2_, mm_, 64);                                  \
          a3_ += __shfl_xor(a3_, mm_, 64);                                  \
        }                                                                   \
        if (lane == 0) {                                                    \
          wv[i0_] = a0_;                                                    \
          if (i1_ < n) wv[i1_] = a1_;                                       \
          if (i2_ < n) wv[i2_] = a2_;                                       \
          if (i3_ < n) wv[i3_] = a3_;                                       \
        }                                                                   \
      }                                                                     \
    } while (0)

__global__ __launch_bounds__(1024) void k_cg_comp(const float* __restrict__ B, const int* __restrict__ g,
                                                  const int* __restrict__ cnt, const int* __restrict__ off5,
                                                  const int* __restrict__ boff, double* __restrict__ walloc) {
  int w = blockIdx.x;  // 40
  int s = w / NK, k = w % NK;
  int n = cnt[s * NK + k];
  if (n == 0) return;
  int lda = (n + 63) & ~63;
  int nch = lda >> 6;
  int off = off5[s * NK + k];
  const float* A = B + (size_t)s * SSTRIDE + (size_t)boff[s * NK + k];
  __shared__ float xv[NA], rv[NA], pv[NA], sv[NA], wv[NA];
  __shared__ int gs[NA];
  __shared__ double redA[16], redB[16];
  __shared__ float rvs[256];
  __shared__ float pw[4][256];
  __shared__ double redC[4], redD[4];
  int t = threadIdx.x, lane = t & 63, wid = t >> 6;
  const double tol = 1e-10 * (double)n;  // rel resid 1e-5: err ~ kappa*1e-5*|w| << floor

  if (n <= 256) {
    // -------- symmetric column-coalesced matvec, f32 vectors --------
    int ic = t & 255, gchunk = t >> 8;   // output column, j-chunk (0..3)
    int jbeg = gchunk << 6;
    bool owner = (t < 256);
    int nrem = n - jbeg;                 // rows in this chunk (uniform per chunk)
    if (nrem > 64) nrem = 64;
    bool act = (ic < lda) && (nrem > 0);
    const float* colp = A + (size_t)jbeg * lda + ic;  // only deref'd when act

#define MV_SYM()                                                            \
    do {                                                                    \
      float part_ = 0.0f;                                                   \
      if (act) {                                                            \
        _Pragma("unroll 8")                                                 \
        for (int u_ = 0; u_ < nrem; u_++)                                   \
          part_ += colp[(size_t)u_ * lda] * rvs[jbeg + u_];                 \
      }                                                                     \
      pw[gchunk][ic] = part_;                                               \
    } while (0)

    // owner-register CG state (f64 scalars, tiny per-iter cost)
    double xr = 0.0, rr = 0.0, pr = 0.0, sr = 0.0, wr = 0.0;
    int gi = 0;
    if (owner) {
      rr = (ic < n) ? 1.0 : 0.0;
      if (ic < n) gi = g[s * NA + off + ic];
      rvs[ic] = (float)rr;
    }
    __syncthreads();

    // w = A r (r = 1)
    MV_SYM();
    __syncthreads();
    if (owner) {
      wr = (double)(((pw[0][ic] + pw[1][ic]) + pw[2][ic]) + pw[3][ic]);
      double g1 = 0.0, g2 = 0.0;
      if (ic < n) { g1 = rr * rr; g2 = rr * wr; }
#pragma unroll
      for (int m = 32; m > 0; m >>= 1) {
        g1 += __shfl_xor(g1, m, 64);
        g2 += __shfl_xor(g2, m, 64);
      }
      if (lane == 0) { redC[wid] = g1; redD[wid] = g2; }
    }
    __syncthreads();
    double gam = (double)n;
    double d1 = ((redD[0] + redD[1]) + redD[2]) + redD[3];  // (w,r), r=1
    double alpha = gam / d1;
    if (owner && ic < n) { pr = rr; sr = wr; }

    for (int iter = 0; iter < 50; iter++) {
      if (owner && ic < n) {
        xr += alpha * pr;
        rr -= alpha * sr;
        rvs[ic] = (float)rr;
      }
      __syncthreads();      // rvs ready
      MV_SYM();
      __syncthreads();      // pw ready
      if (owner) {
        wr = (double)(((pw[0][ic] + pw[1][ic]) + pw[2][ic]) + pw[3][ic]);
        double g1 = 0.0, g2 = 0.0;
        if (ic < n) { g1 = rr * rr; g2 = rr * wr; }
#pragma unroll
        for (int m = 32; m > 0; m >>= 1) {
          g1 += __shfl_xor(g1, m, 64);
          g2 += __shfl_xor(g2, m, 64);
        }
        if (lane == 0) { redC[wid] = g1; redD[wid] = g2; }
      }
      __syncthreads();      // red ready
      double gamn = ((redC[0] + redC[1]) + redC[2]) + redC[3];
      double delt = ((redD[0] + redD[1]) + redD[2]) + redD[3];
      if (gamn < tol) break;  // uniform across block
      double beta = gamn / gam;
      alpha = gamn / (delt - beta * gamn / alpha);
      gam = gamn;
      if (owner && ic < n) {
        pr = rr + beta * pr;
        sr = wr + beta * sr;
      }
    }
    __syncthreads();  // protect redC reuse (all (g)-phase readers done)
    if (owner) {
      double dp = (ic < n) ? xr : 0.0;
#pragma unroll
      for (int m = 32; m > 0; m >>= 1) dp += __shfl_xor(dp, m, 64);
      if (lane == 0) redC[wid] = dp;
    }
    __syncthreads();
    double denom = ((redC[0] + redC[1]) + redC[2]) + redC[3];
    if (owner && ic < n) walloc[s * NA + gi] = xr / denom;
#undef MV_SYM
  } else {
    // -------- fallback: 4-row grouped-ILP matvec, f32 vectors --------
    if (t < n) gs[t] = g[s * NA + off + t];
    rv[t] = (t < n) ? 1.0f : 0.0f;  // pad region zeroed: matvec reads rv up to lda
    if (t < n) xv[t] = 0.0f;
    __syncthreads();
    // w = A r
    FB_MATVEC();
    __syncthreads();
    double gam = (double)n;  // (r,r) with r=1
    double d1, d2;
    blk_sum2_1024((t < n) ? (double)wv[t] : 0.0, 0.0, redA, redB, d1, d2);  // (w,r), r=1
    double alpha = gam / d1;
    if (t < n) { pv[t] = rv[t]; sv[t] = wv[t]; }
    for (int iter = 0; iter < 50; iter++) {
      float af = (float)alpha;
      if (t < n) {
        xv[t] += af * pv[t];
        rv[t] -= af * sv[t];
      }
      __syncthreads();
      // w = A r
      FB_MATVEC();
      __syncthreads();
      double g1 = 0.0, g2 = 0.0;
      if (t < n) {
        double rt = (double)rv[t];
        g1 = rt * rt;
        g2 = rt * (double)wv[t];
      }
      double gamn, delt;
      blk_sum2_1024(g1, g2, redA, redB, gamn, delt);
      if (gamn < tol) break;  // uniform across block
      double beta = gamn / gam;
      alpha = gamn / (delt - beta * gamn / alpha);
      gam = gamn;
      float bf = (float)beta;
      if (t < n) {
        pv[t] = rv[t] + bf * pv[t];
        sv[t] = wv[t] + bf * sv[t];
      }
    }
    double dp = (t < n) ? (double)xv[t] : 0.0;
    double d3, d4;
    blk_sum2_1024(dp, 0.0, redA, redB, d3, d4);
    if (t < n) walloc[s * NA + gs[t]] = (double)xv[t] / d3;
  }
}

// Fallback (ws too small for compact B): R5's full-row CG — verified PASS.
__global__ __launch_bounds__(1024) void k_cg_full(const float* __restrict__ cov,
                                                  const int* __restrict__ g, const int* __restrict__ cnt,
                                                  const int* __restrict__ off5, double* __restrict__ walloc) {
  int w = blockIdx.x;
  int s = w / NK, k = w % NK;
  int n = cnt[s * NK + k];
  if (n == 0) return;
  int off = off5[s * NK + k];
  const float* covS = cov + (size_t)s * NA * NA;
  __shared__ double pfull[NA];
  __shared__ double xv[NA], rv[NA], pv[NA], ap[NA];
  __shared__ int gs[NA];
  __shared__ double red16[16];
  int t = threadIdx.x, lane = t & 63, wid = t >> 6;
  if (t < n) {
    gs[t] = g[s * NA + off + t];
    xv[t] = 0.0; rv[t] = 1.0; pv[t] = 1.0;
  }
  double rr = (double)n;
  __syncthreads();
  for (int iter = 0; iter < 100; iter++) {
    pfull[t] = 0.0;
    __syncthreads();
    if (t < n) pfull[gs[t]] = pv[t];
    __syncthreads();
    for (int i = wid; i < n; i += 16) {
      const float* row = covS + (size_t)gs[i] * NA;
      double acc = 0.0;
#pragma unroll
      for (int c = 0; c < 16; c++) {
        int j = lane + (c << 6);
        acc += (double)row[j] * pfull[j];
      }
      acc = wave_reduce64(acc);
      if (lane == 0) ap[i] = acc;
    }
    __syncthreads();
    double pp = (t < n) ? pv[t] * ap[t] : 0.0;
    double pap = blk_sum_1024(pp, red16);
    double alpha = rr / pap;
    double rp = 0.0;
    if (t < n) {
      xv[t] += alpha * pv[t];
      double rn = rv[t] - alpha * ap[t];
      rv[t] = rn;
      rp = rn * rn;
    }
    double rrn = blk_sum_1024(rp, red16);
    if (rrn < 1e-20 * (double)n) break;
    double beta = rrn / rr;
    rr = rrn;
    if (t < n) pv[t] = rv[t] + beta * pv[t];
    __syncthreads();
  }
  double dp = (t < n) ? xv[t] : 0.0;
  double denom = blk_sum_1024(dp, red16);
  if (t < n) walloc[s * NA + gs[t]] = xv[t] / denom;
}

__global__ __launch_bounds__(256) void k_intery(const float* __restrict__ cov, const double* __restrict__ walloc,
                                                const int* __restrict__ g, const int* __restrict__ cnt,
                                                const int* __restrict__ off5, double* __restrict__ y2) {
  int w = blockIdx.x;  // 160
  int s = w / 20, rem = w % 20, k = rem / 4, seg = rem % 4;
  int n = cnt[s * NK + k], off = off5[s * NK + k];
  int t = threadIdx.x;
  __shared__ int gsl[NA];
  __shared__ double wl[NA];
  for (int i = t; i < n; i += 256) {
    int a = g[s * NA + off + i];
    gsl[i] = a;
    wl[i] = walloc[s * NA + a];
  }
  __syncthreads();
  int j = seg * 256 + t;
  const float* covS = cov + (size_t)s * NA * NA;
  double acc = 0.0;
  for (int i = 0; i < n; i++) acc += wl[i] * (double)covS[(size_t)gsl[i] * NA + j];
  y2[((size_t)s * NK + k) * NA + j] = acc;
}

__global__ __launch_bounds__(256) void k_icov(const double* __restrict__ y2, const double* __restrict__ walloc,
                                              const int* __restrict__ ixs, double* __restrict__ w_inter) {
  int s = blockIdx.x, t = threadIdx.x;
  __shared__ double red4[4];
  __shared__ double ic[NK * NK];
  for (int k = 0; k < NK; k++) {
    double p0 = 0, p1 = 0, p2 = 0, p3 = 0, p4 = 0;
    for (int j = t; j < NA; j += 256) {
      double v = y2[((size_t)s * NK + k) * NA + j] * walloc[s * NA + j];
      int c = ixs[s * NA + j];
      p0 += (c == 0) ? v : 0.0;
      p1 += (c == 1) ? v : 0.0;
      p2 += (c == 2) ? v : 0.0;
      p3 += (c == 3) ? v : 0.0;
      p4 += (c == 4) ? v : 0.0;
    }
    double q0 = blk_sum_256(p0, red4);
    double q1 = blk_sum_256(p1, red4);
    double q2 = blk_sum_256(p2, red4);
    double q3 = blk_sum_256(p3, red4);
    double q4 = blk_sum_256(p4, red4);
    if (t == 0) {
      ic[k * NK + 0] = q0; ic[k * NK + 1] = q1; ic[k * NK + 2] = q2;
      ic[k * NK + 3] = q3; ic[k * NK + 4] = q4;
    }
  }
  __syncthreads();
  if (t == 0) {
    double M[NK * NK], b[NK], z[NK];
    for (int i = 0; i < NK * NK; i++) M[i] = ic[i];
    for (int i = 0; i < NK; i++) b[i] = 1.0;
    for (int c = 0; c < NK; c++) {
      int pr = c;
      double mb = fabs(M[c * NK + c]);
      for (int r = c + 1; r < NK; r++) {
        double a = fabs(M[r * NK + c]);
        if (a > mb) { mb = a; pr = r; }
      }
      if (pr != c) {
        for (int cc = 0; cc < NK; cc++) {
          double tmp = M[c * NK + cc]; M[c * NK + cc] = M[pr * NK + cc]; M[pr * NK + cc] = tmp;
        }
        double tb = b[c]; b[c] = b[pr]; b[pr] = tb;
      }
      double piv = M[c * NK + c];
      for (int r = c + 1; r < NK; r++) {
        double f = M[r * NK + c] / piv;
        for (int cc = c; cc < NK; cc++) M[r * NK + cc] -= f * M[c * NK + cc];
        b[r] -= f * b[c];
      }
    }
    for (int r = NK - 1; r >= 0; r--) {
      double acc = b[r];
      for (int cc = r + 1; cc < NK; cc++) acc -= M[r * NK + cc] * z[cc];
      z[r] = acc / M[r * NK + r];
    }
    double ssum = z[0] + z[1] + z[2] + z[3] + z[4];
    for (int k = 0; k < NK; k++) w_inter[s * NK + k] = z[k] / ssum;
  }
}

__global__ __launch_bounds__(256) void k_final(const double* __restrict__ walloc, const double* __restrict__ w_inter,
                                               const int* __restrict__ ixs, float* __restrict__ out) {
  int gid = blockIdx.x * 256 + threadIdx.x;
  if (gid >= NS * NA) return;
  int s = gid >> 10;
  out[gid] = (float)(walloc[gid] * w_inter[s * NK + ixs[gid]]);
}

// ---------------- launch ----------------
extern "C" void kernel_launch(void* const* d_in, const int* in_sizes, int n_in,
                              void* d_out, int out_size, void* d_ws, size_t ws_size,
                              hipStream_t stream) {
  const float* cov = (const float*)d_in[0];
  float* out = (float*)d_out;
  char* ws = (char*)d_ws;
  size_t o = 0;
  auto alloc = [&](size_t bytes) {
    size_t cur = o;
    o += (bytes + 255) & ~(size_t)255;
    return cur;
  };
  double* C = (double*)(ws + alloc((size_t)NS * NK * NA * 8));
  double* y2 = (double*)(ws + alloc((size_t)NS * NK * NA * 8));
  float* pU = (float*)(ws + alloc((size_t)256 * NK * NA * 4));  // 5.25 MB f32 partials
  double* rstd = (double*)(ws + alloc((size_t)NS * NA * 8));
  double* xn = (double*)(ws + alloc((size_t)NS * NA * 8));
  double* mind = (double*)(ws + alloc((size_t)NS * NA * 8));
  double* walloc = (double*)(ws + alloc((size_t)NS * NA * 8));
  int* ixs = (int*)(ws + alloc((size_t)NS * NA * 4));
  int* g = (int*)(ws + alloc((size_t)NS * NA * 4));
  int* cnt = (int*)(ws + alloc((size_t)NS * NK * 4));
  int* off5 = (int*)(ws + alloc((size_t)NS * NK * 4));
  int* boff = (int*)(ws + alloc((size_t)NS * NK * 4));
  int* conv = (int*)(ws + alloc((size_t)NS * 4));
  double* pot = (double*)(ws + alloc((size_t)NS * 8));
  double* w_inter = (double*)(ws + alloc((size_t)NS * NK * 8));
  size_t bcomp_off = alloc(NS * SSTRIDE * 4);  // 35.7 MB padded blocks, guarded
  float* Bcomp = (float*)(ws + bcomp_off);
  bool use_compact = (ws_size >= o);  // launch-time constant: same graph every call
  (void)in_sizes; (void)n_in; (void)out_size;

  InitIdx ii;
  compute_init_indices(ii);  // data-independent, identical every call

  k_pre<<<553, 256, 0, stream>>>(cov, rstd, xn, C, ii, pot, conv);
  for (int it = 0; it < MAXIT; it++) {
    k_assignA<<<256, 1024, 0, stream>>>(cov, rstd, xn, C, conv, ixs, mind, pU);
    k_updateB<<<32, 256, 0, stream>>>(pU, rstd, ixs, mind, C, pot, conv);
  }
  k_members<<<8, 256, 0, stream>>>(ixs, g, cnt, off5, boff);
  if (use_compact) {
    k_gatherB<<<40, 1024, 0, stream>>>(cov, g, cnt, off5, boff, Bcomp);
    k_cg_comp<<<40, 1024, 0, stream>>>(Bcomp, g, cnt, off5, boff, walloc);
  } else {
    k_cg_full<<<40, 1024, 0, stream>>>(cov, g, cnt, off5, walloc);
  }
  k_intery<<<160, 256, 0, stream>>>(cov, walloc, g, cnt, off5, y2);
  k_icov<<<8, 256, 0, stream>>>(y2, walloc, ixs, w_inter);
  k_final<<<32, 256, 0, stream>>>(walloc, w_inter, ixs, out);
}

// Round 11
// 671.505 us; speedup vs baseline: 1.5976x; 1.1831x over previous
//
#include <hip/hip_runtime.h>
#include <stdint.h>
#include <math.h>
#include <algorithm>

#define NS 8
#define NA 1024
#define NK 5
#define MAXIT 30
#define TOLER 1e-5
#define SSTRIDE ((size_t)NA * NA + 64 * NA)  // padded per-sample Bcomp stride (floats)

// ---------------- host-side threefry-2x32 (JAX-compatible) ----------------
static inline void tf2x32(uint32_t k0, uint32_t k1, uint32_t c0, uint32_t c1,
                          uint32_t& o0, uint32_t& o1) {
  uint32_t ks2 = k0 ^ k1 ^ 0x1BD11BDAu;
  uint32_t x0 = c0 + k0, x1 = c1 + k1;
  auto rot = [](uint32_t x, int r) { return (x << r) | (x >> (32 - r)); };
  auto R4 = [&](int r0, int r1, int r2, int r3) {
    x0 += x1; x1 = rot(x1, r0); x1 ^= x0;
    x0 += x1; x1 = rot(x1, r1); x1 ^= x0;
    x0 += x1; x1 = rot(x1, r2); x1 ^= x0;
    x0 += x1; x1 = rot(x1, r3); x1 ^= x0;
  };
  R4(13, 15, 26, 6);  x0 += k1;  x1 += ks2 + 1u;
  R4(17, 29, 16, 24); x0 += ks2; x1 += k0 + 2u;
  R4(13, 15, 26, 6);  x0 += k0;  x1 += k1 + 3u;
  R4(17, 29, 16, 24); x0 += k1;  x1 += ks2 + 4u;
  R4(13, 15, 26, 6);  x0 += ks2; x1 += k0 + 5u;
  o0 = x0; o1 = x1;
}

struct InitIdx { int v[NS * NK]; };

// jax_threefry_partitionable=True semantics (verified R3/R5-R8: PASS)
static void compute_init_indices(InitIdx& out) {
  const uint32_t rk0 = 0, rk1 = 42;
  for (int s = 0; s < NS; s++) {
    uint32_t k0, k1;
    tf2x32(rk0, rk1, 0u, (uint32_t)s, k0, k1);
    uint32_t sk0, sk1;
    tf2x32(k0, k1, 0u, 1u, sk0, sk1);
    uint32_t bits[NA];
    for (int i = 0; i < NA; i++) {
      uint32_t b0, b1;
      tf2x32(sk0, sk1, 0u, (uint32_t)i, b0, b1);
      bits[i] = b0 ^ b1;
    }
    int idx[NA];
    for (int i = 0; i < NA; i++) idx[i] = i;
    std::stable_sort(idx, idx + NA, [&](int x, int y) { return bits[x] < bits[y]; });
    for (int c = 0; c < NK; c++) out.v[s * NK + c] = idx[c];
  }
}

// ---------------- device helpers ----------------
__device__ __forceinline__ double wave_reduce64(double v) {
#pragma unroll
  for (int m = 32; m > 0; m >>= 1) v += __shfl_xor(v, m, 64);
  return v;
}

__device__ __forceinline__ float wave_reduce64f(float v) {
#pragma unroll
  for (int m = 32; m > 0; m >>= 1) v += __shfl_xor(v, m, 64);
  return v;
}

__device__ __forceinline__ double blk_sum_1024(double v, double* red16) {
  double w = wave_reduce64(v);
  if ((threadIdx.x & 63) == 0) red16[threadIdx.x >> 6] = w;
  __syncthreads();
  double tot = 0.0;
#pragma unroll
  for (int i = 0; i < 16; i++) tot += red16[i];
  __syncthreads();
  return tot;
}

__device__ __forceinline__ double blk_sum_256(double v, double* red4) {
  double w = wave_reduce64(v);
  if ((threadIdx.x & 63) == 0) red4[threadIdx.x >> 6] = w;
  __syncthreads();
  double tot = red4[0] + red4[1] + red4[2] + red4[3];
  __syncthreads();
  return tot;
}

// Fused dual block-sum (1024 thr): one LDS pass, one barrier pair, deterministic.
__device__ __forceinline__ void blk_sum2_1024(double a, double b, double* redA, double* redB,
                                              double& ra, double& rb) {
#pragma unroll
  for (int m = 32; m > 0; m >>= 1) {
    a += __shfl_xor(a, m, 64);
    b += __shfl_xor(b, m, 64);
  }
  if ((threadIdx.x & 63) == 0) {
    redA[threadIdx.x >> 6] = a;
    redB[threadIdx.x >> 6] = b;
  }
  __syncthreads();
  ra = 0.0; rb = 0.0;
#pragma unroll
  for (int i = 0; i < 16; i++) { ra += redA[i]; rb += redB[i]; }
  __syncthreads();
}

// ---------------- fused pre-kernel: xn + centers_init(+cn seed) + rstd + state ----------------
// blocks 0..511: xn (inline rstd); 512..551: centers_init + cnpart seed; 552: rstd[]+pot+conv.
__global__ __launch_bounds__(256) void k_pre(const float* __restrict__ cov, double* __restrict__ rstd,
                                             double* __restrict__ xn, double* __restrict__ C,
                                             InitIdx ii, double* __restrict__ pot, int* __restrict__ conv,
                                             double* __restrict__ cnpart) {
  int w = blockIdx.x;
  if (w < 512) {
    int s = w >> 6;
    __shared__ double rsh[NA];
    const float* covS = cov + (size_t)s * NA * NA;
    for (int j = threadIdx.x; j < NA; j += 256)
      rsh[j] = 1.0 / sqrt((double)covS[(size_t)j * NA + j]);
    __syncthreads();
    int lane = threadIdx.x & 63, wave = threadIdx.x >> 6;
    for (int q = 0; q < 4; q++) {
      int i = (w & 63) * 16 + wave * 4 + q;
      const float* row = covS + (size_t)i * NA;
      double acc = 0.0;
      for (int j = lane; j < NA; j += 64) {
        double v = (double)row[j] * rsh[j];
        acc += v * v;
      }
      acc = wave_reduce64(acc);
      if (lane == 0) {
        double ri = rsh[i];
        xn[s * NA + i] = acc * ri * ri;
      }
    }
  } else if (w < 552) {
    int w2 = w - 512;
    int s = w2 / NK, k = w2 % NK;
    int idx = ii.v[s * NK + k];
    const float* covS = cov + (size_t)s * NA * NA;
    double ri = 1.0 / sqrt((double)covS[(size_t)idx * NA + idx]);
    const float* row = covS + (size_t)idx * NA;
    __shared__ double red4[4];
    double acc = 0.0;
    for (int j = threadIdx.x; j < NA; j += 256) {
      double rj = 1.0 / sqrt((double)covS[(size_t)j * NA + j]);
      double c = (double)row[j] * ri * rj;
      C[((size_t)s * NK + k) * NA + j] = c;
      acc += c * c;
    }
    double tot = blk_sum_256(acc, red4);
    if (threadIdx.x == 0) {
      cnpart[((size_t)s * 4 + 0) * NK + k] = tot;
      cnpart[((size_t)s * 4 + 1) * NK + k] = 0.0;
      cnpart[((size_t)s * 4 + 2) * NK + k] = 0.0;
      cnpart[((size_t)s * 4 + 3) * NK + k] = 0.0;
    }
  } else {
    int t = threadIdx.x;
    for (int gid = t; gid < NS * NA; gid += 256) {
      int s = gid >> 10, a = gid & 1023;
      rstd[gid] = 1.0 / sqrt((double)cov[(size_t)s * NA * NA + (size_t)a * NA + a]);
    }
    if (t < NS) { pot[t] = INFINITY; conv[t] = 0; }
  }
}

// ---------------- KMeans iteration: 2 launches, fused single cov pass ----------------
// R11: assignA was LDS-pipe-bound (~370 LDS ops/thread). (1) cn hoisted out:
// computed once/iter in updateB (+ seeded by k_pre), assignA reads 4 f64
// partials; kills the 5x blk_sum_1024 staging (10 barriers + ~150 LDS ops).
// (2) two-row dot loop fused: each Cs[k][j] read ONCE, feeds both rows' FMAs
// (160 -> 80 ds_read). Butterflies stay f32 (R10).
__global__ __launch_bounds__(1024) void k_assignA(const float* __restrict__ cov, const double* __restrict__ rstd,
                                                  const double* __restrict__ xn, const double* __restrict__ C,
                                                  const double* __restrict__ cnpart,
                                                  const int* __restrict__ conv, int* __restrict__ ixs,
                                                  double* __restrict__ mind, float* __restrict__ pU) {
  int blk = blockIdx.x, s = blk >> 5, rblk = blk & 31;
  if (conv[s]) return;  // frozen: coherent via kernel-boundary ordering
  __shared__ float Cs[NK][NA];  // rstd_j-scaled centers, f32, 20 KB
  __shared__ int bks[32];
  __shared__ float rlocf[32];
  int t = threadIdx.x, lane = t & 63, wid = t >> 6;
  double rj = rstd[s * NA + t];
#pragma unroll
  for (int k = 0; k < NK; k++) {
    double c = C[((size_t)s * NK + k) * NA + t];
    Cs[k][t] = (float)(c * rj);
  }
  double cn[NK];
#pragma unroll
  for (int k = 0; k < NK; k++)
    cn[k] = ((cnpart[((size_t)s * 4 + 0) * NK + k] + cnpart[((size_t)s * 4 + 1) * NK + k]) +
             cnpart[((size_t)s * 4 + 2) * NK + k]) + cnpart[((size_t)s * 4 + 3) * NK + k];
  const float* covS = cov + (size_t)s * NA * NA;
  int i0 = rblk * 32 + wid * 2, i1 = i0 + 1;
  double xi0 = xn[s * NA + i0], ri0 = rstd[s * NA + i0];
  double xi1 = xn[s * NA + i1], ri1 = rstd[s * NA + i1];
  const float* row0 = covS + (size_t)i0 * NA;
  const float* row1 = covS + (size_t)i1 * NA;
  __syncthreads();  // Cs ready
  float a00 = 0.f, a01 = 0.f, a02 = 0.f, a03 = 0.f, a04 = 0.f;
  float a10 = 0.f, a11 = 0.f, a12 = 0.f, a13 = 0.f, a14 = 0.f;
#pragma unroll
  for (int c = 0; c < 16; c++) {
    int j = lane + (c << 6);
    float cv0 = row0[j], cv1 = row1[j];
    float q0 = Cs[0][j], q1 = Cs[1][j], q2 = Cs[2][j], q3 = Cs[3][j], q4 = Cs[4][j];
    a00 += cv0 * q0; a01 += cv0 * q1; a02 += cv0 * q2; a03 += cv0 * q3; a04 += cv0 * q4;
    a10 += cv1 * q0; a11 += cv1 * q1; a12 += cv1 * q2; a13 += cv1 * q3; a14 += cv1 * q4;
  }
  a00 = wave_reduce64f(a00); a01 = wave_reduce64f(a01); a02 = wave_reduce64f(a02);
  a03 = wave_reduce64f(a03); a04 = wave_reduce64f(a04);
  a10 = wave_reduce64f(a10); a11 = wave_reduce64f(a11); a12 = wave_reduce64f(a12);
  a13 = wave_reduce64f(a13); a14 = wave_reduce64f(a14);
  if (lane == 0) {
    double d0[5] = {(double)a00, (double)a01, (double)a02, (double)a03, (double)a04};
    double d1[5] = {(double)a10, (double)a11, (double)a12, (double)a13, (double)a14};
    double best0 = INFINITY, best1 = INFINITY;
    int bk0 = 0, bk1 = 0;
#pragma unroll
    for (int k = 0; k < NK; k++) {
      double dd0 = xi0 + cn[k] - 2.0 * ri0 * d0[k];
      if (dd0 < 0.0) dd0 = 0.0;
      if (dd0 < best0) { best0 = dd0; bk0 = k; }  // first-min like jnp.argmin
      double dd1 = xi1 + cn[k] - 2.0 * ri1 * d1[k];
      if (dd1 < 0.0) dd1 = 0.0;
      if (dd1 < best1) { best1 = dd1; bk1 = k; }
    }
    ixs[s * NA + i0] = bk0; mind[s * NA + i0] = best0;
    ixs[s * NA + i1] = bk1; mind[s * NA + i1] = best1;
    bks[wid * 2] = bk0; rlocf[wid * 2] = (float)ri0;
    bks[wid * 2 + 1] = bk1; rlocf[wid * 2 + 1] = (float)ri1;
  }
  __syncthreads();
  // partial center sums (f32): thread t owns column t; ascending il -> deterministic
  float c0 = 0.f, c1 = 0.f, c2 = 0.f, c3 = 0.f, c4 = 0.f;
#pragma unroll
  for (int il = 0; il < 32; il++) {
    int i = rblk * 32 + il;
    float v = covS[(size_t)i * NA + t] * rlocf[il];  // L2-hot coalesced re-read
    int k = bks[il];
    c0 += (k == 0) ? v : 0.0f;
    c1 += (k == 1) ? v : 0.0f;
    c2 += (k == 2) ? v : 0.0f;
    c3 += (k == 3) ? v : 0.0f;
    c4 += (k == 4) ? v : 0.0f;
  }
  float* p = pU + ((size_t)blk * NK) * NA;
  p[0 * NA + t] = c0; p[1 * NA + t] = c1; p[2 * NA + t] = c2;
  p[3 * NA + t] = c3; p[4 * NA + t] = c4;
}

__global__ __launch_bounds__(256) void k_updateB(const float* __restrict__ pU, const double* __restrict__ rstd,
                                                 const int* __restrict__ ixs, const double* __restrict__ mind,
                                                 double* __restrict__ C, double* __restrict__ pot,
                                                 int* __restrict__ conv, double* __restrict__ cnpart) {
  int w = blockIdx.x, s = w >> 2, seg = w & 3, t = threadIdx.x;
  if (conv[s]) return;
  __shared__ double red4[4];
  double lc[NK] = {0, 0, 0, 0, 0};
#pragma unroll
  for (int q = 0; q < 4; q++) {
    int c = ixs[s * NA + q * 256 + t];
    lc[0] += (c == 0) ? 1.0 : 0.0;
    lc[1] += (c == 1) ? 1.0 : 0.0;
    lc[2] += (c == 2) ? 1.0 : 0.0;
    lc[3] += (c == 3) ? 1.0 : 0.0;
    lc[4] += (c == 4) ? 1.0 : 0.0;
  }
  double cntk[NK];
#pragma unroll
  for (int k = 0; k < NK; k++) cntk[k] = blk_sum_256(lc[k], red4);
  int j = seg * 256 + t;
  double rjj = rstd[s * NA + j];
  double* CS = C + (size_t)s * NK * NA;
  double sq[NK];
#pragma unroll
  for (int k = 0; k < NK; k++) {
    double a = 0.0;
#pragma unroll
    for (int b = 0; b < 32; b++) {  // ascending b == ascending i: deterministic
      int blk = (s << 5) | b;
      a += (double)pU[((size_t)blk * NK + k) * NA + j];
    }
    double cval;
    if (cntk[k] > 0.0) {
      cval = a * rjj / cntk[k];
      CS[(size_t)k * NA + j] = cval;
    } else {
      cval = CS[(size_t)k * NA + j];  // empty cluster: keep previous center
    }
    sq[k] = cval * cval;
  }
  // per-segment cn partials (f64, deterministic butterfly) -> cnpart[s][seg][k]
#pragma unroll
  for (int k = 0; k < NK; k++) {
    double tot = blk_sum_256(sq[k], red4);
    if (t == 0) cnpart[((size_t)s * 4 + seg) * NK + k] = tot;
  }
  if (seg == 0) {
    double v = mind[s * NA + t] + mind[s * NA + 256 + t] +
               mind[s * NA + 512 + t] + mind[s * NA + 768 + t];
    double p = blk_sum_256(v, red4);
    if (t == 0) {
      double prev = pot[s];
      pot[s] = p;
      if (!(fabs(p - prev) >= TOLER)) conv[s] = 1;  // freeze (while-cond fails)
    }
  }
}

// ---------------- post-processing ----------------
__global__ __launch_bounds__(256) void k_members(const int* __restrict__ ixs, int* __restrict__ g,
                                                 int* __restrict__ cnt, int* __restrict__ off5,
                                                 int* __restrict__ boff) {
  int s = blockIdx.x, t = threadIdx.x;
  __shared__ int sc[NK][256];
  __shared__ int base[NK];
  const int* ix = ixs + s * NA;
  int my[4];
  int lc[NK] = {0, 0, 0, 0, 0};
#pragma unroll
  for (int q = 0; q < 4; q++) { my[q] = ix[t * 4 + q]; lc[my[q]]++; }
#pragma unroll
  for (int k = 0; k < NK; k++) sc[k][t] = lc[k];
  __syncthreads();
  for (int off = 1; off < 256; off <<= 1) {
    int v[NK];
#pragma unroll
    for (int k = 0; k < NK; k++) v[k] = (t >= off) ? sc[k][t - off] : 0;
    __syncthreads();
#pragma unroll
    for (int k = 0; k < NK; k++) sc[k][t] += v[k];
    __syncthreads();
  }
  if (t == 0) {
    int b = 0, bo = 0;
    for (int k = 0; k < NK; k++) {
      int tot = sc[k][255];
      base[k] = b;
      cnt[s * NK + k] = tot;
      off5[s * NK + k] = b;
      boff[s * NK + k] = bo;
      b += tot;
      bo += tot * ((tot + 63) & ~63);  // padded: lda = align64(n)
    }
  }
  __syncthreads();
  int pos[NK];
#pragma unroll
  for (int k = 0; k < NK; k++) pos[k] = base[k] + sc[k][t] - lc[k];
#pragma unroll
  for (int q = 0; q < 4; q++) {
    int k = my[q];
    int p = pos[k]++;
    g[s * NA + p] = t * 4 + q;  // stable ascending asset order within cluster
  }
}

// Compact gather, PADDED: lda = align64(n), zero-filled COLUMN pad, rows i<n only.
__global__ __launch_bounds__(1024) void k_gatherB(const float* __restrict__ cov, const int* __restrict__ g,
                                                  const int* __restrict__ cnt, const int* __restrict__ off5,
                                                  const int* __restrict__ boff, float* __restrict__ B) {
  int w = blockIdx.x;  // 40
  int s = w / NK, k = w % NK;
  int n = cnt[s * NK + k];
  if (n == 0) return;
  int lda = (n + 63) & ~63;
  int off = off5[s * NK + k];
  __shared__ int gs[NA];
  int t = threadIdx.x, lane = t & 63, wid = t >> 6;
  if (t < n) gs[t] = g[s * NA + off + t];
  __syncthreads();
  const float* covS = cov + (size_t)s * NA * NA;
  float* Bk = B + (size_t)s * SSTRIDE + (size_t)boff[s * NK + k];
  for (int i = wid; i < n; i += 16) {
    const float* row = covS + (size_t)gs[i] * NA;
    float* out = Bk + (size_t)i * lda;
    for (int j = lane; j < lda; j += 64) out[j] = (j < n) ? row[gs[j]] : 0.0f;
  }
}

// Chronopoulos-Gear CG on padded compact block. Sigma_cc x = 1.
// f32 vectors (R9, PASS 126.9us), f64 scalars/reductions. 4-row grouped-ILP
// fallback for n>256 (R8); symmetric column-coalesced path for n<=256 (R7).
#define FB_MATVEC()                                                         \
    do {                                                                    \
      for (int i0_ = wid; i0_ < n; i0_ += 64) {                             \
        int i1_ = i0_ + 16, i2_ = i0_ + 32, i3_ = i0_ + 48;                 \
        const float* r0_ = A + (size_t)i0_ * lda;                           \
        const float* r1_ = A + (size_t)(i1_ < n ? i1_ : 0) * lda;           \
        const float* r2_ = A + (size_t)(i2_ < n ? i2_ : 0) * lda;           \
        const float* r3_ = A + (size_t)(i3_ < n ? i3_ : 0) * lda;           \
        float a0_ = 0.0f, a1_ = 0.0f, a2_ = 0.0f, a3_ = 0.0f;               \
        _Pragma("unroll 4")                                                 \
        for (int c_ = 0; c_ < nch; c_++) {                                  \
          int j_ = lane + (c_ << 6);                                        \
          float f0_ = r0_[j_], f1_ = r1_[j_], f2_ = r2_[j_], f3_ = r3_[j_]; \
          float rj_ = rv[j_];                                               \
          a0_ += f0_ * rj_; a1_ += f1_ * rj_;                               \
          a2_ += f2_ * rj_; a3_ += f3_ * rj_;                               \
        }                                                                   \
        _Pragma("unroll")                                                   \
        for (int mm_ = 32; mm_ > 0; mm_ >>= 1) {                            \
          a0_ += __shfl_xor(a0_, mm_, 64);                                  \
          a1_ += __shfl_xor(a1_, mm_, 64);                                  \
          a2_ += __shfl_xor(a2_, mm_, 64);                                  \
          a3_ += __shfl_xor(a3_, mm_, 64);                                  \
        }                                                                   \
        if (lane == 0) {                                                    \
          wv[i0_] = a0_;                                                    \
          if (i1_ < n) wv[i1_] = a1_;                                       \
          if (i2_ < n) wv[i2_] = a2_;                                       \
          if (i3_ < n) wv[i3_] = a3_;                                       \
        }                                                                   \
      }                                                                     \
    } while (0)

__global__ __launch_bounds__(1024) void k_cg_comp(const float* __restrict__ B, const int* __restrict__ g,
                                                  const int* __restrict__ cnt, const int* __restrict__ off5,
                                                  const int* __restrict__ boff, double* __restrict__ walloc) {
  int w = blockIdx.x;  // 40
  int s = w / NK, k = w % NK;
  int n = cnt[s * NK + k];
  if (n == 0) return;
  int lda = (n + 63) & ~63;
  int nch = lda >> 6;
  int off = off5[s * NK + k];
  const float* A = B + (size_t)s * SSTRIDE + (size_t)boff[s * NK + k];
  __shared__ float xv[NA], rv[NA], pv[NA], sv[NA], wv[NA];
  __shared__ int gs[NA];
  __shared__ double redA[16], redB[16];
  __shared__ float rvs[256];
  __shared__ float pw[4][256];
  __shared__ double redC[4], redD[4];
  int t = threadIdx.x, lane = t & 63, wid = t >> 6;
  const double tol = 1e-10 * (double)n;  // rel resid 1e-5: err ~ kappa*1e-5*|w| << floor

  if (n <= 256) {
    // -------- symmetric column-coalesced matvec, f32 vectors --------
    int ic = t & 255, gchunk = t >> 8;   // output column, j-chunk (0..3)
    int jbeg = gchunk << 6;
    bool owner = (t < 256);
    int nrem = n - jbeg;                 // rows in this chunk (uniform per chunk)
    if (nrem > 64) nrem = 64;
    bool act = (ic < lda) && (nrem > 0);
    const float* colp = A + (size_t)jbeg * lda + ic;  // only deref'd when act

#define MV_SYM()                                                            \
    do {                                                                    \
      float part_ = 0.0f;                                                   \
      if (act) {                                                            \
        _Pragma("unroll 8")                                                 \
        for (int u_ = 0; u_ < nrem; u_++)                                   \
          part_ += colp[(size_t)u_ * lda] * rvs[jbeg + u_];                 \
      }                                                                     \
      pw[gchunk][ic] = part_;                                               \
    } while (0)

    // owner-register CG state (f64 scalars, tiny per-iter cost)
    double xr = 0.0, rr = 0.0, pr = 0.0, sr = 0.0, wr = 0.0;
    int gi = 0;
    if (owner) {
      rr = (ic < n) ? 1.0 : 0.0;
      if (ic < n) gi = g[s * NA + off + ic];
      rvs[ic] = (float)rr;
    }
    __syncthreads();

    // w = A r (r = 1)
    MV_SYM();
    __syncthreads();
    if (owner) {
      wr = (double)(((pw[0][ic] + pw[1][ic]) + pw[2][ic]) + pw[3][ic]);
      double g1 = 0.0, g2 = 0.0;
      if (ic < n) { g1 = rr * rr; g2 = rr * wr; }
#pragma unroll
      for (int m = 32; m > 0; m >>= 1) {
        g1 += __shfl_xor(g1, m, 64);
        g2 += __shfl_xor(g2, m, 64);
      }
      if (lane == 0) { redC[wid] = g1; redD[wid] = g2; }
    }
    __syncthreads();
    double gam = (double)n;
    double d1 = ((redD[0] + redD[1]) + redD[2]) + redD[3];  // (w,r), r=1
    double alpha = gam / d1;
    if (owner && ic < n) { pr = rr; sr = wr; }

    for (int iter = 0; iter < 50; iter++) {
      if (owner && ic < n) {
        xr += alpha * pr;
        rr -= alpha * sr;
        rvs[ic] = (float)rr;
      }
      __syncthreads();      // rvs ready
      MV_SYM();
      __syncthreads();      // pw ready
      if (owner) {
        wr = (double)(((pw[0][ic] + pw[1][ic]) + pw[2][ic]) + pw[3][ic]);
        double g1 = 0.0, g2 = 0.0;
        if (ic < n) { g1 = rr * rr; g2 = rr * wr; }
#pragma unroll
        for (int m = 32; m > 0; m >>= 1) {
          g1 += __shfl_xor(g1, m, 64);
          g2 += __shfl_xor(g2, m, 64);
        }
        if (lane == 0) { redC[wid] = g1; redD[wid] = g2; }
      }
      __syncthreads();      // red ready
      double gamn = ((redC[0] + redC[1]) + redC[2]) + redC[3];
      double delt = ((redD[0] + redD[1]) + redD[2]) + redD[3];
      if (gamn < tol) break;  // uniform across block
      double beta = gamn / gam;
      alpha = gamn / (delt - beta * gamn / alpha);
      gam = gamn;
      if (owner && ic < n) {
        pr = rr + beta * pr;
        sr = wr + beta * sr;
      }
    }
    __syncthreads();  // protect redC reuse (all (g)-phase readers done)
    if (owner) {
      double dp = (ic < n) ? xr : 0.0;
#pragma unroll
      for (int m = 32; m > 0; m >>= 1) dp += __shfl_xor(dp, m, 64);
      if (lane == 0) redC[wid] = dp;
    }
    __syncthreads();
    double denom = ((redC[0] + redC[1]) + redC[2]) + redC[3];
    if (owner && ic < n) walloc[s * NA + gi] = xr / denom;
#undef MV_SYM
  } else {
    // -------- fallback: 4-row grouped-ILP matvec, f32 vectors --------
    if (t < n) gs[t] = g[s * NA + off + t];
    rv[t] = (t < n) ? 1.0f : 0.0f;  // pad region zeroed: matvec reads rv up to lda
    if (t < n) xv[t] = 0.0f;
    __syncthreads();
    // w = A r
    FB_MATVEC();
    __syncthreads();
    double gam = (double)n;  // (r,r) with r=1
    double d1, d2;
    blk_sum2_1024((t < n) ? (double)wv[t] : 0.0, 0.0, redA, redB, d1, d2);  // (w,r), r=1
    double alpha = gam / d1;
    if (t < n) { pv[t] = rv[t]; sv[t] = wv[t]; }
    for (int iter = 0; iter < 50; iter++) {
      float af = (float)alpha;
      if (t < n) {
        xv[t] += af * pv[t];
        rv[t] -= af * sv[t];
      }
      __syncthreads();
      // w = A r
      FB_MATVEC();
      __syncthreads();
      double g1 = 0.0, g2 = 0.0;
      if (t < n) {
        double rt = (double)rv[t];
        g1 = rt * rt;
        g2 = rt * (double)wv[t];
      }
      double gamn, delt;
      blk_sum2_1024(g1, g2, redA, redB, gamn, delt);
      if (gamn < tol) break;  // uniform across block
      double beta = gamn / gam;
      alpha = gamn / (delt - beta * gamn / alpha);
      gam = gamn;
      float bf = (float)beta;
      if (t < n) {
        pv[t] = rv[t] + bf * pv[t];
        sv[t] = wv[t] + bf * sv[t];
      }
    }
    double dp = (t < n) ? (double)xv[t] : 0.0;
    double d3, d4;
    blk_sum2_1024(dp, 0.0, redA, redB, d3, d4);
    if (t < n) walloc[s * NA + gs[t]] = (double)xv[t] / d3;
  }
}

// Fallback (ws too small for compact B): R5's full-row CG — verified PASS.
__global__ __launch_bounds__(1024) void k_cg_full(const float* __restrict__ cov,
                                                  const int* __restrict__ g, const int* __restrict__ cnt,
                                                  const int* __restrict__ off5, double* __restrict__ walloc) {
  int w = blockIdx.x;
  int s = w / NK, k = w % NK;
  int n = cnt[s * NK + k];
  if (n == 0) return;
  int off = off5[s * NK + k];
  const float* covS = cov + (size_t)s * NA * NA;
  __shared__ double pfull[NA];
  __shared__ double xv[NA], rv[NA], pv[NA], ap[NA];
  __shared__ int gs[NA];
  __shared__ double red16[16];
  int t = threadIdx.x, lane = t & 63, wid = t >> 6;
  if (t < n) {
    gs[t] = g[s * NA + off + t];
    xv[t] = 0.0; rv[t] = 1.0; pv[t] = 1.0;
  }
  double rr = (double)n;
  __syncthreads();
  for (int iter = 0; iter < 100; iter++) {
    pfull[t] = 0.0;
    __syncthreads();
    if (t < n) pfull[gs[t]] = pv[t];
    __syncthreads();
    for (int i = wid; i < n; i += 16) {
      const float* row = covS + (size_t)gs[i] * NA;
      double acc = 0.0;
#pragma unroll
      for (int c = 0; c < 16; c++) {
        int j = lane + (c << 6);
        acc += (double)row[j] * pfull[j];
      }
      acc = wave_reduce64(acc);
      if (lane == 0) ap[i] = acc;
    }
    __syncthreads();
    double pp = (t < n) ? pv[t] * ap[t] : 0.0;
    double pap = blk_sum_1024(pp, red16);
    double alpha = rr / pap;
    double rp = 0.0;
    if (t < n) {
      xv[t] += alpha * pv[t];
      double rn = rv[t] - alpha * ap[t];
      rv[t] = rn;
      rp = rn * rn;
    }
    double rrn = blk_sum_1024(rp, red16);
    if (rrn < 1e-20 * (double)n) break;
    double beta = rrn / rr;
    rr = rrn;
    if (t < n) pv[t] = rv[t] + beta * pv[t];
    __syncthreads();
  }
  double dp = (t < n) ? xv[t] : 0.0;
  double denom = blk_sum_1024(dp, red16);
  if (t < n) walloc[s * NA + gs[t]] = xv[t] / denom;
}

__global__ __launch_bounds__(256) void k_intery(const float* __restrict__ cov, const double* __restrict__ walloc,
                                                const int* __restrict__ g, const int* __restrict__ cnt,
                                                const int* __restrict__ off5, double* __restrict__ y2) {
  int w = blockIdx.x;  // 160
  int s = w / 20, rem = w % 20, k = rem / 4, seg = rem % 4;
  int n = cnt[s * NK + k], off = off5[s * NK + k];
  int t = threadIdx.x;
  __shared__ int gsl[NA];
  __shared__ double wl[NA];
  for (int i = t; i < n; i += 256) {
    int a = g[s * NA + off + i];
    gsl[i] = a;
    wl[i] = walloc[s * NA + a];
  }
  __syncthreads();
  int j = seg * 256 + t;
  const float* covS = cov + (size_t)s * NA * NA;
  double acc = 0.0;
  for (int i = 0; i < n; i++) acc += wl[i] * (double)covS[(size_t)gsl[i] * NA + j];
  y2[((size_t)s * NK + k) * NA + j] = acc;
}

__global__ __launch_bounds__(256) void k_icov(const double* __restrict__ y2, const double* __restrict__ walloc,
                                              const int* __restrict__ ixs, double* __restrict__ w_inter) {
  int s = blockIdx.x, t = threadIdx.x;
  __shared__ double red4[4];
  __shared__ double ic[NK * NK];
  for (int k = 0; k < NK; k++) {
    double p0 = 0, p1 = 0, p2 = 0, p3 = 0, p4 = 0;
    for (int j = t; j < NA; j += 256) {
      double v = y2[((size_t)s * NK + k) * NA + j] * walloc[s * NA + j];
      int c = ixs[s * NA + j];
      p0 += (c == 0) ? v : 0.0;
      p1 += (c == 1) ? v : 0.0;
      p2 += (c == 2) ? v : 0.0;
      p3 += (c == 3) ? v : 0.0;
      p4 += (c == 4) ? v : 0.0;
    }
    double q0 = blk_sum_256(p0, red4);
    double q1 = blk_sum_256(p1, red4);
    double q2 = blk_sum_256(p2, red4);
    double q3 = blk_sum_256(p3, red4);
    double q4 = blk_sum_256(p4, red4);
    if (t == 0) {
      ic[k * NK + 0] = q0; ic[k * NK + 1] = q1; ic[k * NK + 2] = q2;
      ic[k * NK + 3] = q3; ic[k * NK + 4] = q4;
    }
  }
  __syncthreads();
  if (t == 0) {
    double M[NK * NK], b[NK], z[NK];
    for (int i = 0; i < NK * NK; i++) M[i] = ic[i];
    for (int i = 0; i < NK; i++) b[i] = 1.0;
    for (int c = 0; c < NK; c++) {
      int pr = c;
      double mb = fabs(M[c * NK + c]);
      for (int r = c + 1; r < NK; r++) {
        double a = fabs(M[r * NK + c]);
        if (a > mb) { mb = a; pr = r; }
      }
      if (pr != c) {
        for (int cc = 0; cc < NK; cc++) {
          double tmp = M[c * NK + cc]; M[c * NK + cc] = M[pr * NK + cc]; M[pr * NK + cc] = tmp;
        }
        double tb = b[c]; b[c] = b[pr]; b[pr] = tb;
      }
      double piv = M[c * NK + c];
      for (int r = c + 1; r < NK; r++) {
        double f = M[r * NK + c] / piv;
        for (int cc = c; cc < NK; cc++) M[r * NK + cc] -= f * M[c * NK + cc];
        b[r] -= f * b[c];
      }
    }
    for (int r = NK - 1; r >= 0; r--) {
      double acc = b[r];
      for (int cc = r + 1; cc < NK; cc++) acc -= M[r * NK + cc] * z[cc];
      z[r] = acc / M[r * NK + r];
    }
    double ssum = z[0] + z[1] + z[2] + z[3] + z[4];
    for (int k = 0; k < NK; k++) w_inter[s * NK + k] = z[k] / ssum;
  }
}

__global__ __launch_bounds__(256) void k_final(const double* __restrict__ walloc, const double* __restrict__ w_inter,
                                               const int* __restrict__ ixs, float* __restrict__ out) {
  int gid = blockIdx.x * 256 + threadIdx.x;
  if (gid >= NS * NA) return;
  int s = gid >> 10;
  out[gid] = (float)(walloc[gid] * w_inter[s * NK + ixs[gid]]);
}

// ---------------- launch ----------------
extern "C" void kernel_launch(void* const* d_in, const int* in_sizes, int n_in,
                              void* d_out, int out_size, void* d_ws, size_t ws_size,
                              hipStream_t stream) {
  const float* cov = (const float*)d_in[0];
  float* out = (float*)d_out;
  char* ws = (char*)d_ws;
  size_t o = 0;
  auto alloc = [&](size_t bytes) {
    size_t cur = o;
    o += (bytes + 255) & ~(size_t)255;
    return cur;
  };
  double* C = (double*)(ws + alloc((size_t)NS * NK * NA * 8));
  double* y2 = (double*)(ws + alloc((size_t)NS * NK * NA * 8));
  float* pU = (float*)(ws + alloc((size_t)256 * NK * NA * 4));  // 5.25 MB f32 partials
  double* rstd = (double*)(ws + alloc((size_t)NS * NA * 8));
  double* xn = (double*)(ws + alloc((size_t)NS * NA * 8));
  double* mind = (double*)(ws + alloc((size_t)NS * NA * 8));
  double* walloc = (double*)(ws + alloc((size_t)NS * NA * 8));
  int* ixs = (int*)(ws + alloc((size_t)NS * NA * 4));
  int* g = (int*)(ws + alloc((size_t)NS * NA * 4));
  int* cnt = (int*)(ws + alloc((size_t)NS * NK * 4));
  int* off5 = (int*)(ws + alloc((size_t)NS * NK * 4));
  int* boff = (int*)(ws + alloc((size_t)NS * NK * 4));
  int* conv = (int*)(ws + alloc((size_t)NS * 4));
  double* pot = (double*)(ws + alloc((size_t)NS * 8));
  double* w_inter = (double*)(ws + alloc((size_t)NS * NK * 8));
  double* cnpart = (double*)(ws + alloc((size_t)NS * 4 * NK * 8));
  size_t bcomp_off = alloc(NS * SSTRIDE * 4);  // 35.7 MB padded blocks, guarded
  float* Bcomp = (float*)(ws + bcomp_off);
  bool use_compact = (ws_size >= o);  // launch-time constant: same graph every call
  (void)in_sizes; (void)n_in; (void)out_size;

  InitIdx ii;
  compute_init_indices(ii);  // data-independent, identical every call

  k_pre<<<553, 256, 0, stream>>>(cov, rstd, xn, C, ii, pot, conv, cnpart);
  for (int it = 0; it < MAXIT; it++) {
    k_assignA<<<256, 1024, 0, stream>>>(cov, rstd, xn, C, cnpart, conv, ixs, mind, pU);
    k_updateB<<<32, 256, 0, stream>>>(pU, rstd, ixs, mind, C, pot, conv, cnpart);
  }
  k_members<<<8, 256, 0, stream>>>(ixs, g, cnt, off5, boff);
  if (use_compact) {
    k_gatherB<<<40, 1024, 0, stream>>>(cov, g, cnt, off5, boff, Bcomp);
    k_cg_comp<<<40, 1024, 0, stream>>>(Bcomp, g, cnt, off5, boff, walloc);
  } else {
    k_cg_full<<<40, 1024, 0, stream>>>(cov, g, cnt, off5, walloc);
  }
  k_intery<<<160, 256, 0, stream>>>(cov, walloc, g, cnt, off5, y2);
  k_icov<<<8, 256, 0, stream>>>(y2, walloc, ixs, w_inter);
  k_final<<<32, 256, 0, stream>>>(walloc, w_inter, ixs, out);
}